// Round 1
// baseline (1518.893 us; speedup 1.0000x reference)
//
#include <hip/hip_runtime.h>
#include <math.h>

#define NN 8000
#define NE 40000
#define NGB 256
#define SROW 8192   // 64*128 flattened (i,k)
#define KSPLIT 4

__device__ __forceinline__ float sigmoidf_(float x) { return 1.f / (1.f + expf(-x)); }

// out = relu(x @ lin0_w.T + b)   [N,64]
__global__ void k_lin0(const float* __restrict__ x, const float* __restrict__ w,
                       const float* __restrict__ b, float* __restrict__ out) {
    __shared__ float xr[21];
    int n = blockIdx.x, t = threadIdx.x;
    if (t < 21) xr[t] = x[n * 21 + t];
    __syncthreads();
    float s = b[t];
#pragma unroll
    for (int c = 0; c < 21; ++c) s += xr[c] * w[t * 21 + c];
    out[n * 64 + t] = fmaxf(s, 0.f);
}

// e_h = relu(edge_attr @ nn_w1.T + b1)   [E,128]
__global__ void k_eh(const float* __restrict__ ea, const float* __restrict__ w1,
                     const float* __restrict__ b1, float* __restrict__ e_h) {
    __shared__ float a[2][16];
    int t = threadIdx.x;
    int e0 = blockIdx.x * 2;
    if (t < 32) a[t >> 4][t & 15] = ea[(e0 + (t >> 4)) * 16 + (t & 15)];
    __syncthreads();
    int sub = t >> 7, j = t & 127;
    float s = b1[j];
#pragma unroll
    for (int c = 0; c < 16; ++c) s += a[sub][c] * w1[j * 16 + c];
    e_h[(e0 + sub) * 128 + j] = fmaxf(s, 0.f);
}

// Wr[(i*128+k)*64 + o] = nn_w2[(i*64+o)*128 + k]
__global__ void k_wr(const float* __restrict__ nn_w2, float* __restrict__ Wr) {
    int r = blockIdx.x, o = threadIdx.x;
    int i = r >> 7, k = r & 127;
    Wr[r * 64 + o] = nn_w2[((i << 6) + o) * 128 + k];
}

__global__ void k_deg(const int* __restrict__ dst, int* __restrict__ degi) {
    int e = blockIdx.x * blockDim.x + threadIdx.x;
    if (e < NE) atomicAdd(&degi[dst[e]], 1);
}

// single-block scan: rowptr (exclusive), cursor copy, degf = max(deg,1)
__global__ void k_scan(const int* __restrict__ degi, int* __restrict__ rowptr,
                       int* __restrict__ cursor, float* __restrict__ degf) {
    __shared__ int lds[1024];
    __shared__ int carry;
    int t = threadIdx.x;
    if (t == 0) carry = 0;
    __syncthreads();
    for (int base = 0; base < NN; base += 1024) {
        int i = base + t;
        int v = (i < NN) ? degi[i] : 0;
        lds[t] = v;
        __syncthreads();
        for (int off = 1; off < 1024; off <<= 1) {
            int add = (t >= off) ? lds[t - off] : 0;
            __syncthreads();
            lds[t] += add;
            __syncthreads();
        }
        if (i < NN) {
            int exc = lds[t] - v + carry;
            rowptr[i] = exc; cursor[i] = exc;
            degf[i] = (float)(v > 1 ? v : 1);
        }
        __syncthreads();
        if (t == 0) carry += lds[1023];
        __syncthreads();
    }
    if (t == 0) rowptr[NN] = carry;
}

__global__ void k_fill(const int* __restrict__ dst, int* __restrict__ cursor,
                       int* __restrict__ elist) {
    int e = blockIdx.x * blockDim.x + threadIdx.x;
    if (e < NE) { int p = atomicAdd(&cursor[dst[e]], 1); elist[p] = e; }
}

// graph start offsets by binary search in sorted batch
__global__ void k_gstart(const int* __restrict__ batch, int* __restrict__ gstart) {
    int g = blockIdx.x * blockDim.x + threadIdx.x;
    if (g > NGB) return;
    int lo = 0, hi = NN;
    while (lo < hi) { int mid = (lo + hi) >> 1; if (batch[mid] < g) lo = mid + 1; else hi = mid; }
    gstart[g] = lo;
}

// S[local, i*128+k] = sum_{e->n} out[src[e],i]*e_h[e,k];  Osum[n,i] = sum out[src[e],i]
__global__ __launch_bounds__(256) void k_sbuild(
    const float* __restrict__ out, const float* __restrict__ e_h,
    const int* __restrict__ src, const int* __restrict__ rowptr,
    const int* __restrict__ elist, float* __restrict__ S,
    float* __restrict__ Osum, int base) {
    __shared__ float lo[64];
    __shared__ float le[128];
    int t = threadIdx.x;
    int n = base + blockIdx.x;
    float acc[32];
#pragma unroll
    for (int j = 0; j < 32; ++j) acc[j] = 0.f;
    float osum = 0.f;
    int r0 = rowptr[n], r1 = rowptr[n + 1];
    int ib = t >> 7;     // 0/1
    int k = t & 127;
    for (int idx = r0; idx < r1; ++idx) {
        int e = elist[idx];
        int sn = src[e];
        if (t < 64) lo[t] = out[sn * 64 + t];
        else if (t >= 128) le[t - 128] = e_h[(size_t)e * 128 + (t - 128)];
        __syncthreads();
        float ev = le[k];
#pragma unroll
        for (int j = 0; j < 32; ++j) acc[j] += lo[2 * j + ib] * ev;   // elem r=j*256+t -> i=2j+ib, k=t&127
        if (t < 64) osum += lo[t];
        __syncthreads();
    }
    size_t rowbase = (size_t)blockIdx.x * SROW;
#pragma unroll
    for (int j = 0; j < 32; ++j) S[rowbase + j * 256 + t] = acc[j];
    if (t < 64) Osum[(size_t)n * 64 + t] = osum;
}

// P[ks][n,o] = sum_{k in split ks} S[n,k]*Wr[k,o]   (fp32 tiled GEMM, 64x64 tile, 4x4/thread)
#define KB 32
__global__ __launch_bounds__(256) void k_gemm(
    const float* __restrict__ S, const float* __restrict__ Wr,
    float* __restrict__ P, int base) {
    __shared__ __align__(16) float ldsA[KB][68];   // A^T [kk][m], padded
    __shared__ __align__(16) float ldsB[KB][68];
    int t = threadIdx.x;
    int m0 = (t >> 4) * 4, o0 = (t & 15) * 4;
    int mrow = blockIdx.x * 64;      // local (chunk) row
    int ks = blockIdx.y;
    float acc[4][4] = {{0.f}};
    int kbeg = ks * (SROW / KSPLIT), kend = kbeg + SROW / KSPLIT;
    for (int k0 = kbeg; k0 < kend; k0 += KB) {
#pragma unroll
        for (int l = 0; l < 8; ++l) {
            int r = l * 256 + t;
            ldsA[r & 31][r >> 5] = S[(size_t)(mrow + (r >> 5)) * SROW + k0 + (r & 31)];
        }
#pragma unroll
        for (int l = 0; l < 8; ++l) {
            int r = l * 256 + t;
            ldsB[r >> 6][r & 63] = Wr[(size_t)(k0 + (r >> 6)) * 64 + (r & 63)];
        }
        __syncthreads();
#pragma unroll
        for (int kk = 0; kk < KB; ++kk) {
            float4 a = *(const float4*)&ldsA[kk][m0];
            float4 b = *(const float4*)&ldsB[kk][o0];
            acc[0][0] += a.x * b.x; acc[0][1] += a.x * b.y; acc[0][2] += a.x * b.z; acc[0][3] += a.x * b.w;
            acc[1][0] += a.y * b.x; acc[1][1] += a.y * b.y; acc[1][2] += a.y * b.z; acc[1][3] += a.y * b.w;
            acc[2][0] += a.z * b.x; acc[2][1] += a.z * b.y; acc[2][2] += a.z * b.z; acc[2][3] += a.z * b.w;
            acc[3][0] += a.w * b.x; acc[3][1] += a.w * b.y; acc[3][2] += a.w * b.z; acc[3][3] += a.w * b.w;
        }
        __syncthreads();
    }
    size_t pb = (size_t)ks * NN * 64;
#pragma unroll
    for (int i = 0; i < 4; ++i) {
        int n = base + mrow + m0 + i;
        float4 v = make_float4(acc[i][0], acc[i][1], acc[i][2], acc[i][3]);
        *(float4*)&P[pb + (size_t)n * 64 + o0] = v;
    }
}

// m = relu((P_sum + Osum@nn_b2)/deg + out@conv_root + conv_bias); GRU update; out <- h
// one wave per node (slot==wave), 16 nodes per block
__global__ __launch_bounds__(256) void k_gru(
    float* __restrict__ out, const float* __restrict__ P,
    const float* __restrict__ Osum, const float* __restrict__ degf,
    const float* __restrict__ nn_b2, const float* __restrict__ conv_root,
    const float* __restrict__ conv_bias,
    const float* __restrict__ w_ih, const float* __restrict__ w_hh,
    const float* __restrict__ b_ih, const float* __restrict__ b_hh) {
    int t = threadIdx.x, slot = t >> 6, o = t & 63;
    __shared__ float ls_out[4][64], ls_os[4][64], ls_m[4][64];
    for (int rep = 0; rep < 4; ++rep) {
        int n = blockIdx.x * 16 + rep * 4 + slot;
        ls_out[slot][o] = out[(size_t)n * 64 + o];
        ls_os[slot][o] = Osum[(size_t)n * 64 + o];
        float acc = 0.f;
#pragma unroll
        for (int p = 0; p < KSPLIT; ++p) acc += P[((size_t)p * NN + n) * 64 + o];
        float root = 0.f;
#pragma unroll 8
        for (int i = 0; i < 64; ++i) {
            acc += ls_os[slot][i] * nn_b2[i * 64 + o];
            root += ls_out[slot][i] * conv_root[i * 64 + o];
        }
        float m = fmaxf(acc / degf[n] + root + conv_bias[o], 0.f);
        ls_m[slot][o] = m;
        float gi[3], gh[3];
#pragma unroll
        for (int g = 0; g < 3; ++g) {
            float si = b_ih[g * 64 + o], sh = b_hh[g * 64 + o];
            const float4* wi = (const float4*)&w_ih[(g * 64 + o) * 64];
            const float4* wh = (const float4*)&w_hh[(g * 64 + o) * 64];
#pragma unroll
            for (int i4 = 0; i4 < 16; ++i4) {
                float4 a = wi[i4], c = wh[i4];
                si += ls_m[slot][i4 * 4] * a.x + ls_m[slot][i4 * 4 + 1] * a.y
                    + ls_m[slot][i4 * 4 + 2] * a.z + ls_m[slot][i4 * 4 + 3] * a.w;
                sh += ls_out[slot][i4 * 4] * c.x + ls_out[slot][i4 * 4 + 1] * c.y
                    + ls_out[slot][i4 * 4 + 2] * c.z + ls_out[slot][i4 * 4 + 3] * c.w;
            }
            gi[g] = si; gh[g] = sh;
        }
        float r = sigmoidf_(gi[0] + gh[0]);
        float z = sigmoidf_(gi[1] + gh[1]);
        float nv = tanhf(gi[2] + r * gh[2]);
        float hv = (1.f - z) * nv + z * ls_out[slot][o];
        out[(size_t)n * 64 + o] = hv;
    }
}

__global__ __launch_bounds__(256) void k_lstm(
    const float* __restrict__ q_star, float* __restrict__ hs, float* __restrict__ cs,
    const float* __restrict__ w_ih, const float* __restrict__ w_hh,
    const float* __restrict__ b_ih, const float* __restrict__ b_hh) {
    __shared__ float qs[128], hr[64], gates[256];
    int bg = blockIdx.x, t = threadIdx.x;
    if (t < 128) qs[t] = q_star[bg * 128 + t];
    else if (t < 192) hr[t - 128] = hs[bg * 64 + (t - 128)];
    __syncthreads();
    float s = b_ih[t] + b_hh[t];
    const float4* wi = (const float4*)&w_ih[t * 128];
#pragma unroll
    for (int i = 0; i < 32; ++i) {
        float4 a = wi[i];
        s += qs[i * 4] * a.x + qs[i * 4 + 1] * a.y + qs[i * 4 + 2] * a.z + qs[i * 4 + 3] * a.w;
    }
    const float4* wh = (const float4*)&w_hh[t * 64];
#pragma unroll
    for (int i = 0; i < 16; ++i) {
        float4 a = wh[i];
        s += hr[i * 4] * a.x + hr[i * 4 + 1] * a.y + hr[i * 4 + 2] * a.z + hr[i * 4 + 3] * a.w;
    }
    gates[t] = s;
    __syncthreads();
    if (t < 64) {
        float ig = sigmoidf_(gates[t]);
        float fg = sigmoidf_(gates[64 + t]);
        float gg = tanhf(gates[128 + t]);
        float og = sigmoidf_(gates[192 + t]);
        float c = fg * cs[bg * 64 + t] + ig * gg;
        float hv = og * tanhf(c);
        cs[bg * 64 + t] = c;
        hs[bg * 64 + t] = hv;
    }
}

// per-graph softmax attention + readout; q_star = [hs, r_read]
__global__ void k_attn(const float* __restrict__ out, const int* __restrict__ gstart,
                       const float* __restrict__ hs, float* __restrict__ q_star) {
    int g = blockIdx.x, o = threadIdx.x;
    float q = hs[g * 64 + o];
    int s0 = gstart[g], s1 = gstart[g + 1];
    float mmax = -1e30f;
    for (int i = s0; i < s1; ++i) {
        float p = out[(size_t)i * 64 + o] * q;
#pragma unroll
        for (int off = 32; off >= 1; off >>= 1) p += __shfl_xor(p, off);
        mmax = fmaxf(mmax, p);
    }
    float ssum = 0.f, racc = 0.f;
    for (int i = s0; i < s1; ++i) {
        float ov = out[(size_t)i * 64 + o];
        float p = ov * q;
#pragma unroll
        for (int off = 32; off >= 1; off >>= 1) p += __shfl_xor(p, off);
        float w = expf(p - mmax);
        ssum += w;
        racc += w * ov;
    }
    q_star[g * 128 + o] = q;
    q_star[g * 128 + 64 + o] = (s1 > s0) ? (racc / ssum) : 0.f;
}

__global__ void k_final(const float* __restrict__ q_star, const float* __restrict__ w1,
                        const float* __restrict__ b1, const float* __restrict__ w2,
                        const float* __restrict__ b2, float* __restrict__ yout) {
    __shared__ float qs[128];
    int g = blockIdx.x, t = threadIdx.x;
    qs[t] = q_star[g * 128 + t];
    qs[64 + t] = q_star[g * 128 + 64 + t];
    __syncthreads();
    float s = b1[t];
    const float4* w = (const float4*)&w1[t * 128];
#pragma unroll
    for (int i = 0; i < 32; ++i) {
        float4 a = w[i];
        s += qs[i * 4] * a.x + qs[i * 4 + 1] * a.y + qs[i * 4 + 2] * a.z + qs[i * 4 + 3] * a.w;
    }
    s = fmaxf(s, 0.f) * w2[t];
#pragma unroll
    for (int off = 32; off >= 1; off >>= 1) s += __shfl_xor(s, off);
    if (t == 0) yout[g] = s + b2[0];
}

extern "C" void kernel_launch(void* const* d_in, const int* in_sizes, int n_in,
                              void* d_out, int out_size, void* d_ws, size_t ws_size,
                              hipStream_t stream) {
    (void)in_sizes; (void)n_in; (void)out_size;
    const float* x        = (const float*)d_in[0];
    const float* eattr    = (const float*)d_in[1];
    const int*   ei       = (const int*)d_in[2];
    const int*   batch    = (const int*)d_in[3];
    const float* lin0_w   = (const float*)d_in[4];
    const float* lin0_b   = (const float*)d_in[5];
    const float* nn_w1    = (const float*)d_in[6];
    const float* nn_b1    = (const float*)d_in[7];
    const float* nn_w2    = (const float*)d_in[8];
    const float* nn_b2    = (const float*)d_in[9];
    const float* conv_root= (const float*)d_in[10];
    const float* conv_bias= (const float*)d_in[11];
    const float* gw_ih    = (const float*)d_in[12];
    const float* gw_hh    = (const float*)d_in[13];
    const float* gb_ih    = (const float*)d_in[14];
    const float* gb_hh    = (const float*)d_in[15];
    const float* lw_ih    = (const float*)d_in[16];
    const float* lw_hh    = (const float*)d_in[17];
    const float* lb_ih    = (const float*)d_in[18];
    const float* lb_hh    = (const float*)d_in[19];
    const float* lin1_w   = (const float*)d_in[20];
    const float* lin1_b   = (const float*)d_in[21];
    const float* lin2_w   = (const float*)d_in[22];
    const float* lin2_b   = (const float*)d_in[23];
    const int* src = ei;
    const int* dst = ei + NE;

    char* w = (char*)d_ws;
    auto alloc = [&](size_t bytes) { char* p = w; w += (bytes + 255) & ~(size_t)255; return p; };
    float* out    = (float*)alloc((size_t)NN * 64 * 4);
    float* e_h    = (float*)alloc((size_t)NE * 128 * 4);
    float* Wr     = (float*)alloc((size_t)SROW * 64 * 4);
    float* P      = (float*)alloc((size_t)KSPLIT * NN * 64 * 4);
    float* Osum   = (float*)alloc((size_t)NN * 64 * 4);
    float* degf   = (float*)alloc((size_t)NN * 4);
    int*   degi   = (int*)alloc((size_t)NN * 4);
    int*   rowptr = (int*)alloc((size_t)(NN + 1) * 4);
    int*   cursor = (int*)alloc((size_t)(NN + 1) * 4);
    int*   elist  = (int*)alloc((size_t)NE * 4);
    int*   gstart = (int*)alloc((size_t)(NGB + 1) * 4);
    float* q_star = (float*)alloc((size_t)NGB * 128 * 4);
    float* hs     = (float*)alloc((size_t)NGB * 64 * 4);
    float* cs     = (float*)alloc((size_t)NGB * 64 * 4);
    size_t used = (size_t)(w - (char*)d_ws);
    size_t avail = ws_size > used ? ws_size - used : 0;
    size_t maxrows = avail / ((size_t)SROW * 4);
    int chunkN = maxrows > (size_t)NN ? NN : (int)maxrows;
    chunkN = (chunkN / 64) * 64;
    if (chunkN < 64) chunkN = 64;   // below this we cannot run; assume ws is at least ~40MB
    float* S = (float*)w;

    hipMemsetAsync(degi, 0, (size_t)NN * 4, stream);
    hipMemsetAsync(q_star, 0, (size_t)NGB * 128 * 4, stream);
    hipMemsetAsync(hs, 0, (size_t)NGB * 64 * 4, stream);
    hipMemsetAsync(cs, 0, (size_t)NGB * 64 * 4, stream);

    k_lin0<<<NN, 64, 0, stream>>>(x, lin0_w, lin0_b, out);
    k_eh<<<NE / 2, 256, 0, stream>>>(eattr, nn_w1, nn_b1, e_h);
    k_wr<<<SROW, 64, 0, stream>>>(nn_w2, Wr);
    k_deg<<<(NE + 255) / 256, 256, 0, stream>>>(dst, degi);
    k_scan<<<1, 1024, 0, stream>>>(degi, rowptr, cursor, degf);
    k_fill<<<(NE + 255) / 256, 256, 0, stream>>>(dst, cursor, elist);
    k_gstart<<<5, 64, 0, stream>>>(batch, gstart);

    for (int it = 0; it < 3; ++it) {
        for (int cb = 0; cb < NN; cb += chunkN) {
            int cn = (NN - cb) < chunkN ? (NN - cb) : chunkN;
            k_sbuild<<<cn, 256, 0, stream>>>(out, e_h, src, rowptr, elist, S, Osum, cb);
            k_gemm<<<dim3(cn / 64, KSPLIT), 256, 0, stream>>>(S, Wr, P, cb);
        }
        k_gru<<<NN / 16, 256, 0, stream>>>(out, P, Osum, degf, nn_b2, conv_root, conv_bias,
                                           gw_ih, gw_hh, gb_ih, gb_hh);
    }

    for (int st = 0; st < 3; ++st) {
        k_lstm<<<NGB, 256, 0, stream>>>(q_star, hs, cs, lw_ih, lw_hh, lb_ih, lb_hh);
        k_attn<<<NGB, 64, 0, stream>>>(out, gstart, hs, q_star);
    }
    k_final<<<NGB, 64, 0, stream>>>(q_star, lin1_w, lin1_b, lin2_w, lin2_b, (float*)d_out);
}

// Round 3
// 1233.027 us; speedup vs baseline: 1.2318x; 1.2318x over previous
//
#include <hip/hip_runtime.h>
#include <math.h>

#define NN 8000
#define NE 40000
#define NGB 256
#define SK 8192
#define KSPLIT 8

typedef unsigned int u32;
typedef unsigned short u16;
typedef __attribute__((ext_vector_type(8))) short short8v;
typedef __attribute__((ext_vector_type(4))) float float4v;
typedef __attribute__((ext_vector_type(4))) unsigned int uint4v;

__device__ __forceinline__ float sigmoidf_(float x) { return 1.f / (1.f + expf(-x)); }

// round-to-nearest-even bf16 (as u32 holding the 16-bit pattern)
__device__ __forceinline__ u32 bf16_rne(float f) {
    u32 x = __builtin_bit_cast(u32, f);
    return (x + 0x7FFFu + ((x >> 16) & 1u)) >> 16;
}
__device__ __forceinline__ u32 pack_hl(float v) {
    u32 h = bf16_rne(v);
    float fh = __builtin_bit_cast(float, h << 16);
    u32 l = bf16_rne(v - fh);
    return (h << 16) | (l & 0xFFFFu);
}

// ---------- small setup kernels ----------

__global__ void k_lin0(const float* __restrict__ x, const float* __restrict__ w,
                       const float* __restrict__ b, float* __restrict__ out) {
    __shared__ float xr[21];
    int n = blockIdx.x, t = threadIdx.x;
    if (t < 21) xr[t] = x[n * 21 + t];
    __syncthreads();
    float s = b[t];
#pragma unroll
    for (int c = 0; c < 21; ++c) s += xr[c] * w[t * 21 + c];
    out[n * 64 + t] = fmaxf(s, 0.f);
}

__global__ void k_eh(const float* __restrict__ ea, const float* __restrict__ w1,
                     const float* __restrict__ b1, float* __restrict__ e_h) {
    __shared__ float a[2][16];
    int t = threadIdx.x;
    int e0 = blockIdx.x * 2;
    if (t < 32) a[t >> 4][t & 15] = ea[(e0 + (t >> 4)) * 16 + (t & 15)];
    __syncthreads();
    int sub = t >> 7, j = t & 127;
    float s = b1[j];
#pragma unroll
    for (int c = 0; c < 16; ++c) s += a[sub][c] * w1[j * 16 + c];
    e_h[(size_t)(e0 + sub) * 128 + j] = fmaxf(s, 0.f);
}

// W2T hi/lo: Whi/Wlo[o*SK + (i*128+k)] = split(nn_w2[(i*64+o)*128 + k])
__global__ void k_wsplit(const float* __restrict__ nn_w2, u16* __restrict__ Whi,
                         u16* __restrict__ Wlo) {
    int idx = blockIdx.x * 256 + threadIdx.x;   // [0, 64*8192)
    int o = idx >> 13, kap = idx & 8191;
    int i = kap >> 7, k = kap & 127;
    float v = nn_w2[(size_t)((i << 6) + o) * 128 + k];
    u32 h = bf16_rne(v);
    float fh = __builtin_bit_cast(float, h << 16);
    u32 l = bf16_rne(v - fh);
    Whi[idx] = (u16)h; Wlo[idx] = (u16)l;
}

// transposed GRU weights: gwT[mm*4096 + i*64 + o], mm 0..2 = ih gates, 3..5 = hh gates
__global__ void k_prep_gw(const float* __restrict__ w_ih, const float* __restrict__ w_hh,
                          float* __restrict__ gwT) {
    int tg = blockIdx.x * 256 + threadIdx.x;   // < 24576
    int mm = tg >> 12, rem = tg & 4095;
    int i = rem >> 6, o = rem & 63;
    float v = (mm < 3) ? w_ih[((mm * 64 + o) << 6) + i] : w_hh[(((mm - 3) * 64 + o) << 6) + i];
    gwT[tg] = v;
}

__global__ void k_deg(const int* __restrict__ dst, int* __restrict__ degi) {
    int e = blockIdx.x * blockDim.x + threadIdx.x;
    if (e < NE) atomicAdd(&degi[dst[e]], 1);
}

__global__ void k_scan(const int* __restrict__ degi, int* __restrict__ rowptr,
                       int* __restrict__ cursor, float* __restrict__ degf) {
    __shared__ int lds[1024];
    __shared__ int carry;
    int t = threadIdx.x;
    if (t == 0) carry = 0;
    __syncthreads();
    for (int base = 0; base < NN; base += 1024) {
        int i = base + t;
        int v = (i < NN) ? degi[i] : 0;
        lds[t] = v;
        __syncthreads();
        for (int off = 1; off < 1024; off <<= 1) {
            int add = (t >= off) ? lds[t - off] : 0;
            __syncthreads();
            lds[t] += add;
            __syncthreads();
        }
        if (i < NN) {
            int exc = lds[t] - v + carry;
            rowptr[i] = exc; cursor[i] = exc;
            degf[i] = (float)(v > 1 ? v : 1);
        }
        __syncthreads();
        if (t == 0) carry += lds[1023];
        __syncthreads();
    }
    if (t == 0) rowptr[NN] = carry;
}

__global__ void k_fill(const int* __restrict__ dst, int* __restrict__ cursor,
                       int* __restrict__ elist) {
    int e = blockIdx.x * blockDim.x + threadIdx.x;
    if (e < NE) { int p = atomicAdd(&cursor[dst[e]], 1); elist[p] = e; }
}

__global__ void k_gstart(const int* __restrict__ batch, int* __restrict__ gstart) {
    int g = blockIdx.x * blockDim.x + threadIdx.x;
    if (g > NGB) return;
    int lo = 0, hi = NN;
    while (lo < hi) { int mid = (lo + hi) >> 1; if (batch[mid] < g) lo = mid + 1; else hi = mid; }
    gstart[g] = lo;
}

// ---------- NNConv: S build (rank-1 outer products, packed bf16 hi/lo) ----------
// S[local, kappa] with kappa = i*128 + k;  thread t: i-half ib=t>>7, k=t&127, i = ib*32 + j
__global__ __launch_bounds__(256) void k_sbuild(
    const float* __restrict__ out, const float* __restrict__ e_h,
    const int* __restrict__ src, const int* __restrict__ rowptr,
    const int* __restrict__ elist, u32* __restrict__ S_pk,
    float* __restrict__ Osum, int base) {
    int t = threadIdx.x;
    int n = base + blockIdx.x;
    int lane = t & 63;
    int ib = t >> 7;
    int k = t & 127;
    float acc[32];
#pragma unroll
    for (int j = 0; j < 32; ++j) acc[j] = 0.f;
    float osum = 0.f;
    int r0 = rowptr[n], r1 = rowptr[n + 1];
    const float4* out4 = (const float4*)out;
    for (int idx = r0; idx < r1; ++idx) {
        int e = elist[idx];
        int sn = src[e];
        float ehv = e_h[(size_t)e * 128 + k];
        float4 f[8];
#pragma unroll
        for (int q = 0; q < 8; ++q) f[q] = out4[sn * 16 + ib * 8 + q];
#pragma unroll
        for (int q = 0; q < 8; ++q) {
            acc[q * 4 + 0] += f[q].x * ehv;
            acc[q * 4 + 1] += f[q].y * ehv;
            acc[q * 4 + 2] += f[q].z * ehv;
            acc[q * 4 + 3] += f[q].w * ehv;
        }
        if (t < 64) osum += out[(size_t)sn * 64 + lane];
    }
    size_t rb = (size_t)blockIdx.x * SK;
#pragma unroll
    for (int j = 0; j < 32; ++j)
        S_pk[rb + (size_t)((ib * 32 + j) * 128 + k)] = pack_hl(acc[j]);
    if (t < 64) Osum[(size_t)n * 64 + lane] = osum;
}

// ---------- NNConv: MFMA GEMM, bf16x3 compensated: P[ks][n][o] = sum_kappa S*W2T ----------
__global__ __launch_bounds__(256) void k_gemm(
    const u32* __restrict__ S_pk, const u16* __restrict__ Whi,
    const u16* __restrict__ Wlo, float* __restrict__ P, int base) {
    int t = threadIdx.x;
    int wv = t >> 6, lane = t & 63;
    int lrow = lane & 15, lkg = lane >> 4;
    int mloc = blockIdx.x * 64 + wv * 16 + lrow;   // local chunk row (A row)
    int ks = blockIdx.y;
    float4v acc[4];
#pragma unroll
    for (int nt = 0; nt < 4; ++nt) acc[nt] = (float4v){0.f, 0.f, 0.f, 0.f};
    size_t arow = (size_t)mloc * SK;
    for (int kk = 0; kk < 32; ++kk) {
        int kappa = ks * 1024 + kk * 32 + lkg * 8;
        const uint4v* ap = (const uint4v*)&S_pk[arow + kappa];
        uint4v a0 = ap[0], a1 = ap[1];
        uint4v hset = { (a0.x >> 16) | (a0.y & 0xFFFF0000u),
                        (a0.z >> 16) | (a0.w & 0xFFFF0000u),
                        (a1.x >> 16) | (a1.y & 0xFFFF0000u),
                        (a1.z >> 16) | (a1.w & 0xFFFF0000u) };
        uint4v lset = { (a0.x & 0xFFFFu) | (a0.y << 16),
                        (a0.z & 0xFFFFu) | (a0.w << 16),
                        (a1.x & 0xFFFFu) | (a1.y << 16),
                        (a1.z & 0xFFFFu) | (a1.w << 16) };
        short8v ah = __builtin_bit_cast(short8v, hset);
        short8v al = __builtin_bit_cast(short8v, lset);
#pragma unroll
        for (int nt = 0; nt < 4; ++nt) {
            int o = nt * 16 + lrow;
            short8v bh = *(const short8v*)&Whi[(size_t)o * SK + kappa];
            short8v bl = *(const short8v*)&Wlo[(size_t)o * SK + kappa];
            acc[nt] = __builtin_amdgcn_mfma_f32_16x16x32_bf16(ah, bh, acc[nt], 0, 0, 0);
            acc[nt] = __builtin_amdgcn_mfma_f32_16x16x32_bf16(al, bh, acc[nt], 0, 0, 0);
            acc[nt] = __builtin_amdgcn_mfma_f32_16x16x32_bf16(ah, bl, acc[nt], 0, 0, 0);
        }
    }
    int gnode_base = base + blockIdx.x * 64 + wv * 16;
#pragma unroll
    for (int nt = 0; nt < 4; ++nt) {
#pragma unroll
        for (int jj = 0; jj < 4; ++jj) {
            int row = lkg * 4 + jj;          // C/D: row=(lane>>4)*4+reg  [m89 verified]
            int o = nt * 16 + lrow;          //      col=lane&15
            P[((size_t)ks * NN + gnode_base + row) * 64 + o] = acc[nt][jj];
        }
    }
}

// ---------- m = relu((Psum + Osum@nn_b2)/deg + out@conv_root + cb) ----------
__global__ __launch_bounds__(256) void k_mrelu(
    const float* __restrict__ out, const float* __restrict__ P,
    const float* __restrict__ Osum, const float* __restrict__ degf,
    const float* __restrict__ conv_root, const float* __restrict__ nn_b2,
    const float* __restrict__ conv_bias, float* __restrict__ M) {
    __shared__ float CW[8192];          // [0..4095]=conv_root[i][o], [4096..]=nn_b2[i][o]
    __shared__ float stg[4][2][64];
    int t = threadIdx.x;
#pragma unroll
    for (int r = 0; r < 32; ++r) {
        int idx = r * 256 + t;
        CW[idx] = (idx < 4096) ? conv_root[idx] : nn_b2[idx - 4096];
    }
    __syncthreads();
    int wv = t >> 6, lane = t & 63;
    float cb = conv_bias[lane];
    for (int rep = 0; rep < 16; ++rep) {
        int n = blockIdx.x * 64 + wv * 16 + rep;
        float ov = out[(size_t)n * 64 + lane];
        float osv = Osum[(size_t)n * 64 + lane];
        stg[wv][0][lane] = ov; stg[wv][1][lane] = osv;
        float ps = 0.f;
#pragma unroll
        for (int s = 0; s < KSPLIT; ++s) ps += P[((size_t)s * NN + n) * 64 + lane];
        float a1 = 0.f, a2 = 0.f;
#pragma unroll 4
        for (int i4 = 0; i4 < 16; ++i4) {
            float4 o4 = *(const float4*)&stg[wv][0][i4 * 4];
            float4 s4 = *(const float4*)&stg[wv][1][i4 * 4];
            int b0 = (i4 * 4) * 64 + lane;
            a1 += o4.x * CW[b0] + o4.y * CW[b0 + 64] + o4.z * CW[b0 + 128] + o4.w * CW[b0 + 192];
            int b1i = (64 + i4 * 4) * 64 + lane;
            a2 += s4.x * CW[b1i] + s4.y * CW[b1i + 64] + s4.z * CW[b1i + 128] + s4.w * CW[b1i + 192];
        }
        M[(size_t)n * 64 + lane] = fmaxf((ps + a2) / degf[n] + a1 + cb, 0.f);
    }
}

// ---------- GRU gates; out <- h' ----------
__global__ __launch_bounds__(256) void k_gates(
    float* __restrict__ out, const float* __restrict__ M,
    const float* __restrict__ gwT,
    const float* __restrict__ gb_ih, const float* __restrict__ gb_hh) {
    __shared__ float GW[24576];
    __shared__ float stg[4][2][64];
    int t = threadIdx.x;
#pragma unroll
    for (int r = 0; r < 96; ++r) GW[r * 256 + t] = gwT[r * 256 + t];
    __syncthreads();
    int wv = t >> 6, lane = t & 63;
    float bi0 = gb_ih[lane], bi1 = gb_ih[64 + lane], bi2 = gb_ih[128 + lane];
    float bh0 = gb_hh[lane], bh1 = gb_hh[64 + lane], bh2 = gb_hh[128 + lane];
    for (int rep = 0; rep < 16; ++rep) {
        int n = blockIdx.x * 64 + wv * 16 + rep;
        float hv_own = out[(size_t)n * 64 + lane];
        float mv_own = M[(size_t)n * 64 + lane];
        stg[wv][0][lane] = hv_own; stg[wv][1][lane] = mv_own;
        float g0 = 0, g1 = 0, g2 = 0, h0 = 0, h1 = 0, h2 = 0;
#pragma unroll 2
        for (int i4 = 0; i4 < 16; ++i4) {
            float4 m4 = *(const float4*)&stg[wv][1][i4 * 4];
            float4 h4 = *(const float4*)&stg[wv][0][i4 * 4];
            float mv[4] = {m4.x, m4.y, m4.z, m4.w};
            float hh[4] = {h4.x, h4.y, h4.z, h4.w};
#pragma unroll
            for (int c = 0; c < 4; ++c) {
                int base_ = (i4 * 4 + c) * 64 + lane;
                g0 += mv[c] * GW[base_];
                g1 += mv[c] * GW[4096 + base_];
                g2 += mv[c] * GW[8192 + base_];
                h0 += hh[c] * GW[12288 + base_];
                h1 += hh[c] * GW[16384 + base_];
                h2 += hh[c] * GW[20480 + base_];
            }
        }
        float r = sigmoidf_(g0 + h0 + bi0 + bh0);
        float z = sigmoidf_(g1 + h1 + bi1 + bh1);
        float nn_ = tanhf(g2 + bi2 + r * (h2 + bh2));
        out[(size_t)n * 64 + lane] = (1.f - z) * nn_ + z * hv_own;
    }
}

// ---------- Set2Set ----------
__global__ __launch_bounds__(256) void k_lstm(
    const float* __restrict__ q_star, float* __restrict__ hs, float* __restrict__ cs,
    const float* __restrict__ w_ih, const float* __restrict__ w_hh,
    const float* __restrict__ b_ih, const float* __restrict__ b_hh) {
    __shared__ float qs[128], hr[64], gates[256];
    int bg = blockIdx.x, t = threadIdx.x;
    if (t < 128) qs[t] = q_star[bg * 128 + t];
    else if (t < 192) hr[t - 128] = hs[bg * 64 + (t - 128)];
    __syncthreads();
    float s = b_ih[t] + b_hh[t];
    const float4* wi = (const float4*)&w_ih[t * 128];
#pragma unroll
    for (int i = 0; i < 32; ++i) {
        float4 a = wi[i];
        s += qs[i * 4] * a.x + qs[i * 4 + 1] * a.y + qs[i * 4 + 2] * a.z + qs[i * 4 + 3] * a.w;
    }
    const float4* wh = (const float4*)&w_hh[t * 64];
#pragma unroll
    for (int i = 0; i < 16; ++i) {
        float4 a = wh[i];
        s += hr[i * 4] * a.x + hr[i * 4 + 1] * a.y + hr[i * 4 + 2] * a.z + hr[i * 4 + 3] * a.w;
    }
    gates[t] = s;
    __syncthreads();
    if (t < 64) {
        float ig = sigmoidf_(gates[t]);
        float fg = sigmoidf_(gates[64 + t]);
        float gg = tanhf(gates[128 + t]);
        float og = sigmoidf_(gates[192 + t]);
        float c = fg * cs[bg * 64 + t] + ig * gg;
        float hv = og * tanhf(c);
        cs[bg * 64 + t] = c;
        hs[bg * 64 + t] = hv;
    }
}

__global__ void k_attn(const float* __restrict__ out, const int* __restrict__ gstart,
                       const float* __restrict__ hs, float* __restrict__ q_star) {
    int g = blockIdx.x, o = threadIdx.x;
    float q = hs[g * 64 + o];
    int s0 = gstart[g], s1 = gstart[g + 1];
    float mmax = -1e30f;
    for (int i = s0; i < s1; ++i) {
        float p = out[(size_t)i * 64 + o] * q;
#pragma unroll
        for (int off = 32; off >= 1; off >>= 1) p += __shfl_xor(p, off);
        mmax = fmaxf(mmax, p);
    }
    float ssum = 0.f, racc = 0.f;
    for (int i = s0; i < s1; ++i) {
        float ov = out[(size_t)i * 64 + o];
        float p = ov * q;
#pragma unroll
        for (int off = 32; off >= 1; off >>= 1) p += __shfl_xor(p, off);
        float w = expf(p - mmax);
        ssum += w;
        racc += w * ov;
    }
    q_star[g * 128 + o] = q;
    q_star[g * 128 + 64 + o] = (s1 > s0) ? (racc / ssum) : 0.f;
}

__global__ void k_final(const float* __restrict__ q_star, const float* __restrict__ w1,
                        const float* __restrict__ b1, const float* __restrict__ w2,
                        const float* __restrict__ b2, float* __restrict__ yout) {
    __shared__ float qs[128];
    int g = blockIdx.x, t = threadIdx.x;
    qs[t] = q_star[g * 128 + t];
    qs[64 + t] = q_star[g * 128 + 64 + t];
    __syncthreads();
    float s = b1[t];
    const float4* w = (const float4*)&w1[t * 128];
#pragma unroll
    for (int i = 0; i < 32; ++i) {
        float4 a = w[i];
        s += qs[i * 4] * a.x + qs[i * 4 + 1] * a.y + qs[i * 4 + 2] * a.z + qs[i * 4 + 3] * a.w;
    }
    s = fmaxf(s, 0.f) * w2[t];
#pragma unroll
    for (int off = 32; off >= 1; off >>= 1) s += __shfl_xor(s, off);
    if (t == 0) yout[g] = s + b2[0];
}

extern "C" void kernel_launch(void* const* d_in, const int* in_sizes, int n_in,
                              void* d_out, int out_size, void* d_ws, size_t ws_size,
                              hipStream_t stream) {
    (void)in_sizes; (void)n_in; (void)out_size;
    const float* x        = (const float*)d_in[0];
    const float* eattr    = (const float*)d_in[1];
    const int*   ei       = (const int*)d_in[2];
    const int*   batch    = (const int*)d_in[3];
    const float* lin0_w   = (const float*)d_in[4];
    const float* lin0_b   = (const float*)d_in[5];
    const float* nn_w1    = (const float*)d_in[6];
    const float* nn_b1    = (const float*)d_in[7];
    const float* nn_w2    = (const float*)d_in[8];
    const float* nn_b2    = (const float*)d_in[9];
    const float* conv_root= (const float*)d_in[10];
    const float* conv_bias= (const float*)d_in[11];
    const float* gw_ih    = (const float*)d_in[12];
    const float* gw_hh    = (const float*)d_in[13];
    const float* gb_ih    = (const float*)d_in[14];
    const float* gb_hh    = (const float*)d_in[15];
    const float* lw_ih    = (const float*)d_in[16];
    const float* lw_hh    = (const float*)d_in[17];
    const float* lb_ih    = (const float*)d_in[18];
    const float* lb_hh    = (const float*)d_in[19];
    const float* lin1_w   = (const float*)d_in[20];
    const float* lin1_b   = (const float*)d_in[21];
    const float* lin2_w   = (const float*)d_in[22];
    const float* lin2_b   = (const float*)d_in[23];
    const int* src = ei;
    const int* dst = ei + NE;

    char* w = (char*)d_ws;
    auto alloc = [&](size_t bytes) { char* p = w; w += (bytes + 255) & ~(size_t)255; return p; };
    float* out    = (float*)alloc((size_t)NN * 64 * 4);
    float* e_h    = (float*)alloc((size_t)NE * 128 * 4);
    u16*   Whi    = (u16*)alloc((size_t)64 * SK * 2);
    u16*   Wlo    = (u16*)alloc((size_t)64 * SK * 2);
    float* P      = (float*)alloc((size_t)KSPLIT * NN * 64 * 4);
    float* Osum   = (float*)alloc((size_t)NN * 64 * 4);
    float* M      = (float*)alloc((size_t)NN * 64 * 4);
    float* gwT    = (float*)alloc((size_t)6 * 4096 * 4);
    float* degf   = (float*)alloc((size_t)NN * 4);
    int*   degi   = (int*)alloc((size_t)NN * 4);
    int*   rowptr = (int*)alloc((size_t)(NN + 1) * 4);
    int*   cursor = (int*)alloc((size_t)(NN + 1) * 4);
    int*   elist  = (int*)alloc((size_t)NE * 4);
    int*   gstart = (int*)alloc((size_t)(NGB + 1) * 4);
    float* q_star = (float*)alloc((size_t)NGB * 128 * 4);
    float* hs     = (float*)alloc((size_t)NGB * 64 * 4);
    float* cs     = (float*)alloc((size_t)NGB * 64 * 4);
    size_t used = (size_t)(w - (char*)d_ws);
    size_t avail = ws_size > used ? ws_size - used : 0;
    size_t maxrows = avail / ((size_t)SK * 4);
    int chunkN = maxrows > (size_t)NN ? NN : (int)maxrows;
    chunkN = (chunkN / 64) * 64;
    if (chunkN < 64) chunkN = 64;
    u32* S_pk = (u32*)w;

    hipMemsetAsync(degi, 0, (size_t)NN * 4, stream);
    hipMemsetAsync(q_star, 0, (size_t)NGB * 128 * 4, stream);
    hipMemsetAsync(hs, 0, (size_t)NGB * 64 * 4, stream);
    hipMemsetAsync(cs, 0, (size_t)NGB * 64 * 4, stream);

    k_lin0<<<NN, 64, 0, stream>>>(x, lin0_w, lin0_b, out);
    k_eh<<<NE / 2, 256, 0, stream>>>(eattr, nn_w1, nn_b1, e_h);
    k_wsplit<<<(64 * SK) / 256, 256, 0, stream>>>(nn_w2, Whi, Wlo);
    k_prep_gw<<<96, 256, 0, stream>>>(gw_ih, gw_hh, gwT);
    k_deg<<<(NE + 255) / 256, 256, 0, stream>>>(dst, degi);
    k_scan<<<1, 1024, 0, stream>>>(degi, rowptr, cursor, degf);
    k_fill<<<(NE + 255) / 256, 256, 0, stream>>>(dst, cursor, elist);
    k_gstart<<<5, 64, 0, stream>>>(batch, gstart);

    for (int it = 0; it < 3; ++it) {
        for (int cb = 0; cb < NN; cb += chunkN) {
            int cn = (NN - cb) < chunkN ? (NN - cb) : chunkN;
            k_sbuild<<<cn, 256, 0, stream>>>(out, e_h, src, rowptr, elist, S_pk, Osum, cb);
            k_gemm<<<dim3(cn / 64, KSPLIT), 256, 0, stream>>>(S_pk, Whi, Wlo, P, cb);
        }
        k_mrelu<<<NN / 64, 256, 0, stream>>>(out, P, Osum, degf, conv_root, nn_b2, conv_bias, M);
        k_gates<<<NN / 64, 256, 0, stream>>>(out, M, gwT, gb_ih, gb_hh);
    }

    for (int st = 0; st < 3; ++st) {
        k_lstm<<<NGB, 256, 0, stream>>>(q_star, hs, cs, lw_ih, lw_hh, lb_ih, lb_hh);
        k_attn<<<NGB, 64, 0, stream>>>(out, gstart, hs, q_star);
    }
    k_final<<<NGB, 64, 0, stream>>>(q_star, lin1_w, lin1_b, lin2_w, lin2_b, (float*)d_out);
}

// Round 5
// 1156.332 us; speedup vs baseline: 1.3135x; 1.0663x over previous
//
#include <hip/hip_runtime.h>
#include <math.h>

#define NN 8000
#define NE 40000
#define NGB 256
#define SK 8192
#define KSPLIT 8

typedef unsigned int u32;
typedef unsigned short u16;
typedef __attribute__((ext_vector_type(8))) short short8v;
typedef __attribute__((ext_vector_type(4))) float float4v;
typedef __attribute__((ext_vector_type(4))) unsigned int uint4v;

__device__ __forceinline__ float sigmoidf_(float x) { return 1.f / (1.f + expf(-x)); }

// round-to-nearest-even bf16 (as u32 holding the 16-bit pattern)
__device__ __forceinline__ u32 bf16_rne(float f) {
    u32 x = __builtin_bit_cast(u32, f);
    return (x + 0x7FFFu + ((x >> 16) & 1u)) >> 16;
}
__device__ __forceinline__ u32 pack_hl(float v) {
    u32 h = bf16_rne(v);
    float fh = __builtin_bit_cast(float, h << 16);
    u32 l = bf16_rne(v - fh);
    return (h << 16) | (l & 0xFFFFu);
}

// ---------- small setup kernels ----------

__global__ void k_lin0(const float* __restrict__ x, const float* __restrict__ w,
                       const float* __restrict__ b, float* __restrict__ out) {
    __shared__ float xr[21];
    int n = blockIdx.x, t = threadIdx.x;
    if (t < 21) xr[t] = x[n * 21 + t];
    __syncthreads();
    float s = b[t];
#pragma unroll
    for (int c = 0; c < 21; ++c) s += xr[c] * w[t * 21 + c];
    out[n * 64 + t] = fmaxf(s, 0.f);
}

__global__ void k_eh(const float* __restrict__ ea, const float* __restrict__ w1,
                     const float* __restrict__ b1, float* __restrict__ e_h) {
    __shared__ float a[2][16];
    int t = threadIdx.x;
    int e0 = blockIdx.x * 2;
    if (t < 32) a[t >> 4][t & 15] = ea[(e0 + (t >> 4)) * 16 + (t & 15)];
    __syncthreads();
    int sub = t >> 7, j = t & 127;
    float s = b1[j];
#pragma unroll
    for (int c = 0; c < 16; ++c) s += a[sub][c] * w1[j * 16 + c];
    e_h[(size_t)(e0 + sub) * 128 + j] = fmaxf(s, 0.f);
}

// W2T hi/lo: Whi/Wlo[o*SK + (i*128+k)] = split(nn_w2[(i*64+o)*128 + k])
__global__ void k_wsplit(const float* __restrict__ nn_w2, u16* __restrict__ Whi,
                         u16* __restrict__ Wlo) {
    int idx = blockIdx.x * 256 + threadIdx.x;   // [0, 64*8192)
    int o = idx >> 13, kap = idx & 8191;
    int i = kap >> 7, k = kap & 127;
    float v = nn_w2[(size_t)((i << 6) + o) * 128 + k];
    u32 h = bf16_rne(v);
    float fh = __builtin_bit_cast(float, h << 16);
    u32 l = bf16_rne(v - fh);
    Whi[idx] = (u16)h; Wlo[idx] = (u16)l;
}

// transposed GRU weights: gwT[mm*4096 + i*64 + o], mm 0..2 = ih gates, 3..5 = hh gates
__global__ void k_prep_gw(const float* __restrict__ w_ih, const float* __restrict__ w_hh,
                          float* __restrict__ gwT) {
    int tg = blockIdx.x * 256 + threadIdx.x;   // < 24576
    int mm = tg >> 12, rem = tg & 4095;
    int i = rem >> 6, o = rem & 63;
    float v = (mm < 3) ? w_ih[((mm * 64 + o) << 6) + i] : w_hh[(((mm - 3) * 64 + o) << 6) + i];
    gwT[tg] = v;
}

__global__ void k_deg(const int* __restrict__ dst, int* __restrict__ degi) {
    int e = blockIdx.x * blockDim.x + threadIdx.x;
    if (e < NE) atomicAdd(&degi[dst[e]], 1);
}

__global__ void k_scan(const int* __restrict__ degi, int* __restrict__ rowptr,
                       int* __restrict__ cursor, float* __restrict__ degf) {
    __shared__ int lds[1024];
    __shared__ int carry;
    int t = threadIdx.x;
    if (t == 0) carry = 0;
    __syncthreads();
    for (int base = 0; base < NN; base += 1024) {
        int i = base + t;
        int v = (i < NN) ? degi[i] : 0;
        lds[t] = v;
        __syncthreads();
        for (int off = 1; off < 1024; off <<= 1) {
            int add = (t >= off) ? lds[t - off] : 0;
            __syncthreads();
            lds[t] += add;
            __syncthreads();
        }
        if (i < NN) {
            int exc = lds[t] - v + carry;
            rowptr[i] = exc; cursor[i] = exc;
            degf[i] = (float)(v > 1 ? v : 1);
        }
        __syncthreads();
        if (t == 0) carry += lds[1023];
        __syncthreads();
    }
    if (t == 0) rowptr[NN] = carry;
}

__global__ void k_fill(const int* __restrict__ dst, int* __restrict__ cursor,
                       int* __restrict__ elist) {
    int e = blockIdx.x * blockDim.x + threadIdx.x;
    if (e < NE) { int p = atomicAdd(&cursor[dst[e]], 1); elist[p] = e; }
}

__global__ void k_gstart(const int* __restrict__ batch, int* __restrict__ gstart) {
    int g = blockIdx.x * blockDim.x + threadIdx.x;
    if (g > NGB) return;
    int lo = 0, hi = NN;
    while (lo < hi) { int mid = (lo + hi) >> 1; if (batch[mid] < g) lo = mid + 1; else hi = mid; }
    gstart[g] = lo;
}

// ---------- NNConv: S build (rank-1 outer products, packed bf16 hi/lo) ----------
// thread t: i-group ib=t>>5 (8 rows), k-quad kq=t&31 (k=kq*4..+3)
__global__ __launch_bounds__(256) void k_sbuild(
    const float* __restrict__ out, const float* __restrict__ e_h,
    const int* __restrict__ src, const int* __restrict__ rowptr,
    const int* __restrict__ elist, u32* __restrict__ S_pk,
    float* __restrict__ Osum, int base) {
    int t = threadIdx.x;
    int n = base + blockIdx.x;
    int ib = t >> 5;
    int kq = t & 31;
    int lane = t & 63;
    float acc[8][4];
#pragma unroll
    for (int j = 0; j < 8; ++j) { acc[j][0] = 0.f; acc[j][1] = 0.f; acc[j][2] = 0.f; acc[j][3] = 0.f; }
    float osum = 0.f;
    int r0 = rowptr[n], r1 = rowptr[n + 1];
    const float4* out4 = (const float4*)out;
    const float4* eh4p = (const float4*)e_h;
    for (int idx = r0; idx < r1; ++idx) {
        int e = elist[idx];
        int sn = src[e];
        float4 eh = eh4p[(size_t)e * 32 + kq];
        float4 f0 = out4[sn * 16 + ib * 2];
        float4 f1 = out4[sn * 16 + ib * 2 + 1];
        float fv[8] = {f0.x, f0.y, f0.z, f0.w, f1.x, f1.y, f1.z, f1.w};
#pragma unroll
        for (int j = 0; j < 8; ++j) {
            acc[j][0] += fv[j] * eh.x; acc[j][1] += fv[j] * eh.y;
            acc[j][2] += fv[j] * eh.z; acc[j][3] += fv[j] * eh.w;
        }
        if (t < 64) osum += out[(size_t)sn * 64 + lane];
    }
    size_t rb4 = (size_t)blockIdx.x * (SK / 4);
    uint4v* S4 = (uint4v*)S_pk;
#pragma unroll
    for (int j = 0; j < 8; ++j) {
        uint4v v = { pack_hl(acc[j][0]), pack_hl(acc[j][1]), pack_hl(acc[j][2]), pack_hl(acc[j][3]) };
        S4[rb4 + (size_t)(ib * 8 + j) * 32 + kq] = v;
    }
    if (t < 64) Osum[(size_t)n * 64 + lane] = osum;
}

// ---------- NNConv: MFMA GEMM, bf16x3, register-double-buffered ----------
__global__ __launch_bounds__(256) void k_gemm(
    const u32* __restrict__ S_pk, const u16* __restrict__ Whi,
    const u16* __restrict__ Wlo, float* __restrict__ P, int base) {
    int t = threadIdx.x;
    int wv = t >> 6, lane = t & 63;
    int lrow = lane & 15, lkg = lane >> 4;
    int mloc = blockIdx.x * 64 + wv * 16 + lrow;   // local chunk row (A row)
    int ks = blockIdx.y;
    float4v acc[4];
#pragma unroll
    for (int nt = 0; nt < 4; ++nt) acc[nt] = (float4v){0.f, 0.f, 0.f, 0.f};
    int kappa0 = ks * 1024 + lkg * 8;
    const uint4v* ap = (const uint4v*)&S_pk[(size_t)mloc * SK + kappa0];  // +8 per kk
    const short8v* bhv = (const short8v*)Whi;
    const short8v* blv = (const short8v*)Wlo;
    int bbase = lrow * 1024 + (kappa0 >> 3);       // +nt*16384 per o-subtile, +4 per kk

    uint4v a0 = ap[0], a1 = ap[1];
    short8v bh[4], bl[4];
#pragma unroll
    for (int nt = 0; nt < 4; ++nt) {
        bh[nt] = bhv[bbase + nt * 16384];
        bl[nt] = blv[bbase + nt * 16384];
    }
    for (int kk = 0; kk < 32; ++kk) {
        int nk = (kk + 1) & 31;                    // wrap: last prefetch re-reads kk=0 (valid, unused)
        uint4v na0 = ap[nk * 8], na1 = ap[nk * 8 + 1];
        short8v nbh[4], nbl[4];
#pragma unroll
        for (int nt = 0; nt < 4; ++nt) {
            nbh[nt] = bhv[bbase + nt * 16384 + nk * 4];
            nbl[nt] = blv[bbase + nt * 16384 + nk * 4];
        }
        uint4v hset = { (a0.x >> 16) | (a0.y & 0xFFFF0000u),
                        (a0.z >> 16) | (a0.w & 0xFFFF0000u),
                        (a1.x >> 16) | (a1.y & 0xFFFF0000u),
                        (a1.z >> 16) | (a1.w & 0xFFFF0000u) };
        uint4v lset = { (a0.x & 0xFFFFu) | (a0.y << 16),
                        (a0.z & 0xFFFFu) | (a0.w << 16),
                        (a1.x & 0xFFFFu) | (a1.y << 16),
                        (a1.z & 0xFFFFu) | (a1.w << 16) };
        short8v ah = __builtin_bit_cast(short8v, hset);
        short8v al = __builtin_bit_cast(short8v, lset);
#pragma unroll
        for (int nt = 0; nt < 4; ++nt) {
            acc[nt] = __builtin_amdgcn_mfma_f32_16x16x32_bf16(ah, bh[nt], acc[nt], 0, 0, 0);
            acc[nt] = __builtin_amdgcn_mfma_f32_16x16x32_bf16(al, bh[nt], acc[nt], 0, 0, 0);
            acc[nt] = __builtin_amdgcn_mfma_f32_16x16x32_bf16(ah, bl[nt], acc[nt], 0, 0, 0);
        }
        a0 = na0; a1 = na1;
#pragma unroll
        for (int nt = 0; nt < 4; ++nt) { bh[nt] = nbh[nt]; bl[nt] = nbl[nt]; }
    }
    int gnode_base = base + blockIdx.x * 64 + wv * 16;
#pragma unroll
    for (int nt = 0; nt < 4; ++nt) {
#pragma unroll
        for (int jj = 0; jj < 4; ++jj) {
            int row = lkg * 4 + jj;          // C/D: row=(lane>>4)*4+reg  [m89 verified]
            int o = nt * 16 + lrow;          //      col=lane&15
            P[((size_t)ks * NN + gnode_base + row) * 64 + o] = acc[nt][jj];
        }
    }
}

// ---------- m = relu((Psum + Osum@nn_b2)/deg + out@conv_root + cb) ----------
__global__ __launch_bounds__(256) void k_mrelu(
    const float* __restrict__ out, const float* __restrict__ P,
    const float* __restrict__ Osum, const float* __restrict__ degf,
    const float* __restrict__ conv_root, const float* __restrict__ nn_b2,
    const float* __restrict__ conv_bias, float* __restrict__ M) {
    __shared__ float CW[8192];          // [0..4095]=conv_root[i][o], [4096..]=nn_b2[i][o]
    __shared__ float stg[4][2][64];
    int t = threadIdx.x;
#pragma unroll
    for (int r = 0; r < 32; ++r) {
        int idx = r * 256 + t;
        CW[idx] = (idx < 4096) ? conv_root[idx] : nn_b2[idx - 4096];
    }
    __syncthreads();
    int wv = t >> 6, lane = t & 63;
    float cb = conv_bias[lane];
    for (int rep = 0; rep < 16; ++rep) {
        int n = blockIdx.x * 64 + wv * 16 + rep;
        float ov = out[(size_t)n * 64 + lane];
        float osv = Osum[(size_t)n * 64 + lane];
        stg[wv][0][lane] = ov; stg[wv][1][lane] = osv;
        float ps = 0.f;
#pragma unroll
        for (int s = 0; s < KSPLIT; ++s) ps += P[((size_t)s * NN + n) * 64 + lane];
        float a1 = 0.f, a2 = 0.f;
#pragma unroll 4
        for (int i4 = 0; i4 < 16; ++i4) {
            float4 o4 = *(const float4*)&stg[wv][0][i4 * 4];
            float4 s4 = *(const float4*)&stg[wv][1][i4 * 4];
            int b0 = (i4 * 4) * 64 + lane;
            a1 += o4.x * CW[b0] + o4.y * CW[b0 + 64] + o4.z * CW[b0 + 128] + o4.w * CW[b0 + 192];
            int b1i = (64 + i4 * 4) * 64 + lane;
            a2 += s4.x * CW[b1i] + s4.y * CW[b1i + 64] + s4.z * CW[b1i + 128] + s4.w * CW[b1i + 192];
        }
        M[(size_t)n * 64 + lane] = fmaxf((ps + a2) / degf[n] + a1 + cb, 0.f);
    }
}

// ---------- GRU gates; out <- h' ----------
__global__ __launch_bounds__(256) void k_gates(
    float* __restrict__ out, const float* __restrict__ M,
    const float* __restrict__ gwT,
    const float* __restrict__ gb_ih, const float* __restrict__ gb_hh) {
    __shared__ float GW[24576];
    __shared__ float stg[4][2][64];
    int t = threadIdx.x;
#pragma unroll
    for (int r = 0; r < 96; ++r) GW[r * 256 + t] = gwT[r * 256 + t];
    __syncthreads();
    int wv = t >> 6, lane = t & 63;
    float bi0 = gb_ih[lane], bi1 = gb_ih[64 + lane], bi2 = gb_ih[128 + lane];
    float bh0 = gb_hh[lane], bh1 = gb_hh[64 + lane], bh2 = gb_hh[128 + lane];
    for (int rep = 0; rep < 16; ++rep) {
        int n = blockIdx.x * 64 + wv * 16 + rep;
        float hv_own = out[(size_t)n * 64 + lane];
        float mv_own = M[(size_t)n * 64 + lane];
        stg[wv][0][lane] = hv_own; stg[wv][1][lane] = mv_own;
        float g0 = 0, g1 = 0, g2 = 0, h0 = 0, h1 = 0, h2 = 0;
#pragma unroll 2
        for (int i4 = 0; i4 < 16; ++i4) {
            float4 m4 = *(const float4*)&stg[wv][1][i4 * 4];
            float4 h4 = *(const float4*)&stg[wv][0][i4 * 4];
            float mv[4] = {m4.x, m4.y, m4.z, m4.w};
            float hh[4] = {h4.x, h4.y, h4.z, h4.w};
#pragma unroll
            for (int c = 0; c < 4; ++c) {
                int base_ = (i4 * 4 + c) * 64 + lane;
                g0 += mv[c] * GW[base_];
                g1 += mv[c] * GW[4096 + base_];
                g2 += mv[c] * GW[8192 + base_];
                h0 += hh[c] * GW[12288 + base_];
                h1 += hh[c] * GW[16384 + base_];
                h2 += hh[c] * GW[20480 + base_];
            }
        }
        float r = sigmoidf_(g0 + h0 + bi0 + bh0);
        float z = sigmoidf_(g1 + h1 + bi1 + bh1);
        float nn_ = tanhf(g2 + bi2 + r * (h2 + bh2));
        out[(size_t)n * 64 + lane] = (1.f - z) * nn_ + z * hv_own;
    }
}

// ---------- Set2Set ----------
__global__ __launch_bounds__(256) void k_lstm(
    const float* __restrict__ q_star, float* __restrict__ hs, float* __restrict__ cs,
    const float* __restrict__ w_ih, const float* __restrict__ w_hh,
    const float* __restrict__ b_ih, const float* __restrict__ b_hh) {
    __shared__ float qs[128], hr[64], gates[256];
    int bg = blockIdx.x, t = threadIdx.x;
    if (t < 128) qs[t] = q_star[bg * 128 + t];
    else if (t < 192) hr[t - 128] = hs[bg * 64 + (t - 128)];
    __syncthreads();
    float s = b_ih[t] + b_hh[t];
    const float4* wi = (const float4*)&w_ih[t * 128];
#pragma unroll
    for (int i = 0; i < 32; ++i) {
        float4 a = wi[i];
        s += qs[i * 4] * a.x + qs[i * 4 + 1] * a.y + qs[i * 4 + 2] * a.z + qs[i * 4 + 3] * a.w;
    }
    const float4* wh = (const float4*)&w_hh[t * 64];
#pragma unroll
    for (int i = 0; i < 16; ++i) {
        float4 a = wh[i];
        s += hr[i * 4] * a.x + hr[i * 4 + 1] * a.y + hr[i * 4 + 2] * a.z + hr[i * 4 + 3] * a.w;
    }
    gates[t] = s;
    __syncthreads();
    if (t < 64) {
        float ig = sigmoidf_(gates[t]);
        float fg = sigmoidf_(gates[64 + t]);
        float gg = tanhf(gates[128 + t]);
        float og = sigmoidf_(gates[192 + t]);
        float c = fg * cs[bg * 64 + t] + ig * gg;
        float hv = og * tanhf(c);
        cs[bg * 64 + t] = c;
        hs[bg * 64 + t] = hv;
    }
}

__global__ void k_attn(const float* __restrict__ out, const int* __restrict__ gstart,
                       const float* __restrict__ hs, float* __restrict__ q_star) {
    int g = blockIdx.x, o = threadIdx.x;
    float q = hs[g * 64 + o];
    int s0 = gstart[g], s1 = gstart[g + 1];
    float mmax = -1e30f;
    for (int i = s0; i < s1; ++i) {
        float p = out[(size_t)i * 64 + o] * q;
#pragma unroll
        for (int off = 32; off >= 1; off >>= 1) p += __shfl_xor(p, off);
        mmax = fmaxf(mmax, p);
    }
    float ssum = 0.f, racc = 0.f;
    for (int i = s0; i < s1; ++i) {
        float ov = out[(size_t)i * 64 + o];
        float p = ov * q;
#pragma unroll
        for (int off = 32; off >= 1; off >>= 1) p += __shfl_xor(p, off);
        float w = expf(p - mmax);
        ssum += w;
        racc += w * ov;
    }
    q_star[g * 128 + o] = q;
    q_star[g * 128 + 64 + o] = (s1 > s0) ? (racc / ssum) : 0.f;
}

__global__ void k_final(const float* __restrict__ q_star, const float* __restrict__ w1,
                        const float* __restrict__ b1, const float* __restrict__ w2,
                        const float* __restrict__ b2, float* __restrict__ yout) {
    __shared__ float qs[128];
    int g = blockIdx.x, t = threadIdx.x;
    qs[t] = q_star[g * 128 + t];
    qs[64 + t] = q_star[g * 128 + 64 + t];
    __syncthreads();
    float s = b1[t];
    const float4* w = (const float4*)&w1[t * 128];
#pragma unroll
    for (int i = 0; i < 32; ++i) {
        float4 a = w[i];
        s += qs[i * 4] * a.x + qs[i * 4 + 1] * a.y + qs[i * 4 + 2] * a.z + qs[i * 4 + 3] * a.w;
    }
    s = fmaxf(s, 0.f) * w2[t];
#pragma unroll
    for (int off = 32; off >= 1; off >>= 1) s += __shfl_xor(s, off);
    if (t == 0) yout[g] = s + b2[0];
}

extern "C" void kernel_launch(void* const* d_in, const int* in_sizes, int n_in,
                              void* d_out, int out_size, void* d_ws, size_t ws_size,
                              hipStream_t stream) {
    (void)in_sizes; (void)n_in; (void)out_size;
    const float* x        = (const float*)d_in[0];
    const float* eattr    = (const float*)d_in[1];
    const int*   ei       = (const int*)d_in[2];
    const int*   batch    = (const int*)d_in[3];
    const float* lin0_w   = (const float*)d_in[4];
    const float* lin0_b   = (const float*)d_in[5];
    const float* nn_w1    = (const float*)d_in[6];
    const float* nn_b1    = (const float*)d_in[7];
    const float* nn_w2    = (const float*)d_in[8];
    const float* nn_b2    = (const float*)d_in[9];
    const float* conv_root= (const float*)d_in[10];
    const float* conv_bias= (const float*)d_in[11];
    const float* gw_ih    = (const float*)d_in[12];
    const float* gw_hh    = (const float*)d_in[13];
    const float* gb_ih    = (const float*)d_in[14];
    const float* gb_hh    = (const float*)d_in[15];
    const float* lw_ih    = (const float*)d_in[16];
    const float* lw_hh    = (const float*)d_in[17];
    const float* lb_ih    = (const float*)d_in[18];
    const float* lb_hh    = (const float*)d_in[19];
    const float* lin1_w   = (const float*)d_in[20];
    const float* lin1_b   = (const float*)d_in[21];
    const float* lin2_w   = (const float*)d_in[22];
    const float* lin2_b   = (const float*)d_in[23];
    const int* src = ei;
    const int* dst = ei + NE;

    char* w = (char*)d_ws;
    auto alloc = [&](size_t bytes) { char* p = w; w += (bytes + 255) & ~(size_t)255; return p; };
    float* out    = (float*)alloc((size_t)NN * 64 * 4);
    float* e_h    = (float*)alloc((size_t)NE * 128 * 4);
    u16*   Whi    = (u16*)alloc((size_t)64 * SK * 2);
    u16*   Wlo    = (u16*)alloc((size_t)64 * SK * 2);
    float* P      = (float*)alloc((size_t)KSPLIT * NN * 64 * 4);
    float* Osum   = (float*)alloc((size_t)NN * 64 * 4);
    float* M      = (float*)alloc((size_t)NN * 64 * 4);
    float* gwT    = (float*)alloc((size_t)6 * 4096 * 4);
    float* degf   = (float*)alloc((size_t)NN * 4);
    int*   degi   = (int*)alloc((size_t)NN * 4);
    int*   rowptr = (int*)alloc((size_t)(NN + 1) * 4);
    int*   cursor = (int*)alloc((size_t)(NN + 1) * 4);
    int*   elist  = (int*)alloc((size_t)NE * 4);
    int*   gstart = (int*)alloc((size_t)(NGB + 1) * 4);
    float* q_star = (float*)alloc((size_t)NGB * 128 * 4);
    float* hs     = (float*)alloc((size_t)NGB * 64 * 4);
    float* cs     = (float*)alloc((size_t)NGB * 64 * 4);
    size_t used = (size_t)(w - (char*)d_ws);
    size_t avail = ws_size > used ? ws_size - used : 0;
    size_t maxrows = avail / ((size_t)SK * 4);
    int chunkN = maxrows > (size_t)NN ? NN : (int)maxrows;
    chunkN = (chunkN / 64) * 64;
    if (chunkN < 64) chunkN = 64;
    u32* S_pk = (u32*)w;

    hipMemsetAsync(degi, 0, (size_t)NN * 4, stream);
    hipMemsetAsync(q_star, 0, (size_t)NGB * 128 * 4, stream);
    hipMemsetAsync(hs, 0, (size_t)NGB * 64 * 4, stream);
    hipMemsetAsync(cs, 0, (size_t)NGB * 64 * 4, stream);

    k_lin0<<<NN, 64, 0, stream>>>(x, lin0_w, lin0_b, out);
    k_eh<<<NE / 2, 256, 0, stream>>>(eattr, nn_w1, nn_b1, e_h);
    k_wsplit<<<(64 * SK) / 256, 256, 0, stream>>>(nn_w2, Whi, Wlo);
    k_prep_gw<<<96, 256, 0, stream>>>(gw_ih, gw_hh, gwT);
    k_deg<<<(NE + 255) / 256, 256, 0, stream>>>(dst, degi);
    k_scan<<<1, 1024, 0, stream>>>(degi, rowptr, cursor, degf);
    k_fill<<<(NE + 255) / 256, 256, 0, stream>>>(dst, cursor, elist);
    k_gstart<<<5, 64, 0, stream>>>(batch, gstart);

    for (int it = 0; it < 3; ++it) {
        for (int cb = 0; cb < NN; cb += chunkN) {
            int cn = (NN - cb) < chunkN ? (NN - cb) : chunkN;
            k_sbuild<<<cn, 256, 0, stream>>>(out, e_h, src, rowptr, elist, S_pk, Osum, cb);
            k_gemm<<<dim3(cn / 64, KSPLIT), 256, 0, stream>>>(S_pk, Whi, Wlo, P, cb);
        }
        k_mrelu<<<NN / 64, 256, 0, stream>>>(out, P, Osum, degf, conv_root, nn_b2, conv_bias, M);
        k_gates<<<NN / 64, 256, 0, stream>>>(out, M, gwT, gb_ih, gb_hh);
    }

    for (int st = 0; st < 3; ++st) {
        k_lstm<<<NGB, 256, 0, stream>>>(q_star, hs, cs, lw_ih, lw_hh, lb_ih, lb_hh);
        k_attn<<<NGB, 64, 0, stream>>>(out, gstart, hs, q_star);
    }
    k_final<<<NGB, 64, 0, stream>>>(q_star, lin1_w, lin1_b, lin2_w, lin2_b, (float*)d_out);
}

// Round 6
// 1106.586 us; speedup vs baseline: 1.3726x; 1.0450x over previous
//
#include <hip/hip_runtime.h>
#include <math.h>

#define NN 8000
#define NE 40000
#define NGB 256
#define SK 8192
#define KSPLIT 8

typedef unsigned int u32;
typedef unsigned short u16;
typedef __attribute__((ext_vector_type(8))) short short8v;
typedef __attribute__((ext_vector_type(4))) float float4v;
typedef __attribute__((ext_vector_type(4))) unsigned int uint4v;

__device__ __forceinline__ float sigmoidf_(float x) { return 1.f / (1.f + expf(-x)); }

// round-to-nearest-even bf16 (as u32 holding the 16-bit pattern)
__device__ __forceinline__ u32 bf16_rne(float f) {
    u32 x = __builtin_bit_cast(u32, f);
    return (x + 0x7FFFu + ((x >> 16) & 1u)) >> 16;
}
__device__ __forceinline__ u32 pack_hl(float v) {
    u32 h = bf16_rne(v);
    float fh = __builtin_bit_cast(float, h << 16);
    u32 l = bf16_rne(v - fh);
    return (h << 16) | (l & 0xFFFFu);
}

// async global->LDS, 16 bytes per lane, linear LDS dest (wave base + lane*16)
__device__ __forceinline__ void gload16(const u32* g, u32* l) {
    __builtin_amdgcn_global_load_lds((const __attribute__((address_space(1))) void*)g,
                                     (__attribute__((address_space(3))) void*)l, 16, 0, 0);
}

// ---------- small setup kernels ----------

__global__ void k_lin0(const float* __restrict__ x, const float* __restrict__ w,
                       const float* __restrict__ b, float* __restrict__ out) {
    __shared__ float xr[21];
    int n = blockIdx.x, t = threadIdx.x;
    if (t < 21) xr[t] = x[n * 21 + t];
    __syncthreads();
    float s = b[t];
#pragma unroll
    for (int c = 0; c < 21; ++c) s += xr[c] * w[t * 21 + c];
    out[n * 64 + t] = fmaxf(s, 0.f);
}

__global__ void k_eh(const float* __restrict__ ea, const float* __restrict__ w1,
                     const float* __restrict__ b1, float* __restrict__ e_h) {
    __shared__ float a[2][16];
    int t = threadIdx.x;
    int e0 = blockIdx.x * 2;
    if (t < 32) a[t >> 4][t & 15] = ea[(e0 + (t >> 4)) * 16 + (t & 15)];
    __syncthreads();
    int sub = t >> 7, j = t & 127;
    float s = b1[j];
#pragma unroll
    for (int c = 0; c < 16; ++c) s += a[sub][c] * w1[j * 16 + c];
    e_h[(size_t)(e0 + sub) * 128 + j] = fmaxf(s, 0.f);
}

// W2T hi/lo: Whi/Wlo[o*SK + (i*128+k)] = split(nn_w2[(i*64+o)*128 + k])
__global__ void k_wsplit(const float* __restrict__ nn_w2, u16* __restrict__ Whi,
                         u16* __restrict__ Wlo) {
    int idx = blockIdx.x * 256 + threadIdx.x;   // [0, 64*8192)
    int o = idx >> 13, kap = idx & 8191;
    int i = kap >> 7, k = kap & 127;
    float v = nn_w2[(size_t)((i << 6) + o) * 128 + k];
    u32 h = bf16_rne(v);
    float fh = __builtin_bit_cast(float, h << 16);
    u32 l = bf16_rne(v - fh);
    Whi[idx] = (u16)h; Wlo[idx] = (u16)l;
}

// transposed GRU weights: gwT[mm*4096 + i*64 + o], mm 0..2 = ih gates, 3..5 = hh gates
__global__ void k_prep_gw(const float* __restrict__ w_ih, const float* __restrict__ w_hh,
                          float* __restrict__ gwT) {
    int tg = blockIdx.x * 256 + threadIdx.x;   // < 24576
    int mm = tg >> 12, rem = tg & 4095;
    int i = rem >> 6, o = rem & 63;
    float v = (mm < 3) ? w_ih[((mm * 64 + o) << 6) + i] : w_hh[(((mm - 3) * 64 + o) << 6) + i];
    gwT[tg] = v;
}

__global__ void k_deg(const int* __restrict__ dst, int* __restrict__ degi) {
    int e = blockIdx.x * blockDim.x + threadIdx.x;
    if (e < NE) atomicAdd(&degi[dst[e]], 1);
}

__global__ void k_scan(const int* __restrict__ degi, int* __restrict__ rowptr,
                       int* __restrict__ cursor, float* __restrict__ degf) {
    __shared__ int lds[1024];
    __shared__ int carry;
    int t = threadIdx.x;
    if (t == 0) carry = 0;
    __syncthreads();
    for (int base = 0; base < NN; base += 1024) {
        int i = base + t;
        int v = (i < NN) ? degi[i] : 0;
        lds[t] = v;
        __syncthreads();
        for (int off = 1; off < 1024; off <<= 1) {
            int add = (t >= off) ? lds[t - off] : 0;
            __syncthreads();
            lds[t] += add;
            __syncthreads();
        }
        if (i < NN) {
            int exc = lds[t] - v + carry;
            rowptr[i] = exc; cursor[i] = exc;
            degf[i] = (float)(v > 1 ? v : 1);
        }
        __syncthreads();
        if (t == 0) carry += lds[1023];
        __syncthreads();
    }
    if (t == 0) rowptr[NN] = carry;
}

__global__ void k_fill(const int* __restrict__ dst, int* __restrict__ cursor,
                       int* __restrict__ elist) {
    int e = blockIdx.x * blockDim.x + threadIdx.x;
    if (e < NE) { int p = atomicAdd(&cursor[dst[e]], 1); elist[p] = e; }
}

__global__ void k_gstart(const int* __restrict__ batch, int* __restrict__ gstart) {
    int g = blockIdx.x * blockDim.x + threadIdx.x;
    if (g > NGB) return;
    int lo = 0, hi = NN;
    while (lo < hi) { int mid = (lo + hi) >> 1; if (batch[mid] < g) lo = mid + 1; else hi = mid; }
    gstart[g] = lo;
}

// ---------- NNConv: S build (rank-1 outer products, packed bf16 hi/lo) ----------
// thread t: i-group ib=t>>5 (8 rows), k-quad kq=t&31 (k=kq*4..+3)
__global__ __launch_bounds__(256) void k_sbuild(
    const float* __restrict__ out, const float* __restrict__ e_h,
    const int* __restrict__ src, const int* __restrict__ rowptr,
    const int* __restrict__ elist, u32* __restrict__ S_pk,
    float* __restrict__ Osum, int base) {
    int t = threadIdx.x;
    int n = base + blockIdx.x;
    int ib = t >> 5;
    int kq = t & 31;
    int lane = t & 63;
    float acc[8][4];
#pragma unroll
    for (int j = 0; j < 8; ++j) { acc[j][0] = 0.f; acc[j][1] = 0.f; acc[j][2] = 0.f; acc[j][3] = 0.f; }
    float osum = 0.f;
    int r0 = rowptr[n], r1 = rowptr[n + 1];
    const float4* out4 = (const float4*)out;
    const float4* eh4p = (const float4*)e_h;
    for (int idx = r0; idx < r1; ++idx) {
        int e = elist[idx];
        int sn = src[e];
        float4 eh = eh4p[(size_t)e * 32 + kq];
        float4 f0 = out4[sn * 16 + ib * 2];
        float4 f1 = out4[sn * 16 + ib * 2 + 1];
        float fv[8] = {f0.x, f0.y, f0.z, f0.w, f1.x, f1.y, f1.z, f1.w};
#pragma unroll
        for (int j = 0; j < 8; ++j) {
            acc[j][0] += fv[j] * eh.x; acc[j][1] += fv[j] * eh.y;
            acc[j][2] += fv[j] * eh.z; acc[j][3] += fv[j] * eh.w;
        }
        if (t < 64) osum += out[(size_t)sn * 64 + lane];
    }
    size_t rb4 = (size_t)blockIdx.x * (SK / 4);
    uint4v* S4 = (uint4v*)S_pk;
#pragma unroll
    for (int j = 0; j < 8; ++j) {
        uint4v v = { pack_hl(acc[j][0]), pack_hl(acc[j][1]), pack_hl(acc[j][2]), pack_hl(acc[j][3]) };
        S4[rb4 + (size_t)(ib * 8 + j) * 32 + kq] = v;
    }
    if (t < 64) Osum[(size_t)n * 64 + lane] = osum;
}

// ---------- NNConv: MFMA GEMM, bf16x3, LDS-staged A with global_load_lds dbuf ----------
// block: 4 waves, M-tile 64 rows, K-step 64 u32-kappa, 16 steps per ks-split
__global__ __launch_bounds__(256) void k_gemm(
    const u32* __restrict__ S_pk, const u16* __restrict__ Whi,
    const u16* __restrict__ Wlo, float* __restrict__ P, int base) {
    __shared__ __align__(16) u32 Abuf[2][4096];   // [dbuf][64 rows x 64 kappa]
    int t = threadIdx.x;
    int wv = t >> 6, lane = t & 63;
    int lrow = lane & 15, lkg = lane >> 4;
    int ks = blockIdx.y;
    int kbase = ks * 1024;                  // u32-kappa base within a row
    int mloc0 = blockIdx.x * 64;            // local chunk row of this tile
    // staging address for this thread (row mloc0 + j*16 + t>>4, 16B chunk t&15)
    const u32* sbase = S_pk + (size_t)(mloc0 + (t >> 4)) * SK + kbase + (t & 15) * 4;
    float4v acc[4];
#pragma unroll
    for (int nt = 0; nt < 4; ++nt) acc[nt] = (float4v){0.f, 0.f, 0.f, 0.f};
    const short8v* bhv = (const short8v*)Whi;
    const short8v* blv = (const short8v*)Wlo;
    int bidx = lrow * 1024 + (kbase >> 3) + lkg;   // +nt*16384, +step*8, +kk*4

#pragma unroll
    for (int j = 0; j < 4; ++j)
        gload16(sbase + (size_t)j * 16 * SK, &Abuf[0][(j * 256 + t) * 4]);
    __syncthreads();   // drain: Abuf[0] ready

    for (int step = 0; step < 16; ++step) {
        int cur = step & 1;
        if (step < 15) {
            const u32* sn = sbase + (step + 1) * 64;
#pragma unroll
            for (int j = 0; j < 4; ++j)
                gload16(sn + (size_t)j * 16 * SK, &Abuf[cur ^ 1][(j * 256 + t) * 4]);
        }
#pragma unroll
        for (int kk = 0; kk < 2; ++kk) {
            const uint4v* ap = (const uint4v*)&Abuf[cur][(wv * 16 + lrow) * 64 + kk * 32 + lkg * 8];
            uint4v a0 = ap[0], a1 = ap[1];
            uint4v hset = { (a0.x >> 16) | (a0.y & 0xFFFF0000u),
                            (a0.z >> 16) | (a0.w & 0xFFFF0000u),
                            (a1.x >> 16) | (a1.y & 0xFFFF0000u),
                            (a1.z >> 16) | (a1.w & 0xFFFF0000u) };
            uint4v lset = { (a0.x & 0xFFFFu) | (a0.y << 16),
                            (a0.z & 0xFFFFu) | (a0.w << 16),
                            (a1.x & 0xFFFFu) | (a1.y << 16),
                            (a1.z & 0xFFFFu) | (a1.w << 16) };
            short8v ah = __builtin_bit_cast(short8v, hset);
            short8v al = __builtin_bit_cast(short8v, lset);
            int bo = bidx + step * 8 + kk * 4;
#pragma unroll
            for (int nt = 0; nt < 4; ++nt) {
                short8v bh = bhv[bo + nt * 16384];
                short8v bl = blv[bo + nt * 16384];
                acc[nt] = __builtin_amdgcn_mfma_f32_16x16x32_bf16(ah, bh, acc[nt], 0, 0, 0);
                acc[nt] = __builtin_amdgcn_mfma_f32_16x16x32_bf16(al, bh, acc[nt], 0, 0, 0);
                acc[nt] = __builtin_amdgcn_mfma_f32_16x16x32_bf16(ah, bl, acc[nt], 0, 0, 0);
            }
        }
        __syncthreads();   // readers done with Abuf[cur]; prefetch into Abuf[cur^1] drained
    }
    int gnode_base = base + blockIdx.x * 64 + wv * 16;
#pragma unroll
    for (int nt = 0; nt < 4; ++nt) {
#pragma unroll
        for (int jj = 0; jj < 4; ++jj) {
            int row = lkg * 4 + jj;          // C/D: row=(lane>>4)*4+reg  [m89 verified]
            int o = nt * 16 + lrow;          //      col=lane&15
            P[((size_t)ks * NN + gnode_base + row) * 64 + o] = acc[nt][jj];
        }
    }
}

// ---------- m = relu((Psum + Osum@nn_b2)/deg + out@conv_root + cb) ----------
__global__ __launch_bounds__(256) void k_mrelu(
    const float* __restrict__ out, const float* __restrict__ P,
    const float* __restrict__ Osum, const float* __restrict__ degf,
    const float* __restrict__ conv_root, const float* __restrict__ nn_b2,
    const float* __restrict__ conv_bias, float* __restrict__ M) {
    __shared__ float CW[8192];          // [0..4095]=conv_root[i][o], [4096..]=nn_b2[i][o]
    __shared__ float stg[4][2][64];
    int t = threadIdx.x;
#pragma unroll
    for (int r = 0; r < 32; ++r) {
        int idx = r * 256 + t;
        CW[idx] = (idx < 4096) ? conv_root[idx] : nn_b2[idx - 4096];
    }
    __syncthreads();
    int wv = t >> 6, lane = t & 63;
    float cb = conv_bias[lane];
    for (int rep = 0; rep < 16; ++rep) {
        int n = blockIdx.x * 64 + wv * 16 + rep;
        float ov = out[(size_t)n * 64 + lane];
        float osv = Osum[(size_t)n * 64 + lane];
        stg[wv][0][lane] = ov; stg[wv][1][lane] = osv;
        float ps = 0.f;
#pragma unroll
        for (int s = 0; s < KSPLIT; ++s) ps += P[((size_t)s * NN + n) * 64 + lane];
        float a1 = 0.f, a2 = 0.f;
#pragma unroll 4
        for (int i4 = 0; i4 < 16; ++i4) {
            float4 o4 = *(const float4*)&stg[wv][0][i4 * 4];
            float4 s4 = *(const float4*)&stg[wv][1][i4 * 4];
            int b0 = (i4 * 4) * 64 + lane;
            a1 += o4.x * CW[b0] + o4.y * CW[b0 + 64] + o4.z * CW[b0 + 128] + o4.w * CW[b0 + 192];
            int b1i = (64 + i4 * 4) * 64 + lane;
            a2 += s4.x * CW[b1i] + s4.y * CW[b1i + 64] + s4.z * CW[b1i + 128] + s4.w * CW[b1i + 192];
        }
        M[(size_t)n * 64 + lane] = fmaxf((ps + a2) / degf[n] + a1 + cb, 0.f);
    }
}

// ---------- GRU gates; out <- h' ----------
__global__ __launch_bounds__(256) void k_gates(
    float* __restrict__ out, const float* __restrict__ M,
    const float* __restrict__ gwT,
    const float* __restrict__ gb_ih, const float* __restrict__ gb_hh) {
    __shared__ float GW[24576];
    __shared__ float stg[4][2][64];
    int t = threadIdx.x;
#pragma unroll
    for (int r = 0; r < 96; ++r) GW[r * 256 + t] = gwT[r * 256 + t];
    __syncthreads();
    int wv = t >> 6, lane = t & 63;
    float bi0 = gb_ih[lane], bi1 = gb_ih[64 + lane], bi2 = gb_ih[128 + lane];
    float bh0 = gb_hh[lane], bh1 = gb_hh[64 + lane], bh2 = gb_hh[128 + lane];
    for (int rep = 0; rep < 16; ++rep) {
        int n = blockIdx.x * 64 + wv * 16 + rep;
        float hv_own = out[(size_t)n * 64 + lane];
        float mv_own = M[(size_t)n * 64 + lane];
        stg[wv][0][lane] = hv_own; stg[wv][1][lane] = mv_own;
        float g0 = 0, g1 = 0, g2 = 0, h0 = 0, h1 = 0, h2 = 0;
#pragma unroll 2
        for (int i4 = 0; i4 < 16; ++i4) {
            float4 m4 = *(const float4*)&stg[wv][1][i4 * 4];
            float4 h4 = *(const float4*)&stg[wv][0][i4 * 4];
            float mv[4] = {m4.x, m4.y, m4.z, m4.w};
            float hh[4] = {h4.x, h4.y, h4.z, h4.w};
#pragma unroll
            for (int c = 0; c < 4; ++c) {
                int base_ = (i4 * 4 + c) * 64 + lane;
                g0 += mv[c] * GW[base_];
                g1 += mv[c] * GW[4096 + base_];
                g2 += mv[c] * GW[8192 + base_];
                h0 += hh[c] * GW[12288 + base_];
                h1 += hh[c] * GW[16384 + base_];
                h2 += hh[c] * GW[20480 + base_];
            }
        }
        float r = sigmoidf_(g0 + h0 + bi0 + bh0);
        float z = sigmoidf_(g1 + h1 + bi1 + bh1);
        float nn_ = tanhf(g2 + bi2 + r * (h2 + bh2));
        out[(size_t)n * 64 + lane] = (1.f - z) * nn_ + z * hv_own;
    }
}

// ---------- Set2Set ----------
__global__ __launch_bounds__(256) void k_lstm(
    const float* __restrict__ q_star, float* __restrict__ hs, float* __restrict__ cs,
    const float* __restrict__ w_ih, const float* __restrict__ w_hh,
    const float* __restrict__ b_ih, const float* __restrict__ b_hh) {
    __shared__ float qs[128], hr[64], gates[256];
    int bg = blockIdx.x, t = threadIdx.x;
    if (t < 128) qs[t] = q_star[bg * 128 + t];
    else if (t < 192) hr[t - 128] = hs[bg * 64 + (t - 128)];
    __syncthreads();
    float s = b_ih[t] + b_hh[t];
    const float4* wi = (const float4*)&w_ih[t * 128];
#pragma unroll
    for (int i = 0; i < 32; ++i) {
        float4 a = wi[i];
        s += qs[i * 4] * a.x + qs[i * 4 + 1] * a.y + qs[i * 4 + 2] * a.z + qs[i * 4 + 3] * a.w;
    }
    const float4* wh = (const float4*)&w_hh[t * 64];
#pragma unroll
    for (int i = 0; i < 16; ++i) {
        float4 a = wh[i];
        s += hr[i * 4] * a.x + hr[i * 4 + 1] * a.y + hr[i * 4 + 2] * a.z + hr[i * 4 + 3] * a.w;
    }
    gates[t] = s;
    __syncthreads();
    if (t < 64) {
        float ig = sigmoidf_(gates[t]);
        float fg = sigmoidf_(gates[64 + t]);
        float gg = tanhf(gates[128 + t]);
        float og = sigmoidf_(gates[192 + t]);
        float c = fg * cs[bg * 64 + t] + ig * gg;
        float hv = og * tanhf(c);
        cs[bg * 64 + t] = c;
        hs[bg * 64 + t] = hv;
    }
}

__global__ void k_attn(const float* __restrict__ out, const int* __restrict__ gstart,
                       const float* __restrict__ hs, float* __restrict__ q_star) {
    int g = blockIdx.x, o = threadIdx.x;
    float q = hs[g * 64 + o];
    int s0 = gstart[g], s1 = gstart[g + 1];
    float mmax = -1e30f;
    for (int i = s0; i < s1; ++i) {
        float p = out[(size_t)i * 64 + o] * q;
#pragma unroll
        for (int off = 32; off >= 1; off >>= 1) p += __shfl_xor(p, off);
        mmax = fmaxf(mmax, p);
    }
    float ssum = 0.f, racc = 0.f;
    for (int i = s0; i < s1; ++i) {
        float ov = out[(size_t)i * 64 + o];
        float p = ov * q;
#pragma unroll
        for (int off = 32; off >= 1; off >>= 1) p += __shfl_xor(p, off);
        float w = expf(p - mmax);
        ssum += w;
        racc += w * ov;
    }
    q_star[g * 128 + o] = q;
    q_star[g * 128 + 64 + o] = (s1 > s0) ? (racc / ssum) : 0.f;
}

__global__ void k_final(const float* __restrict__ q_star, const float* __restrict__ w1,
                        const float* __restrict__ b1, const float* __restrict__ w2,
                        const float* __restrict__ b2, float* __restrict__ yout) {
    __shared__ float qs[128];
    int g = blockIdx.x, t = threadIdx.x;
    qs[t] = q_star[g * 128 + t];
    qs[64 + t] = q_star[g * 128 + 64 + t];
    __syncthreads();
    float s = b1[t];
    const float4* w = (const float4*)&w1[t * 128];
#pragma unroll
    for (int i = 0; i < 32; ++i) {
        float4 a = w[i];
        s += qs[i * 4] * a.x + qs[i * 4 + 1] * a.y + qs[i * 4 + 2] * a.z + qs[i * 4 + 3] * a.w;
    }
    s = fmaxf(s, 0.f) * w2[t];
#pragma unroll
    for (int off = 32; off >= 1; off >>= 1) s += __shfl_xor(s, off);
    if (t == 0) yout[g] = s + b2[0];
}

extern "C" void kernel_launch(void* const* d_in, const int* in_sizes, int n_in,
                              void* d_out, int out_size, void* d_ws, size_t ws_size,
                              hipStream_t stream) {
    (void)in_sizes; (void)n_in; (void)out_size;
    const float* x        = (const float*)d_in[0];
    const float* eattr    = (const float*)d_in[1];
    const int*   ei       = (const int*)d_in[2];
    const int*   batch    = (const int*)d_in[3];
    const float* lin0_w   = (const float*)d_in[4];
    const float* lin0_b   = (const float*)d_in[5];
    const float* nn_w1    = (const float*)d_in[6];
    const float* nn_b1    = (const float*)d_in[7];
    const float* nn_w2    = (const float*)d_in[8];
    const float* nn_b2    = (const float*)d_in[9];
    const float* conv_root= (const float*)d_in[10];
    const float* conv_bias= (const float*)d_in[11];
    const float* gw_ih    = (const float*)d_in[12];
    const float* gw_hh    = (const float*)d_in[13];
    const float* gb_ih    = (const float*)d_in[14];
    const float* gb_hh    = (const float*)d_in[15];
    const float* lw_ih    = (const float*)d_in[16];
    const float* lw_hh    = (const float*)d_in[17];
    const float* lb_ih    = (const float*)d_in[18];
    const float* lb_hh    = (const float*)d_in[19];
    const float* lin1_w   = (const float*)d_in[20];
    const float* lin1_b   = (const float*)d_in[21];
    const float* lin2_w   = (const float*)d_in[22];
    const float* lin2_b   = (const float*)d_in[23];
    const int* src = ei;
    const int* dst = ei + NE;

    char* w = (char*)d_ws;
    auto alloc = [&](size_t bytes) { char* p = w; w += (bytes + 255) & ~(size_t)255; return p; };
    float* out    = (float*)alloc((size_t)NN * 64 * 4);
    float* e_h    = (float*)alloc((size_t)NE * 128 * 4);
    u16*   Whi    = (u16*)alloc((size_t)64 * SK * 2);
    u16*   Wlo    = (u16*)alloc((size_t)64 * SK * 2);
    float* P      = (float*)alloc((size_t)KSPLIT * NN * 64 * 4);
    float* Osum   = (float*)alloc((size_t)NN * 64 * 4);
    float* M      = (float*)alloc((size_t)NN * 64 * 4);
    float* gwT    = (float*)alloc((size_t)6 * 4096 * 4);
    float* degf   = (float*)alloc((size_t)NN * 4);
    int*   degi   = (int*)alloc((size_t)NN * 4);
    int*   rowptr = (int*)alloc((size_t)(NN + 1) * 4);
    int*   cursor = (int*)alloc((size_t)(NN + 1) * 4);
    int*   elist  = (int*)alloc((size_t)NE * 4);
    int*   gstart = (int*)alloc((size_t)(NGB + 1) * 4);
    float* q_star = (float*)alloc((size_t)NGB * 128 * 4);
    float* hs     = (float*)alloc((size_t)NGB * 64 * 4);
    float* cs     = (float*)alloc((size_t)NGB * 64 * 4);
    size_t used = (size_t)(w - (char*)d_ws);
    size_t avail = ws_size > used ? ws_size - used : 0;
    size_t maxrows = avail / ((size_t)SK * 4);
    int chunkN = maxrows > (size_t)NN ? NN : (int)maxrows;
    chunkN = (chunkN / 64) * 64;
    if (chunkN < 64) chunkN = 64;
    u32* S_pk = (u32*)w;

    hipMemsetAsync(degi, 0, (size_t)NN * 4, stream);
    hipMemsetAsync(q_star, 0, (size_t)NGB * 128 * 4, stream);
    hipMemsetAsync(hs, 0, (size_t)NGB * 64 * 4, stream);
    hipMemsetAsync(cs, 0, (size_t)NGB * 64 * 4, stream);

    k_lin0<<<NN, 64, 0, stream>>>(x, lin0_w, lin0_b, out);
    k_eh<<<NE / 2, 256, 0, stream>>>(eattr, nn_w1, nn_b1, e_h);
    k_wsplit<<<(64 * SK) / 256, 256, 0, stream>>>(nn_w2, Whi, Wlo);
    k_prep_gw<<<96, 256, 0, stream>>>(gw_ih, gw_hh, gwT);
    k_deg<<<(NE + 255) / 256, 256, 0, stream>>>(dst, degi);
    k_scan<<<1, 1024, 0, stream>>>(degi, rowptr, cursor, degf);
    k_fill<<<(NE + 255) / 256, 256, 0, stream>>>(dst, cursor, elist);
    k_gstart<<<5, 64, 0, stream>>>(batch, gstart);

    for (int it = 0; it < 3; ++it) {
        for (int cb = 0; cb < NN; cb += chunkN) {
            int cn = (NN - cb) < chunkN ? (NN - cb) : chunkN;
            k_sbuild<<<cn, 256, 0, stream>>>(out, e_h, src, rowptr, elist, S_pk, Osum, cb);
            k_gemm<<<dim3(cn / 64, KSPLIT), 256, 0, stream>>>(S_pk, Whi, Wlo, P, cb);
        }
        k_mrelu<<<NN / 64, 256, 0, stream>>>(out, P, Osum, degf, conv_root, nn_b2, conv_bias, M);
        k_gates<<<NN / 64, 256, 0, stream>>>(out, M, gwT, gb_ih, gb_hh);
    }

    for (int st = 0; st < 3; ++st) {
        k_lstm<<<NGB, 256, 0, stream>>>(q_star, hs, cs, lw_ih, lw_hh, lb_ih, lb_hh);
        k_attn<<<NGB, 64, 0, stream>>>(out, gstart, hs, q_star);
    }
    k_final<<<NGB, 64, 0, stream>>>(q_star, lin1_w, lin1_b, lin2_w, lin2_b, (float*)d_out);
}

// Round 7
// 813.384 us; speedup vs baseline: 1.8674x; 1.3605x over previous
//
#include <hip/hip_runtime.h>
#include <math.h>

#define NN 8000
#define NE 40000
#define NGB 256
#define SK 8192
#define KSPLIT 16

typedef unsigned int u32;
typedef unsigned short u16;
typedef __attribute__((ext_vector_type(8))) short short8v;
typedef __attribute__((ext_vector_type(4))) float float4v;
typedef __attribute__((ext_vector_type(4))) unsigned int uint4v;

__device__ __forceinline__ float sigmoidf_(float x) { return 1.f / (1.f + expf(-x)); }

// round-to-nearest-even bf16 (as u32 holding the 16-bit pattern)
__device__ __forceinline__ u32 bf16_rne(float f) {
    u32 x = __builtin_bit_cast(u32, f);
    return (x + 0x7FFFu + ((x >> 16) & 1u)) >> 16;
}
__device__ __forceinline__ u32 pack_hl(float v) {
    u32 h = bf16_rne(v);
    float fh = __builtin_bit_cast(float, h << 16);
    u32 l = bf16_rne(v - fh);
    return (h << 16) | (l & 0xFFFFu);
}

// unpack 8 packed (hi<<16|lo) kappa-u32 into hi-bf16x8 and lo-bf16x8 fragments
__device__ __forceinline__ void unpack_hl(uint4v p0, uint4v p1, short8v& ah, short8v& al) {
    uint4v hset = { (p0.x >> 16) | (p0.y & 0xFFFF0000u),
                    (p0.z >> 16) | (p0.w & 0xFFFF0000u),
                    (p1.x >> 16) | (p1.y & 0xFFFF0000u),
                    (p1.z >> 16) | (p1.w & 0xFFFF0000u) };
    uint4v lset = { (p0.x & 0xFFFFu) | (p0.y << 16),
                    (p0.z & 0xFFFFu) | (p0.w << 16),
                    (p1.x & 0xFFFFu) | (p1.y << 16),
                    (p1.z & 0xFFFFu) | (p1.w << 16) };
    ah = __builtin_bit_cast(short8v, hset);
    al = __builtin_bit_cast(short8v, lset);
}

// ---------- small setup kernels ----------

__global__ void k_lin0(const float* __restrict__ x, const float* __restrict__ w,
                       const float* __restrict__ b, float* __restrict__ out) {
    __shared__ float xr[21];
    int n = blockIdx.x, t = threadIdx.x;
    if (t < 21) xr[t] = x[n * 21 + t];
    __syncthreads();
    float s = b[t];
#pragma unroll
    for (int c = 0; c < 21; ++c) s += xr[c] * w[t * 21 + c];
    out[n * 64 + t] = fmaxf(s, 0.f);
}

__global__ void k_eh(const float* __restrict__ ea, const float* __restrict__ w1,
                     const float* __restrict__ b1, float* __restrict__ e_h) {
    __shared__ float a[2][16];
    int t = threadIdx.x;
    int e0 = blockIdx.x * 2;
    if (t < 32) a[t >> 4][t & 15] = ea[(e0 + (t >> 4)) * 16 + (t & 15)];
    __syncthreads();
    int sub = t >> 7, j = t & 127;
    float s = b1[j];
#pragma unroll
    for (int c = 0; c < 16; ++c) s += a[sub][c] * w1[j * 16 + c];
    e_h[(size_t)(e0 + sub) * 128 + j] = fmaxf(s, 0.f);
}

// W2T hi/lo in kchunk-major coalesced layout:
//   pos = ((kap>>3)*64 + o)*8 + (kap&7)   holds split of nn_w2[(i*64+o)*128 + k], kap=i*128+k
__global__ void k_wsplit(const float* __restrict__ nn_w2, u16* __restrict__ Whi,
                         u16* __restrict__ Wlo) {
    int idx = blockIdx.x * 256 + threadIdx.x;   // [0, 64*8192)
    int o = idx >> 13, kap = idx & 8191;
    int i = kap >> 7, k = kap & 127;
    float v = nn_w2[(size_t)((i << 6) + o) * 128 + k];
    u32 h = bf16_rne(v);
    float fh = __builtin_bit_cast(float, h << 16);
    u32 l = bf16_rne(v - fh);
    int pos = ((kap >> 3) * 64 + o) * 8 + (kap & 7);
    Whi[pos] = (u16)h; Wlo[pos] = (u16)l;
}

// transposed GRU weights: gwT[mm*4096 + i*64 + o], mm 0..2 = ih gates, 3..5 = hh gates
__global__ void k_prep_gw(const float* __restrict__ w_ih, const float* __restrict__ w_hh,
                          float* __restrict__ gwT) {
    int tg = blockIdx.x * 256 + threadIdx.x;   // < 24576
    int mm = tg >> 12, rem = tg & 4095;
    int i = rem >> 6, o = rem & 63;
    float v = (mm < 3) ? w_ih[((mm * 64 + o) << 6) + i] : w_hh[(((mm - 3) * 64 + o) << 6) + i];
    gwT[tg] = v;
}

__global__ void k_deg(const int* __restrict__ dst, int* __restrict__ degi) {
    int e = blockIdx.x * blockDim.x + threadIdx.x;
    if (e < NE) atomicAdd(&degi[dst[e]], 1);
}

__global__ void k_scan(const int* __restrict__ degi, int* __restrict__ rowptr,
                       int* __restrict__ cursor, float* __restrict__ degf) {
    __shared__ int lds[1024];
    __shared__ int carry;
    int t = threadIdx.x;
    if (t == 0) carry = 0;
    __syncthreads();
    for (int base = 0; base < NN; base += 1024) {
        int i = base + t;
        int v = (i < NN) ? degi[i] : 0;
        lds[t] = v;
        __syncthreads();
        for (int off = 1; off < 1024; off <<= 1) {
            int add = (t >= off) ? lds[t - off] : 0;
            __syncthreads();
            lds[t] += add;
            __syncthreads();
        }
        if (i < NN) {
            int exc = lds[t] - v + carry;
            rowptr[i] = exc; cursor[i] = exc;
            degf[i] = (float)(v > 1 ? v : 1);
        }
        __syncthreads();
        if (t == 0) carry += lds[1023];
        __syncthreads();
    }
    if (t == 0) rowptr[NN] = carry;
}

__global__ void k_fill(const int* __restrict__ dst, int* __restrict__ cursor,
                       int* __restrict__ elist) {
    int e = blockIdx.x * blockDim.x + threadIdx.x;
    if (e < NE) { int p = atomicAdd(&cursor[dst[e]], 1); elist[p] = e; }
}

__global__ void k_gstart(const int* __restrict__ batch, int* __restrict__ gstart) {
    int g = blockIdx.x * blockDim.x + threadIdx.x;
    if (g > NGB) return;
    int lo = 0, hi = NN;
    while (lo < hi) { int mid = (lo + hi) >> 1; if (batch[mid] < g) lo = mid + 1; else hi = mid; }
    gstart[g] = lo;
}

// ---------- NNConv: S build (rank-1 outer products, packed bf16 hi/lo) ----------
// thread t: i-group ib=t>>5 (8 rows), k-quad kq=t&31 (k=kq*4..+3)
__global__ __launch_bounds__(256) void k_sbuild(
    const float* __restrict__ out, const float* __restrict__ e_h,
    const int* __restrict__ src, const int* __restrict__ rowptr,
    const int* __restrict__ elist, u32* __restrict__ S_pk,
    float* __restrict__ Osum, int base) {
    int t = threadIdx.x;
    int n = base + blockIdx.x;
    int ib = t >> 5;
    int kq = t & 31;
    int lane = t & 63;
    float acc[8][4];
#pragma unroll
    for (int j = 0; j < 8; ++j) { acc[j][0] = 0.f; acc[j][1] = 0.f; acc[j][2] = 0.f; acc[j][3] = 0.f; }
    float osum = 0.f;
    int r0 = rowptr[n], r1 = rowptr[n + 1];
    const float4* out4 = (const float4*)out;
    const float4* eh4p = (const float4*)e_h;
    for (int idx = r0; idx < r1; ++idx) {
        int e = elist[idx];
        int sn = src[e];
        float4 eh = eh4p[(size_t)e * 32 + kq];
        float4 f0 = out4[sn * 16 + ib * 2];
        float4 f1 = out4[sn * 16 + ib * 2 + 1];
        float fv[8] = {f0.x, f0.y, f0.z, f0.w, f1.x, f1.y, f1.z, f1.w};
#pragma unroll
        for (int j = 0; j < 8; ++j) {
            acc[j][0] += fv[j] * eh.x; acc[j][1] += fv[j] * eh.y;
            acc[j][2] += fv[j] * eh.z; acc[j][3] += fv[j] * eh.w;
        }
        if (t < 64) osum += out[(size_t)sn * 64 + lane];
    }
    size_t rb4 = (size_t)blockIdx.x * (SK / 4);
    uint4v* S4 = (uint4v*)S_pk;
#pragma unroll
    for (int j = 0; j < 8; ++j) {
        uint4v v = { pack_hl(acc[j][0]), pack_hl(acc[j][1]), pack_hl(acc[j][2]), pack_hl(acc[j][3]) };
        S4[rb4 + (size_t)(ib * 8 + j) * 32 + kq] = v;
    }
    if (t < 64) Osum[(size_t)n * 64 + lane] = osum;
}

// ---------- NNConv: MFMA GEMM, bf16x3. 1 wave/block, M=32/wave, no LDS/barriers ----------
__global__ __launch_bounds__(64) void k_gemm(
    const u32* __restrict__ S_pk, const u16* __restrict__ Whi,
    const u16* __restrict__ Wlo, float* __restrict__ P, int base) {
    int lane = threadIdx.x;
    int lrow = lane & 15, lkg = lane >> 4;
    int m0 = blockIdx.x * 32;               // local chunk row base
    int ks = blockIdx.y;
    int kbase = ks * (SK / KSPLIT);         // 512 u32-kappa per split
    float4v acc[2][4];
#pragma unroll
    for (int ms = 0; ms < 2; ++ms)
#pragma unroll
        for (int nt = 0; nt < 4; ++nt) acc[ms][nt] = (float4v){0.f, 0.f, 0.f, 0.f};
    const short8v* bhv = (const short8v*)Whi;
    const short8v* blv = (const short8v*)Wlo;
    const u32* ar0 = S_pk + (size_t)(m0 + lrow) * SK + kbase + lkg * 8;
    const u32* ar1 = ar0 + (size_t)16 * SK;
    int kc0 = (kbase >> 3) + lkg;           // kchunk index (8 kappa per chunk)

#pragma unroll 2
    for (int kk = 0; kk < SK / KSPLIT / 32; ++kk) {    // 16 iterations, K=32 each
        uint4v a00 = *(const uint4v*)(ar0 + kk * 32);
        uint4v a01 = *(const uint4v*)(ar0 + kk * 32 + 4);
        uint4v a10 = *(const uint4v*)(ar1 + kk * 32);
        uint4v a11 = *(const uint4v*)(ar1 + kk * 32 + 4);
        int bo = (kc0 + kk * 4) * 64 + lrow;            // short8v index, coalesced in lrow
        short8v bh[4], bl[4];
#pragma unroll
        for (int nt = 0; nt < 4; ++nt) { bh[nt] = bhv[bo + nt * 16]; bl[nt] = blv[bo + nt * 16]; }
        short8v ah0, al0, ah1, al1;
        unpack_hl(a00, a01, ah0, al0);
        unpack_hl(a10, a11, ah1, al1);
#pragma unroll
        for (int nt = 0; nt < 4; ++nt) {
            acc[0][nt] = __builtin_amdgcn_mfma_f32_16x16x32_bf16(ah0, bh[nt], acc[0][nt], 0, 0, 0);
            acc[0][nt] = __builtin_amdgcn_mfma_f32_16x16x32_bf16(al0, bh[nt], acc[0][nt], 0, 0, 0);
            acc[0][nt] = __builtin_amdgcn_mfma_f32_16x16x32_bf16(ah0, bl[nt], acc[0][nt], 0, 0, 0);
            acc[1][nt] = __builtin_amdgcn_mfma_f32_16x16x32_bf16(ah1, bh[nt], acc[1][nt], 0, 0, 0);
            acc[1][nt] = __builtin_amdgcn_mfma_f32_16x16x32_bf16(al1, bh[nt], acc[1][nt], 0, 0, 0);
            acc[1][nt] = __builtin_amdgcn_mfma_f32_16x16x32_bf16(ah1, bl[nt], acc[1][nt], 0, 0, 0);
        }
    }
    int gbase = base + m0;
#pragma unroll
    for (int ms = 0; ms < 2; ++ms)
#pragma unroll
        for (int nt = 0; nt < 4; ++nt)
#pragma unroll
            for (int jj = 0; jj < 4; ++jj) {
                int row = ms * 16 + lkg * 4 + jj;   // C/D: row=(lane>>4)*4+reg  [m89 verified]
                int o = nt * 16 + lrow;             //      col=lane&15
                P[((size_t)ks * NN + gbase + row) * 64 + o] = acc[ms][nt][jj];
            }
}

// ---------- m = relu((Psum + Osum@nn_b2)/deg + out@conv_root + cb) ----------
__global__ __launch_bounds__(256) void k_mrelu(
    const float* __restrict__ out, const float* __restrict__ P,
    const float* __restrict__ Osum, const float* __restrict__ degf,
    const float* __restrict__ conv_root, const float* __restrict__ nn_b2,
    const float* __restrict__ conv_bias, float* __restrict__ M) {
    __shared__ float CW[8192];          // [0..4095]=conv_root[i][o], [4096..]=nn_b2[i][o]
    __shared__ float stg[4][2][64];
    int t = threadIdx.x;
#pragma unroll
    for (int r = 0; r < 32; ++r) {
        int idx = r * 256 + t;
        CW[idx] = (idx < 4096) ? conv_root[idx] : nn_b2[idx - 4096];
    }
    __syncthreads();
    int wv = t >> 6, lane = t & 63;
    float cb = conv_bias[lane];
    for (int rep = 0; rep < 16; ++rep) {
        int n = blockIdx.x * 64 + wv * 16 + rep;
        float ov = out[(size_t)n * 64 + lane];
        float osv = Osum[(size_t)n * 64 + lane];
        stg[wv][0][lane] = ov; stg[wv][1][lane] = osv;
        float ps = 0.f;
#pragma unroll
        for (int s = 0; s < KSPLIT; ++s) ps += P[((size_t)s * NN + n) * 64 + lane];
        float a1 = 0.f, a2 = 0.f;
#pragma unroll 4
        for (int i4 = 0; i4 < 16; ++i4) {
            float4 o4 = *(const float4*)&stg[wv][0][i4 * 4];
            float4 s4 = *(const float4*)&stg[wv][1][i4 * 4];
            int b0 = (i4 * 4) * 64 + lane;
            a1 += o4.x * CW[b0] + o4.y * CW[b0 + 64] + o4.z * CW[b0 + 128] + o4.w * CW[b0 + 192];
            int b1i = (64 + i4 * 4) * 64 + lane;
            a2 += s4.x * CW[b1i] + s4.y * CW[b1i + 64] + s4.z * CW[b1i + 128] + s4.w * CW[b1i + 192];
        }
        M[(size_t)n * 64 + lane] = fmaxf((ps + a2) / degf[n] + a1 + cb, 0.f);
    }
}

// ---------- GRU gates; out <- h' ----------
__global__ __launch_bounds__(256) void k_gates(
    float* __restrict__ out, const float* __restrict__ M,
    const float* __restrict__ gwT,
    const float* __restrict__ gb_ih, const float* __restrict__ gb_hh) {
    __shared__ float GW[24576];
    __shared__ float stg[4][2][64];
    int t = threadIdx.x;
#pragma unroll
    for (int r = 0; r < 96; ++r) GW[r * 256 + t] = gwT[r * 256 + t];
    __syncthreads();
    int wv = t >> 6, lane = t & 63;
    float bi0 = gb_ih[lane], bi1 = gb_ih[64 + lane], bi2 = gb_ih[128 + lane];
    float bh0 = gb_hh[lane], bh1 = gb_hh[64 + lane], bh2 = gb_hh[128 + lane];
    for (int rep = 0; rep < 16; ++rep) {
        int n = blockIdx.x * 64 + wv * 16 + rep;
        float hv_own = out[(size_t)n * 64 + lane];
        float mv_own = M[(size_t)n * 64 + lane];
        stg[wv][0][lane] = hv_own; stg[wv][1][lane] = mv_own;
        float g0 = 0, g1 = 0, g2 = 0, h0 = 0, h1 = 0, h2 = 0;
#pragma unroll 2
        for (int i4 = 0; i4 < 16; ++i4) {
            float4 m4 = *(const float4*)&stg[wv][1][i4 * 4];
            float4 h4 = *(const float4*)&stg[wv][0][i4 * 4];
            float mv[4] = {m4.x, m4.y, m4.z, m4.w};
            float hh[4] = {h4.x, h4.y, h4.z, h4.w};
#pragma unroll
            for (int c = 0; c < 4; ++c) {
                int base_ = (i4 * 4 + c) * 64 + lane;
                g0 += mv[c] * GW[base_];
                g1 += mv[c] * GW[4096 + base_];
                g2 += mv[c] * GW[8192 + base_];
                h0 += hh[c] * GW[12288 + base_];
                h1 += hh[c] * GW[16384 + base_];
                h2 += hh[c] * GW[20480 + base_];
            }
        }
        float r = sigmoidf_(g0 + h0 + bi0 + bh0);
        float z = sigmoidf_(g1 + h1 + bi1 + bh1);
        float nn_ = tanhf(g2 + bi2 + r * (h2 + bh2));
        out[(size_t)n * 64 + lane] = (1.f - z) * nn_ + z * hv_own;
    }
}

// ---------- Set2Set ----------
__global__ __launch_bounds__(256) void k_lstm(
    const float* __restrict__ q_star, float* __restrict__ hs, float* __restrict__ cs,
    const float* __restrict__ w_ih, const float* __restrict__ w_hh,
    const float* __restrict__ b_ih, const float* __restrict__ b_hh) {
    __shared__ float qs[128], hr[64], gates[256];
    int bg = blockIdx.x, t = threadIdx.x;
    if (t < 128) qs[t] = q_star[bg * 128 + t];
    else if (t < 192) hr[t - 128] = hs[bg * 64 + (t - 128)];
    __syncthreads();
    float s = b_ih[t] + b_hh[t];
    const float4* wi = (const float4*)&w_ih[t * 128];
#pragma unroll
    for (int i = 0; i < 32; ++i) {
        float4 a = wi[i];
        s += qs[i * 4] * a.x + qs[i * 4 + 1] * a.y + qs[i * 4 + 2] * a.z + qs[i * 4 + 3] * a.w;
    }
    const float4* wh = (const float4*)&w_hh[t * 64];
#pragma unroll
    for (int i = 0; i < 16; ++i) {
        float4 a = wh[i];
        s += hr[i * 4] * a.x + hr[i * 4 + 1] * a.y + hr[i * 4 + 2] * a.z + hr[i * 4 + 3] * a.w;
    }
    gates[t] = s;
    __syncthreads();
    if (t < 64) {
        float ig = sigmoidf_(gates[t]);
        float fg = sigmoidf_(gates[64 + t]);
        float gg = tanhf(gates[128 + t]);
        float og = sigmoidf_(gates[192 + t]);
        float c = fg * cs[bg * 64 + t] + ig * gg;
        float hv = og * tanhf(c);
        cs[bg * 64 + t] = c;
        hs[bg * 64 + t] = hv;
    }
}

__global__ void k_attn(const float* __restrict__ out, const int* __restrict__ gstart,
                       const float* __restrict__ hs, float* __restrict__ q_star) {
    int g = blockIdx.x, o = threadIdx.x;
    float q = hs[g * 64 + o];
    int s0 = gstart[g], s1 = gstart[g + 1];
    float mmax = -1e30f;
    for (int i = s0; i < s1; ++i) {
        float p = out[(size_t)i * 64 + o] * q;
#pragma unroll
        for (int off = 32; off >= 1; off >>= 1) p += __shfl_xor(p, off);
        mmax = fmaxf(mmax, p);
    }
    float ssum = 0.f, racc = 0.f;
    for (int i = s0; i < s1; ++i) {
        float ov = out[(size_t)i * 64 + o];
        float p = ov * q;
#pragma unroll
        for (int off = 32; off >= 1; off >>= 1) p += __shfl_xor(p, off);
        float w = expf(p - mmax);
        ssum += w;
        racc += w * ov;
    }
    q_star[g * 128 + o] = q;
    q_star[g * 128 + 64 + o] = (s1 > s0) ? (racc / ssum) : 0.f;
}

__global__ void k_final(const float* __restrict__ q_star, const float* __restrict__ w1,
                        const float* __restrict__ b1, const float* __restrict__ w2,
                        const float* __restrict__ b2, float* __restrict__ yout) {
    __shared__ float qs[128];
    int g = blockIdx.x, t = threadIdx.x;
    qs[t] = q_star[g * 128 + t];
    qs[64 + t] = q_star[g * 128 + 64 + t];
    __syncthreads();
    float s = b1[t];
    const float4* w = (const float4*)&w1[t * 128];
#pragma unroll
    for (int i = 0; i < 32; ++i) {
        float4 a = w[i];
        s += qs[i * 4] * a.x + qs[i * 4 + 1] * a.y + qs[i * 4 + 2] * a.z + qs[i * 4 + 3] * a.w;
    }
    s = fmaxf(s, 0.f) * w2[t];
#pragma unroll
    for (int off = 32; off >= 1; off >>= 1) s += __shfl_xor(s, off);
    if (t == 0) yout[g] = s + b2[0];
}

extern "C" void kernel_launch(void* const* d_in, const int* in_sizes, int n_in,
                              void* d_out, int out_size, void* d_ws, size_t ws_size,
                              hipStream_t stream) {
    (void)in_sizes; (void)n_in; (void)out_size;
    const float* x        = (const float*)d_in[0];
    const float* eattr    = (const float*)d_in[1];
    const int*   ei       = (const int*)d_in[2];
    const int*   batch    = (const int*)d_in[3];
    const float* lin0_w   = (const float*)d_in[4];
    const float* lin0_b   = (const float*)d_in[5];
    const float* nn_w1    = (const float*)d_in[6];
    const float* nn_b1    = (const float*)d_in[7];
    const float* nn_w2    = (const float*)d_in[8];
    const float* nn_b2    = (const float*)d_in[9];
    const float* conv_root= (const float*)d_in[10];
    const float* conv_bias= (const float*)d_in[11];
    const float* gw_ih    = (const float*)d_in[12];
    const float* gw_hh    = (const float*)d_in[13];
    const float* gb_ih    = (const float*)d_in[14];
    const float* gb_hh    = (const float*)d_in[15];
    const float* lw_ih    = (const float*)d_in[16];
    const float* lw_hh    = (const float*)d_in[17];
    const float* lb_ih    = (const float*)d_in[18];
    const float* lb_hh    = (const float*)d_in[19];
    const float* lin1_w   = (const float*)d_in[20];
    const float* lin1_b   = (const float*)d_in[21];
    const float* lin2_w   = (const float*)d_in[22];
    const float* lin2_b   = (const float*)d_in[23];
    const int* src = ei;
    const int* dst = ei + NE;

    char* w = (char*)d_ws;
    auto alloc = [&](size_t bytes) { char* p = w; w += (bytes + 255) & ~(size_t)255; return p; };
    float* out    = (float*)alloc((size_t)NN * 64 * 4);
    float* e_h    = (float*)alloc((size_t)NE * 128 * 4);
    u16*   Whi    = (u16*)alloc((size_t)64 * SK * 2);
    u16*   Wlo    = (u16*)alloc((size_t)64 * SK * 2);
    float* P      = (float*)alloc((size_t)KSPLIT * NN * 64 * 4);
    float* Osum   = (float*)alloc((size_t)NN * 64 * 4);
    float* M      = (float*)alloc((size_t)NN * 64 * 4);
    float* gwT    = (float*)alloc((size_t)6 * 4096 * 4);
    float* degf   = (float*)alloc((size_t)NN * 4);
    int*   degi   = (int*)alloc((size_t)NN * 4);
    int*   rowptr = (int*)alloc((size_t)(NN + 1) * 4);
    int*   cursor = (int*)alloc((size_t)(NN + 1) * 4);
    int*   elist  = (int*)alloc((size_t)NE * 4);
    int*   gstart = (int*)alloc((size_t)(NGB + 1) * 4);
    float* q_star = (float*)alloc((size_t)NGB * 128 * 4);
    float* hs     = (float*)alloc((size_t)NGB * 64 * 4);
    float* cs     = (float*)alloc((size_t)NGB * 64 * 4);
    size_t used = (size_t)(w - (char*)d_ws);
    size_t avail = ws_size > used ? ws_size - used : 0;
    size_t maxrows = avail / ((size_t)SK * 4);
    int chunkN = maxrows > (size_t)NN ? NN : (int)maxrows;
    chunkN = (chunkN / 64) * 64;
    if (chunkN < 64) chunkN = 64;
    u32* S_pk = (u32*)w;

    hipMemsetAsync(degi, 0, (size_t)NN * 4, stream);
    hipMemsetAsync(q_star, 0, (size_t)NGB * 128 * 4, stream);
    hipMemsetAsync(hs, 0, (size_t)NGB * 64 * 4, stream);
    hipMemsetAsync(cs, 0, (size_t)NGB * 64 * 4, stream);

    k_lin0<<<NN, 64, 0, stream>>>(x, lin0_w, lin0_b, out);
    k_eh<<<NE / 2, 256, 0, stream>>>(eattr, nn_w1, nn_b1, e_h);
    k_wsplit<<<(64 * SK) / 256, 256, 0, stream>>>(nn_w2, Whi, Wlo);
    k_prep_gw<<<96, 256, 0, stream>>>(gw_ih, gw_hh, gwT);
    k_deg<<<(NE + 255) / 256, 256, 0, stream>>>(dst, degi);
    k_scan<<<1, 1024, 0, stream>>>(degi, rowptr, cursor, degf);
    k_fill<<<(NE + 255) / 256, 256, 0, stream>>>(dst, cursor, elist);
    k_gstart<<<5, 64, 0, stream>>>(batch, gstart);

    for (int it = 0; it < 3; ++it) {
        for (int cb = 0; cb < NN; cb += chunkN) {
            int cn = (NN - cb) < chunkN ? (NN - cb) : chunkN;
            k_sbuild<<<cn, 256, 0, stream>>>(out, e_h, src, rowptr, elist, S_pk, Osum, cb);
            k_gemm<<<dim3(cn / 32, KSPLIT), 64, 0, stream>>>(S_pk, Whi, Wlo, P, cb);
        }
        k_mrelu<<<NN / 64, 256, 0, stream>>>(out, P, Osum, degf, conv_root, nn_b2, conv_bias, M);
        k_gates<<<NN / 64, 256, 0, stream>>>(out, M, gwT, gb_ih, gb_hh);
    }

    for (int st = 0; st < 3; ++st) {
        k_lstm<<<NGB, 256, 0, stream>>>(q_star, hs, cs, lw_ih, lw_hh, lb_ih, lb_hh);
        k_attn<<<NGB, 64, 0, stream>>>(out, gstart, hs, q_star);
    }
    k_final<<<NGB, 64, 0, stream>>>(q_star, lin1_w, lin1_b, lin2_w, lin2_b, (float*)d_out);
}

// Round 9
// 737.601 us; speedup vs baseline: 2.0592x; 1.1027x over previous
//
#include <hip/hip_runtime.h>
#include <math.h>

#define NN 8000
#define NE 40000
#define NGB 256
#define SK 8192
#define KSPLIT 16
#define CHUNK_CAP 2048

typedef unsigned int u32;
typedef unsigned short u16;
typedef __attribute__((ext_vector_type(8))) short short8v;
typedef __attribute__((ext_vector_type(4))) float float4v;
typedef __attribute__((ext_vector_type(4))) unsigned int uint4v;

__device__ __forceinline__ float sigmoidf_(float x) { return 1.f / (1.f + expf(-x)); }

__device__ __forceinline__ u32 bf16_rne(float f) {
    u32 x = __builtin_bit_cast(u32, f);
    return (x + 0x7FFFu + ((x >> 16) & 1u)) >> 16;
}
__device__ __forceinline__ u32 pack_hl(float v) {
    u32 h = bf16_rne(v);
    float fh = __builtin_bit_cast(float, h << 16);
    u32 l = bf16_rne(v - fh);
    return (h << 16) | (l & 0xFFFFu);
}

// unpack 8 packed (hi<<16|lo) kappa-u32 into hi/lo bf16x8 fragments
__device__ __forceinline__ void unpack_hl(uint4v p0, uint4v p1, short8v& ah, short8v& al) {
    uint4v hset = { (p0.x >> 16) | (p0.y & 0xFFFF0000u),
                    (p0.z >> 16) | (p0.w & 0xFFFF0000u),
                    (p1.x >> 16) | (p1.y & 0xFFFF0000u),
                    (p1.z >> 16) | (p1.w & 0xFFFF0000u) };
    uint4v lset = { (p0.x & 0xFFFFu) | (p0.y << 16),
                    (p0.z & 0xFFFFu) | (p0.w << 16),
                    (p1.x & 0xFFFFu) | (p1.y << 16),
                    (p1.z & 0xFFFFu) | (p1.w << 16) };
    ah = __builtin_bit_cast(short8v, hset);
    al = __builtin_bit_cast(short8v, lset);
}

// load 8 consecutive floats, scale, split into hi/lo bf16x8 fragments
__device__ __forceinline__ void pack8(const float* p, float scale, short8v& ah, short8v& al) {
    float4 f0 = *(const float4*)p;
    float4 f1 = *(const float4*)(p + 4);
    float v[8] = {f0.x, f0.y, f0.z, f0.w, f1.x, f1.y, f1.z, f1.w};
    u32 hu[8], lu[8];
#pragma unroll
    for (int j = 0; j < 8; ++j) {
        float s = v[j] * scale;
        hu[j] = bf16_rne(s);
        float fh = __builtin_bit_cast(float, hu[j] << 16);
        lu[j] = bf16_rne(s - fh);
    }
    uint4v hset = { hu[0] | (hu[1] << 16), hu[2] | (hu[3] << 16),
                    hu[4] | (hu[5] << 16), hu[6] | (hu[7] << 16) };
    uint4v lset = { lu[0] | (lu[1] << 16), lu[2] | (lu[3] << 16),
                    lu[4] | (lu[5] << 16), lu[6] | (lu[7] << 16) };
    ah = __builtin_bit_cast(short8v, hset);
    al = __builtin_bit_cast(short8v, lset);
}

// ---------- small setup kernels ----------

__global__ void k_lin0(const float* __restrict__ x, const float* __restrict__ w,
                       const float* __restrict__ b, float* __restrict__ out) {
    __shared__ float xr[21];
    int n = blockIdx.x, t = threadIdx.x;
    if (t < 21) xr[t] = x[n * 21 + t];
    __syncthreads();
    float s = b[t];
#pragma unroll
    for (int c = 0; c < 21; ++c) s += xr[c] * w[t * 21 + c];
    out[n * 64 + t] = fmaxf(s, 0.f);
}

__global__ void k_eh(const float* __restrict__ ea, const float* __restrict__ w1,
                     const float* __restrict__ b1, float* __restrict__ e_h) {
    __shared__ float a[2][16];
    int t = threadIdx.x;
    int e0 = blockIdx.x * 2;
    if (t < 32) a[t >> 4][t & 15] = ea[(e0 + (t >> 4)) * 16 + (t & 15)];
    __syncthreads();
    int sub = t >> 7, j = t & 127;
    float s = b1[j];
#pragma unroll
    for (int c = 0; c < 16; ++c) s += a[sub][c] * w1[j * 16 + c];
    e_h[(size_t)(e0 + sub) * 128 + j] = fmaxf(s, 0.f);
}

// W2T hi/lo in kchunk-major coalesced layout:
//   pos = ((kap>>3)*64 + o)*8 + (kap&7)  holds split of nn_w2[(i*64+o)*128 + k], kap=i*128+k
__global__ void k_wsplit(const float* __restrict__ nn_w2, u16* __restrict__ Whi,
                         u16* __restrict__ Wlo) {
    int idx = blockIdx.x * 256 + threadIdx.x;   // [0, 64*8192)
    int o = idx >> 13, kap = idx & 8191;
    int i = kap >> 7, k = kap & 127;
    float v = nn_w2[(size_t)((i << 6) + o) * 128 + k];
    u32 h = bf16_rne(v);
    float fh = __builtin_bit_cast(float, h << 16);
    u32 l = bf16_rne(v - fh);
    int pos = ((kap >> 3) * 64 + o) * 8 + (kap & 7);
    Whi[pos] = (u16)h; Wlo[pos] = (u16)l;
}

// mrelu B (FIXED pairing): A rows k<64 carry Osum/deg -> B must be nn_b2;
//                          A rows k>=64 carry out    -> B must be conv_root.
// pos=((k>>3)*64+o)*8+(k&7)
__global__ void k_prep_mw(const float* __restrict__ conv_root, const float* __restrict__ nn_b2,
                          u16* __restrict__ Bmh, u16* __restrict__ Bml) {
    int idx = blockIdx.x * 256 + threadIdx.x;   // < 8192
    int k = idx >> 6, o = idx & 63;
    float v = (k < 64) ? nn_b2[k * 64 + o] : conv_root[(k - 64) * 64 + o];
    u32 h = bf16_rne(v);
    float fh = __builtin_bit_cast(float, h << 16);
    u32 l = bf16_rne(v - fh);
    int pos = ((k >> 3) * 64 + o) * 8 + (k & 7);
    Bmh[pos] = (u16)h; Bml[pos] = (u16)l;
}

// gate B: W^T[k,o] = w[o*64+k], o in [0,192), k in [0,64); pos=((k>>3)*192+o)*8+(k&7)
__global__ void k_prep_gb(const float* __restrict__ w_ih, const float* __restrict__ w_hh,
                          u16* __restrict__ Bih_h, u16* __restrict__ Bih_l,
                          u16* __restrict__ Bhh_h, u16* __restrict__ Bhh_l) {
    int idx = blockIdx.x * 256 + threadIdx.x;   // < 24576
    int half = idx >= 12288;
    int i2 = idx - half * 12288;
    int o = i2 % 192, k = i2 / 192;
    float v = half ? w_hh[o * 64 + k] : w_ih[o * 64 + k];
    u32 h = bf16_rne(v);
    float fh = __builtin_bit_cast(float, h << 16);
    u32 l = bf16_rne(v - fh);
    int pos = ((k >> 3) * 192 + o) * 8 + (k & 7);
    if (half) { Bhh_h[pos] = (u16)h; Bhh_l[pos] = (u16)l; }
    else      { Bih_h[pos] = (u16)h; Bih_l[pos] = (u16)l; }
}

__global__ void k_deg(const int* __restrict__ dst, int* __restrict__ degi) {
    int e = blockIdx.x * blockDim.x + threadIdx.x;
    if (e < NE) atomicAdd(&degi[dst[e]], 1);
}

__global__ void k_scan(const int* __restrict__ degi, int* __restrict__ rowptr,
                       int* __restrict__ cursor, float* __restrict__ degf) {
    __shared__ int lds[1024];
    __shared__ int carry;
    int t = threadIdx.x;
    if (t == 0) carry = 0;
    __syncthreads();
    for (int base = 0; base < NN; base += 1024) {
        int i = base + t;
        int v = (i < NN) ? degi[i] : 0;
        lds[t] = v;
        __syncthreads();
        for (int off = 1; off < 1024; off <<= 1) {
            int add = (t >= off) ? lds[t - off] : 0;
            __syncthreads();
            lds[t] += add;
            __syncthreads();
        }
        if (i < NN) {
            int exc = lds[t] - v + carry;
            rowptr[i] = exc; cursor[i] = exc;
            degf[i] = (float)(v > 1 ? v : 1);
        }
        __syncthreads();
        if (t == 0) carry += lds[1023];
        __syncthreads();
    }
    if (t == 0) rowptr[NN] = carry;
}

__global__ void k_fill(const int* __restrict__ dst, int* __restrict__ cursor,
                       int* __restrict__ elist) {
    int e = blockIdx.x * blockDim.x + threadIdx.x;
    if (e < NE) { int p = atomicAdd(&cursor[dst[e]], 1); elist[p] = e; }
}

__global__ void k_gstart(const int* __restrict__ batch, int* __restrict__ gstart) {
    int g = blockIdx.x * blockDim.x + threadIdx.x;
    if (g > NGB) return;
    int lo = 0, hi = NN;
    while (lo < hi) { int mid = (lo + hi) >> 1; if (batch[mid] < g) lo = mid + 1; else hi = mid; }
    gstart[g] = lo;
}

// ---------- NNConv: S build ----------
__global__ __launch_bounds__(256) void k_sbuild(
    const float* __restrict__ out, const float* __restrict__ e_h,
    const int* __restrict__ src, const int* __restrict__ rowptr,
    const int* __restrict__ elist, u32* __restrict__ S_pk,
    float* __restrict__ Osum, int base) {
    int t = threadIdx.x;
    int n = base + blockIdx.x;
    int ib = t >> 5;
    int kq = t & 31;
    int lane = t & 63;
    float acc[8][4];
#pragma unroll
    for (int j = 0; j < 8; ++j) { acc[j][0] = 0.f; acc[j][1] = 0.f; acc[j][2] = 0.f; acc[j][3] = 0.f; }
    float osum = 0.f;
    int r0 = rowptr[n], r1 = rowptr[n + 1];
    const float4* out4 = (const float4*)out;
    const float4* eh4p = (const float4*)e_h;
    for (int idx = r0; idx < r1; ++idx) {
        int e = elist[idx];
        int sn = src[e];
        float4 eh = eh4p[(size_t)e * 32 + kq];
        float4 f0 = out4[sn * 16 + ib * 2];
        float4 f1 = out4[sn * 16 + ib * 2 + 1];
        float fv[8] = {f0.x, f0.y, f0.z, f0.w, f1.x, f1.y, f1.z, f1.w};
#pragma unroll
        for (int j = 0; j < 8; ++j) {
            acc[j][0] += fv[j] * eh.x; acc[j][1] += fv[j] * eh.y;
            acc[j][2] += fv[j] * eh.z; acc[j][3] += fv[j] * eh.w;
        }
        if (t < 64) osum += out[(size_t)sn * 64 + lane];
    }
    size_t rb4 = (size_t)blockIdx.x * (SK / 4);
    uint4v* S4 = (uint4v*)S_pk;
#pragma unroll
    for (int j = 0; j < 8; ++j) {
        uint4v v = { pack_hl(acc[j][0]), pack_hl(acc[j][1]), pack_hl(acc[j][2]), pack_hl(acc[j][3]) };
        S4[rb4 + (size_t)(ib * 8 + j) * 32 + kq] = v;
    }
    if (t < 64) Osum[(size_t)n * 64 + lane] = osum;
}

// ---------- NNConv: MFMA GEMM, bf16x3. 1 wave/block, M=32/wave ----------
__global__ __launch_bounds__(64) void k_gemm(
    const u32* __restrict__ S_pk, const u16* __restrict__ Whi,
    const u16* __restrict__ Wlo, float* __restrict__ P, int base) {
    int lane = threadIdx.x;
    int lrow = lane & 15, lkg = lane >> 4;
    int m0 = blockIdx.x * 32;
    int ks = blockIdx.y;
    int kbase = ks * (SK / KSPLIT);
    float4v acc[2][4];
#pragma unroll
    for (int ms = 0; ms < 2; ++ms)
#pragma unroll
        for (int nt = 0; nt < 4; ++nt) acc[ms][nt] = (float4v){0.f, 0.f, 0.f, 0.f};
    const short8v* bhv = (const short8v*)Whi;
    const short8v* blv = (const short8v*)Wlo;
    const u32* ar0 = S_pk + (size_t)(m0 + lrow) * SK + kbase + lkg * 8;
    const u32* ar1 = ar0 + (size_t)16 * SK;
    int kc0 = (kbase >> 3) + lkg;

#pragma unroll 2
    for (int kk = 0; kk < SK / KSPLIT / 32; ++kk) {
        uint4v a00 = *(const uint4v*)(ar0 + kk * 32);
        uint4v a01 = *(const uint4v*)(ar0 + kk * 32 + 4);
        uint4v a10 = *(const uint4v*)(ar1 + kk * 32);
        uint4v a11 = *(const uint4v*)(ar1 + kk * 32 + 4);
        int bo = (kc0 + kk * 4) * 64 + lrow;
        short8v bh[4], bl[4];
#pragma unroll
        for (int nt = 0; nt < 4; ++nt) { bh[nt] = bhv[bo + nt * 16]; bl[nt] = blv[bo + nt * 16]; }
        short8v ah0, al0, ah1, al1;
        unpack_hl(a00, a01, ah0, al0);
        unpack_hl(a10, a11, ah1, al1);
#pragma unroll
        for (int nt = 0; nt < 4; ++nt) {
            acc[0][nt] = __builtin_amdgcn_mfma_f32_16x16x32_bf16(ah0, bh[nt], acc[0][nt], 0, 0, 0);
            acc[0][nt] = __builtin_amdgcn_mfma_f32_16x16x32_bf16(al0, bh[nt], acc[0][nt], 0, 0, 0);
            acc[0][nt] = __builtin_amdgcn_mfma_f32_16x16x32_bf16(ah0, bl[nt], acc[0][nt], 0, 0, 0);
            acc[1][nt] = __builtin_amdgcn_mfma_f32_16x16x32_bf16(ah1, bh[nt], acc[1][nt], 0, 0, 0);
            acc[1][nt] = __builtin_amdgcn_mfma_f32_16x16x32_bf16(al1, bh[nt], acc[1][nt], 0, 0, 0);
            acc[1][nt] = __builtin_amdgcn_mfma_f32_16x16x32_bf16(ah1, bl[nt], acc[1][nt], 0, 0, 0);
        }
    }
    int gbase = base + m0;
#pragma unroll
    for (int ms = 0; ms < 2; ++ms)
#pragma unroll
        for (int nt = 0; nt < 4; ++nt)
#pragma unroll
            for (int jj = 0; jj < 4; ++jj) {
                int row = ms * 16 + lkg * 4 + jj;
                int o = nt * 16 + lrow;
                P[((size_t)ks * NN + gbase + row) * 64 + o] = acc[ms][nt][jj];
            }
}

// ---------- Psum reduce: Psum = sum over KSPLIT planes ----------
__global__ __launch_bounds__(256) void k_psum(const float* __restrict__ P,
                                              float* __restrict__ Psum) {
    int i = blockIdx.x * 256 + threadIdx.x;    // < NN*64/4
    const float4* P4 = (const float4*)P;
    float4 s = P4[i];
#pragma unroll
    for (int p = 1; p < KSPLIT; ++p) {
        float4 v = P4[(size_t)p * (NN * 16) + i];
        s.x += v.x; s.y += v.y; s.z += v.z; s.w += v.w;
    }
    ((float4*)Psum)[i] = s;
}

// ---------- m = relu((Psum + Osum@b2)/deg + out@root + cb)  [MFMA bf16x3] ----------
__global__ __launch_bounds__(64) void k_mrelu2(
    const float* __restrict__ out, const float* __restrict__ Osum,
    const float* __restrict__ Psum, const float* __restrict__ degf,
    const u16* __restrict__ Bmh, const u16* __restrict__ Bml,
    const float* __restrict__ conv_bias, float* __restrict__ M) {
    int lane = threadIdx.x;
    int lrow = lane & 15, lkg = lane >> 4;
    int n0 = blockIdx.x * 16;
    int arow = n0 + lrow;
    float invd = 1.f / degf[arow];
    float4v acc[4];
#pragma unroll
    for (int nt = 0; nt < 4; ++nt) acc[nt] = (float4v){0.f, 0.f, 0.f, 0.f};
    const short8v* bhv = (const short8v*)Bmh;
    const short8v* blv = (const short8v*)Bml;
#pragma unroll
    for (int s = 0; s < 4; ++s) {
        short8v ah, al;
        if (s < 2) pack8(&Osum[(size_t)arow * 64 + s * 32 + lkg * 8], invd, ah, al);
        else       pack8(&out[(size_t)arow * 64 + (s - 2) * 32 + lkg * 8], 1.f, ah, al);
        int kc = s * 4 + lkg;
#pragma unroll
        for (int nt = 0; nt < 4; ++nt) {
            short8v bh = bhv[kc * 64 + nt * 16 + lrow];
            short8v bl = blv[kc * 64 + nt * 16 + lrow];
            acc[nt] = __builtin_amdgcn_mfma_f32_16x16x32_bf16(ah, bh, acc[nt], 0, 0, 0);
            acc[nt] = __builtin_amdgcn_mfma_f32_16x16x32_bf16(al, bh, acc[nt], 0, 0, 0);
            acc[nt] = __builtin_amdgcn_mfma_f32_16x16x32_bf16(ah, bl, acc[nt], 0, 0, 0);
        }
    }
    float invd2[4];
#pragma unroll
    for (int jj = 0; jj < 4; ++jj) invd2[jj] = 1.f / degf[n0 + lkg * 4 + jj];
#pragma unroll
    for (int nt = 0; nt < 4; ++nt) {
        int o = nt * 16 + lrow;
        float cb = conv_bias[o];
#pragma unroll
        for (int jj = 0; jj < 4; ++jj) {
            int row = n0 + lkg * 4 + jj;
            M[(size_t)row * 64 + o] = fmaxf(acc[nt][jj] + Psum[(size_t)row * 64 + o] * invd2[jj] + cb, 0.f);
        }
    }
}

// ---------- GRU gates [MFMA bf16x3]; out <- h' ----------
__global__ __launch_bounds__(64) void k_gates2(
    float* __restrict__ out, const float* __restrict__ M,
    const u16* __restrict__ Bih_h, const u16* __restrict__ Bih_l,
    const u16* __restrict__ Bhh_h, const u16* __restrict__ Bhh_l,
    const float* __restrict__ gb_ih, const float* __restrict__ gb_hh) {
    int lane = threadIdx.x;
    int lrow = lane & 15, lkg = lane >> 4;
    int n0 = blockIdx.x * 16;
    int arow = n0 + lrow;
    float4v ai[12], ah_[12];
#pragma unroll
    for (int nt = 0; nt < 12; ++nt) { ai[nt] = (float4v){0.f, 0.f, 0.f, 0.f}; ah_[nt] = (float4v){0.f, 0.f, 0.f, 0.f}; }
    const short8v* bih_h = (const short8v*)Bih_h;
    const short8v* bih_l = (const short8v*)Bih_l;
    const short8v* bhh_h = (const short8v*)Bhh_h;
    const short8v* bhh_l = (const short8v*)Bhh_l;
#pragma unroll
    for (int s = 0; s < 2; ++s) {
        short8v mh, ml, hh, hl;
        pack8(&M[(size_t)arow * 64 + s * 32 + lkg * 8], 1.f, mh, ml);
        pack8(&out[(size_t)arow * 64 + s * 32 + lkg * 8], 1.f, hh, hl);
        int kc = s * 4 + lkg;
#pragma unroll
        for (int nt = 0; nt < 12; ++nt) {
            int bo = kc * 192 + nt * 16 + lrow;
            short8v b1 = bih_h[bo], b2 = bih_l[bo];
            ai[nt] = __builtin_amdgcn_mfma_f32_16x16x32_bf16(mh, b1, ai[nt], 0, 0, 0);
            ai[nt] = __builtin_amdgcn_mfma_f32_16x16x32_bf16(ml, b1, ai[nt], 0, 0, 0);
            ai[nt] = __builtin_amdgcn_mfma_f32_16x16x32_bf16(mh, b2, ai[nt], 0, 0, 0);
            short8v b3 = bhh_h[bo], b4 = bhh_l[bo];
            ah_[nt] = __builtin_amdgcn_mfma_f32_16x16x32_bf16(hh, b3, ah_[nt], 0, 0, 0);
            ah_[nt] = __builtin_amdgcn_mfma_f32_16x16x32_bf16(hl, b3, ah_[nt], 0, 0, 0);
            ah_[nt] = __builtin_amdgcn_mfma_f32_16x16x32_bf16(hh, b4, ah_[nt], 0, 0, 0);
        }
    }
#pragma unroll
    for (int nt = 0; nt < 4; ++nt) {
        int o = nt * 16 + lrow;
        float bi0 = gb_ih[o], bi1 = gb_ih[64 + o], bi2 = gb_ih[128 + o];
        float bh0 = gb_hh[o], bh1 = gb_hh[64 + o], bh2 = gb_hh[128 + o];
#pragma unroll
        for (int jj = 0; jj < 4; ++jj) {
            int row = n0 + lkg * 4 + jj;
            float ir = ai[nt][jj] + bi0,  hr = ah_[nt][jj] + bh0;
            float iz = ai[nt + 4][jj] + bi1, hz = ah_[nt + 4][jj] + bh1;
            float in_ = ai[nt + 8][jj] + bi2, hn = ah_[nt + 8][jj] + bh2;
            float r = sigmoidf_(ir + hr);
            float z = sigmoidf_(iz + hz);
            float nv = tanhf(in_ + r * hn);
            float ho = out[(size_t)row * 64 + o];
            out[(size_t)row * 64 + o] = (1.f - z) * nv + z * ho;
        }
    }
}

// ---------- Set2Set ----------
__global__ __launch_bounds__(256) void k_lstm(
    const float* __restrict__ q_star, float* __restrict__ hs, float* __restrict__ cs,
    const float* __restrict__ w_ih, const float* __restrict__ w_hh,
    const float* __restrict__ b_ih, const float* __restrict__ b_hh) {
    __shared__ float qs[128], hr[64], gates[256];
    int bg = blockIdx.x, t = threadIdx.x;
    if (t < 128) qs[t] = q_star[bg * 128 + t];
    else if (t < 192) hr[t - 128] = hs[bg * 64 + (t - 128)];
    __syncthreads();
    float s = b_ih[t] + b_hh[t];
    const float4* wi = (const float4*)&w_ih[t * 128];
#pragma unroll
    for (int i = 0; i < 32; ++i) {
        float4 a = wi[i];
        s += qs[i * 4] * a.x + qs[i * 4 + 1] * a.y + qs[i * 4 + 2] * a.z + qs[i * 4 + 3] * a.w;
    }
    const float4* wh = (const float4*)&w_hh[t * 64];
#pragma unroll
    for (int i = 0; i < 16; ++i) {
        float4 a = wh[i];
        s += hr[i * 4] * a.x + hr[i * 4 + 1] * a.y + hr[i * 4 + 2] * a.z + hr[i * 4 + 3] * a.w;
    }
    gates[t] = s;
    __syncthreads();
    if (t < 64) {
        float ig = sigmoidf_(gates[t]);
        float fg = sigmoidf_(gates[64 + t]);
        float gg = tanhf(gates[128 + t]);
        float og = sigmoidf_(gates[192 + t]);
        float c = fg * cs[bg * 64 + t] + ig * gg;
        float hv = og * tanhf(c);
        cs[bg * 64 + t] = c;
        hs[bg * 64 + t] = hv;
    }
}

__global__ void k_attn(const float* __restrict__ out, const int* __restrict__ gstart,
                       const float* __restrict__ hs, float* __restrict__ q_star) {
    int g = blockIdx.x, o = threadIdx.x;
    float q = hs[g * 64 + o];
    int s0 = gstart[g], s1 = gstart[g + 1];
    float mmax = -1e30f;
    for (int i = s0; i < s1; ++i) {
        float p = out[(size_t)i * 64 + o] * q;
#pragma unroll
        for (int off = 32; off >= 1; off >>= 1) p += __shfl_xor(p, off);
        mmax = fmaxf(mmax, p);
    }
    float ssum = 0.f, racc = 0.f;
    for (int i = s0; i < s1; ++i) {
        float ov = out[(size_t)i * 64 + o];
        float p = ov * q;
#pragma unroll
        for (int off = 32; off >= 1; off >>= 1) p += __shfl_xor(p, off);
        float w = expf(p - mmax);
        ssum += w;
        racc += w * ov;
    }
    q_star[g * 128 + o] = q;
    q_star[g * 128 + 64 + o] = (s1 > s0) ? (racc / ssum) : 0.f;
}

__global__ void k_final(const float* __restrict__ q_star, const float* __restrict__ w1,
                        const float* __restrict__ b1, const float* __restrict__ w2,
                        const float* __restrict__ b2, float* __restrict__ yout) {
    __shared__ float qs[128];
    int g = blockIdx.x, t = threadIdx.x;
    qs[t] = q_star[g * 128 + t];
    qs[64 + t] = q_star[g * 128 + 64 + t];
    __syncthreads();
    float s = b1[t];
    const float4* w = (const float4*)&w1[t * 128];
#pragma unroll
    for (int i = 0; i < 32; ++i) {
        float4 a = w[i];
        s += qs[i * 4] * a.x + qs[i * 4 + 1] * a.y + qs[i * 4 + 2] * a.z + qs[i * 4 + 3] * a.w;
    }
    s = fmaxf(s, 0.f) * w2[t];
#pragma unroll
    for (int off = 32; off >= 1; off >>= 1) s += __shfl_xor(s, off);
    if (t == 0) yout[g] = s + b2[0];
}

extern "C" void kernel_launch(void* const* d_in, const int* in_sizes, int n_in,
                              void* d_out, int out_size, void* d_ws, size_t ws_size,
                              hipStream_t stream) {
    (void)in_sizes; (void)n_in; (void)out_size;
    const float* x        = (const float*)d_in[0];
    const float* eattr    = (const float*)d_in[1];
    const int*   ei       = (const int*)d_in[2];
    const int*   batch    = (const int*)d_in[3];
    const float* lin0_w   = (const float*)d_in[4];
    const float* lin0_b   = (const float*)d_in[5];
    const float* nn_w1    = (const float*)d_in[6];
    const float* nn_b1    = (const float*)d_in[7];
    const float* nn_w2    = (const float*)d_in[8];
    const float* nn_b2    = (const float*)d_in[9];
    const float* conv_root= (const float*)d_in[10];
    const float* conv_bias= (const float*)d_in[11];
    const float* gw_ih    = (const float*)d_in[12];
    const float* gw_hh    = (const float*)d_in[13];
    const float* gb_ih    = (const float*)d_in[14];
    const float* gb_hh    = (const float*)d_in[15];
    const float* lw_ih    = (const float*)d_in[16];
    const float* lw_hh    = (const float*)d_in[17];
    const float* lb_ih    = (const float*)d_in[18];
    const float* lb_hh    = (const float*)d_in[19];
    const float* lin1_w   = (const float*)d_in[20];
    const float* lin1_b   = (const float*)d_in[21];
    const float* lin2_w   = (const float*)d_in[22];
    const float* lin2_b   = (const float*)d_in[23];
    const int* src = ei;
    const int* dst = ei + NE;

    char* w = (char*)d_ws;
    auto alloc = [&](size_t bytes) { char* p = w; w += (bytes + 255) & ~(size_t)255; return p; };
    float* out    = (float*)alloc((size_t)NN * 64 * 4);
    float* e_h    = (float*)alloc((size_t)NE * 128 * 4);
    u16*   Whi    = (u16*)alloc((size_t)64 * SK * 2);
    u16*   Wlo    = (u16*)alloc((size_t)64 * SK * 2);
    float* P      = (float*)alloc((size_t)KSPLIT * NN * 64 * 4);
    float* Psum   = (float*)alloc((size_t)NN * 64 * 4);
    float* Osum   = (float*)alloc((size_t)NN * 64 * 4);
    float* M      = (float*)alloc((size_t)NN * 64 * 4);
    u16*   Bmh    = (u16*)alloc((size_t)8192 * 2);
    u16*   Bml    = (u16*)alloc((size_t)8192 * 2);
    u16*   Bih_h  = (u16*)alloc((size_t)12288 * 2);
    u16*   Bih_l  = (u16*)alloc((size_t)12288 * 2);
    u16*   Bhh_h  = (u16*)alloc((size_t)12288 * 2);
    u16*   Bhh_l  = (u16*)alloc((size_t)12288 * 2);
    float* degf   = (float*)alloc((size_t)NN * 4);
    int*   degi   = (int*)alloc((size_t)NN * 4);
    int*   rowptr = (int*)alloc((size_t)(NN + 1) * 4);
    int*   cursor = (int*)alloc((size_t)(NN + 1) * 4);
    int*   elist  = (int*)alloc((size_t)NE * 4);
    int*   gstart = (int*)alloc((size_t)(NGB + 1) * 4);
    float* q_star = (float*)alloc((size_t)NGB * 128 * 4);
    float* hs     = (float*)alloc((size_t)NGB * 64 * 4);
    float* cs     = (float*)alloc((size_t)NGB * 64 * 4);
    size_t used = (size_t)(w - (char*)d_ws);
    size_t avail = ws_size > used ? ws_size - used : 0;
    size_t maxrows = avail / ((size_t)SK * 4);
    int chunkN = maxrows > (size_t)NN ? NN : (int)maxrows;
    chunkN = (chunkN / 64) * 64;
    if (chunkN < 64) chunkN = 64;
    if (chunkN > CHUNK_CAP) chunkN = CHUNK_CAP;   // keep S chunk L3-resident (64 MB)
    u32* S_pk = (u32*)w;

    hipMemsetAsync(degi, 0, (size_t)NN * 4, stream);
    hipMemsetAsync(q_star, 0, (size_t)NGB * 128 * 4, stream);
    hipMemsetAsync(hs, 0, (size_t)NGB * 64 * 4, stream);
    hipMemsetAsync(cs, 0, (size_t)NGB * 64 * 4, stream);

    k_lin0<<<NN, 64, 0, stream>>>(x, lin0_w, lin0_b, out);
    k_eh<<<NE / 2, 256, 0, stream>>>(eattr, nn_w1, nn_b1, e_h);
    k_wsplit<<<(64 * SK) / 256, 256, 0, stream>>>(nn_w2, Whi, Wlo);
    k_prep_mw<<<32, 256, 0, stream>>>(conv_root, nn_b2, Bmh, Bml);
    k_prep_gb<<<96, 256, 0, stream>>>(gw_ih, gw_hh, Bih_h, Bih_l, Bhh_h, Bhh_l);
    k_deg<<<(NE + 255) / 256, 256, 0, stream>>>(dst, degi);
    k_scan<<<1, 1024, 0, stream>>>(degi, rowptr, cursor, degf);
    k_fill<<<(NE + 255) / 256, 256, 0, stream>>>(dst, cursor, elist);
    k_gstart<<<5, 64, 0, stream>>>(batch, gstart);

    for (int it = 0; it < 3; ++it) {
        for (int cb = 0; cb < NN; cb += chunkN) {
            int cn = (NN - cb) < chunkN ? (NN - cb) : chunkN;
            k_sbuild<<<cn, 256, 0, stream>>>(out, e_h, src, rowptr, elist, S_pk, Osum, cb);
            k_gemm<<<dim3(cn / 32, KSPLIT), 64, 0, stream>>>(S_pk, Whi, Wlo, P, cb);
        }
        k_psum<<<NN / 16, 256, 0, stream>>>(P, Psum);
        k_mrelu2<<<NN / 16, 64, 0, stream>>>(out, Osum, Psum, degf, Bmh, Bml, conv_bias, M);
        k_gates2<<<NN / 16, 64, 0, stream>>>(out, M, Bih_h, Bih_l, Bhh_h, Bhh_l, gb_ih, gb_hh);
    }

    for (int st = 0; st < 3; ++st) {
        k_lstm<<<NGB, 256, 0, stream>>>(q_star, hs, cs, lw_ih, lw_hh, lb_ih, lb_hh);
        k_attn<<<NGB, 64, 0, stream>>>(out, gstart, hs, q_star);
    }
    k_final<<<NGB, 64, 0, stream>>>(q_star, lin1_w, lin1_b, lin2_w, lin2_b, (float*)d_out);
}

// Round 11
// 496.975 us; speedup vs baseline: 3.0563x; 1.4842x over previous
//
#include <hip/hip_runtime.h>
#include <math.h>

#define NN 8000
#define NE 40000
#define NGB 256
#define SK 8192
#define KSPLIT 16

typedef unsigned int u32;
typedef unsigned short u16;
typedef __attribute__((ext_vector_type(8))) short short8v;
typedef __attribute__((ext_vector_type(4))) float float4v;
typedef __attribute__((ext_vector_type(4))) unsigned int uint4v;

__device__ __forceinline__ float sigmoidf_(float x) { return 1.f / (1.f + expf(-x)); }

__device__ __forceinline__ u32 bf16_rne(float f) {
    u32 x = __builtin_bit_cast(u32, f);
    return (x + 0x7FFFu + ((x >> 16) & 1u)) >> 16;
}

// pack 8 floats -> 8 bf16 (RNE) in a uint4
__device__ __forceinline__ uint4v pack_bf8(const float v[8]) {
    u32 h[8];
#pragma unroll
    for (int j = 0; j < 8; ++j) h[j] = bf16_rne(v[j]);
    return (uint4v){ h[0] | (h[1] << 16), h[2] | (h[3] << 16),
                     h[4] | (h[5] << 16), h[6] | (h[7] << 16) };
}

// load 8 consecutive floats, scale, split into hi/lo bf16x8 fragments (for tiny GEMMs)
__device__ __forceinline__ void pack8(const float* p, float scale, short8v& ah, short8v& al) {
    float4 f0 = *(const float4*)p;
    float4 f1 = *(const float4*)(p + 4);
    float v[8] = {f0.x, f0.y, f0.z, f0.w, f1.x, f1.y, f1.z, f1.w};
    u32 hu[8], lu[8];
#pragma unroll
    for (int j = 0; j < 8; ++j) {
        float s = v[j] * scale;
        hu[j] = bf16_rne(s);
        float fh = __builtin_bit_cast(float, hu[j] << 16);
        lu[j] = bf16_rne(s - fh);
    }
    uint4v hset = { hu[0] | (hu[1] << 16), hu[2] | (hu[3] << 16),
                    hu[4] | (hu[5] << 16), hu[6] | (hu[7] << 16) };
    uint4v lset = { lu[0] | (lu[1] << 16), lu[2] | (lu[3] << 16),
                    lu[4] | (lu[5] << 16), lu[6] | (lu[7] << 16) };
    ah = __builtin_bit_cast(short8v, hset);
    al = __builtin_bit_cast(short8v, lset);
}

// ---------- small setup kernels ----------

__global__ void k_lin0(const float* __restrict__ x, const float* __restrict__ w,
                       const float* __restrict__ b, float* __restrict__ out) {
    __shared__ float xr[21];
    int n = blockIdx.x, t = threadIdx.x;
    if (t < 21) xr[t] = x[n * 21 + t];
    __syncthreads();
    float s = b[t];
#pragma unroll
    for (int c = 0; c < 21; ++c) s += xr[c] * w[t * 21 + c];
    out[n * 64 + t] = fmaxf(s, 0.f);
}

__global__ void k_eh(const float* __restrict__ ea, const float* __restrict__ w1,
                     const float* __restrict__ b1, float* __restrict__ e_h) {
    __shared__ float a[2][16];
    int t = threadIdx.x;
    int e0 = blockIdx.x * 2;
    if (t < 32) a[t >> 4][t & 15] = ea[(e0 + (t >> 4)) * 16 + (t & 15)];
    __syncthreads();
    int sub = t >> 7, j = t & 127;
    float s = b1[j];
#pragma unroll
    for (int c = 0; c < 16; ++c) s += a[sub][c] * w1[j * 16 + c];
    e_h[(size_t)(e0 + sub) * 128 + j] = fmaxf(s, 0.f);
}

// W2T hi/lo in kchunk-major coalesced layout:
//   pos = ((kap>>3)*64 + o)*8 + (kap&7)  holds split of nn_w2[(i*64+o)*128 + k], kap=i*128+k
__global__ void k_wsplit(const float* __restrict__ nn_w2, u16* __restrict__ Whi,
                         u16* __restrict__ Wlo) {
    int idx = blockIdx.x * 256 + threadIdx.x;   // [0, 64*8192)
    int o = idx >> 13, kap = idx & 8191;
    int i = kap >> 7, k = kap & 127;
    float v = nn_w2[(size_t)((i << 6) + o) * 128 + k];
    u32 h = bf16_rne(v);
    float fh = __builtin_bit_cast(float, h << 16);
    u32 l = bf16_rne(v - fh);
    int pos = ((kap >> 3) * 64 + o) * 8 + (kap & 7);
    Whi[pos] = (u16)h; Wlo[pos] = (u16)l;
}

// mrelu B: A rows k<64 carry Osum/deg -> nn_b2; rows k>=64 carry out -> conv_root.
__global__ void k_prep_mw(const float* __restrict__ conv_root, const float* __restrict__ nn_b2,
                          u16* __restrict__ Bmh, u16* __restrict__ Bml) {
    int idx = blockIdx.x * 256 + threadIdx.x;   // < 8192
    int k = idx >> 6, o = idx & 63;
    float v = (k < 64) ? nn_b2[k * 64 + o] : conv_root[(k - 64) * 64 + o];
    u32 h = bf16_rne(v);
    float fh = __builtin_bit_cast(float, h << 16);
    u32 l = bf16_rne(v - fh);
    int pos = ((k >> 3) * 64 + o) * 8 + (k & 7);
    Bmh[pos] = (u16)h; Bml[pos] = (u16)l;
}

// gate B: W^T[k,o] = w[o*64+k], o in [0,192), k in [0,64); pos=((k>>3)*192+o)*8+(k&7)
__global__ void k_prep_gb(const float* __restrict__ w_ih, const float* __restrict__ w_hh,
                          u16* __restrict__ Bih_h, u16* __restrict__ Bih_l,
                          u16* __restrict__ Bhh_h, u16* __restrict__ Bhh_l) {
    int idx = blockIdx.x * 256 + threadIdx.x;   // < 24576
    int half = idx >= 12288;
    int i2 = idx - half * 12288;
    int o = i2 % 192, k = i2 / 192;
    float v = half ? w_hh[o * 64 + k] : w_ih[o * 64 + k];
    u32 h = bf16_rne(v);
    float fh = __builtin_bit_cast(float, h << 16);
    u32 l = bf16_rne(v - fh);
    int pos = ((k >> 3) * 192 + o) * 8 + (k & 7);
    if (half) { Bhh_h[pos] = (u16)h; Bhh_l[pos] = (u16)l; }
    else      { Bih_h[pos] = (u16)h; Bih_l[pos] = (u16)l; }
}

__global__ void k_deg(const int* __restrict__ dst, int* __restrict__ degi) {
    int e = blockIdx.x * blockDim.x + threadIdx.x;
    if (e < NE) atomicAdd(&degi[dst[e]], 1);
}

__global__ void k_scan(const int* __restrict__ degi, int* __restrict__ rowptr,
                       int* __restrict__ cursor, float* __restrict__ degf) {
    __shared__ int lds[1024];
    __shared__ int carry;
    int t = threadIdx.x;
    if (t == 0) carry = 0;
    __syncthreads();
    for (int base = 0; base < NN; base += 1024) {
        int i = base + t;
        int v = (i < NN) ? degi[i] : 0;
        lds[t] = v;
        __syncthreads();
        for (int off = 1; off < 1024; off <<= 1) {
            int add = (t >= off) ? lds[t - off] : 0;
            __syncthreads();
            lds[t] += add;
            __syncthreads();
        }
        if (i < NN) {
            int exc = lds[t] - v + carry;
            rowptr[i] = exc; cursor[i] = exc;
            degf[i] = (float)(v > 1 ? v : 1);
        }
        __syncthreads();
        if (t == 0) carry += lds[1023];
        __syncthreads();
    }
    if (t == 0) rowptr[NN] = carry;
}

__global__ void k_fill(const int* __restrict__ dst, int* __restrict__ cursor,
                       int* __restrict__ elist) {
    int e = blockIdx.x * blockDim.x + threadIdx.x;
    if (e < NE) { int p = atomicAdd(&cursor[dst[e]], 1); elist[p] = e; }
}

__global__ void k_gstart(const int* __restrict__ batch, int* __restrict__ gstart) {
    int g = blockIdx.x * blockDim.x + threadIdx.x;
    if (g > NGB) return;
    int lo = 0, hi = NN;
    while (lo < hi) { int mid = (lo + hi) >> 1; if (batch[mid] < g) lo = mid + 1; else hi = mid; }
    gstart[g] = lo;
}

// ---------- NNConv: S build (bf16 S) ----------
// thread t: i-group ig=t>>4 (4 rows: i=ig*4+j), k-oct k8=t&15 (k=k8*8..+7)
__global__ __launch_bounds__(256) void k_sbuild(
    const float* __restrict__ out, const float* __restrict__ e_h,
    const int* __restrict__ src, const int* __restrict__ rowptr,
    const int* __restrict__ elist, u16* __restrict__ S_bf,
    float* __restrict__ Osum, int base) {
    int t = threadIdx.x;
    int n = base + blockIdx.x;
    int ig = t >> 4;
    int k8 = t & 15;
    int lane = t & 63;
    float acc[4][8];
#pragma unroll
    for (int j = 0; j < 4; ++j)
#pragma unroll
        for (int c = 0; c < 8; ++c) acc[j][c] = 0.f;
    float osum = 0.f;
    int r0 = rowptr[n], r1 = rowptr[n + 1];
    const float4* out4 = (const float4*)out;
    const float4* eh4p = (const float4*)e_h;
    for (int idx = r0; idx < r1; ++idx) {
        int e = elist[idx];
        int sn = src[e];
        float4 e0 = eh4p[(size_t)e * 32 + k8 * 2];
        float4 e1 = eh4p[(size_t)e * 32 + k8 * 2 + 1];
        float ehv[8] = {e0.x, e0.y, e0.z, e0.w, e1.x, e1.y, e1.z, e1.w};
        float4 f = out4[sn * 16 + ig];
        float fv[4] = {f.x, f.y, f.z, f.w};
#pragma unroll
        for (int j = 0; j < 4; ++j)
#pragma unroll
            for (int c = 0; c < 8; ++c) acc[j][c] += fv[j] * ehv[c];
        if (t < 64) osum += out[(size_t)sn * 64 + lane];
    }
    uint4v* S4 = (uint4v*)S_bf;
    size_t rb = (size_t)blockIdx.x * (SK / 8);
#pragma unroll
    for (int j = 0; j < 4; ++j)
        S4[rb + (size_t)(ig * 4 + j) * 16 + k8] = pack_bf8(acc[j]);
    if (t < 64) Osum[(size_t)n * 64 + lane] = osum;
}

// ---------- NNConv: MFMA GEMM, bf16-S x {Whi,Wlo}. 1 wave/block, M=32/wave ----------
__global__ __launch_bounds__(64) void k_gemm(
    const u16* __restrict__ S_bf, const u16* __restrict__ Whi,
    const u16* __restrict__ Wlo, float* __restrict__ P, int base) {
    int lane = threadIdx.x;
    int lrow = lane & 15, lkg = lane >> 4;
    int m0 = blockIdx.x * 32;
    int ks = blockIdx.y;
    int kbase = ks * (SK / KSPLIT);         // 512 kappa per split
    float4v acc[2][4];
#pragma unroll
    for (int ms = 0; ms < 2; ++ms)
#pragma unroll
        for (int nt = 0; nt < 4; ++nt) acc[ms][nt] = (float4v){0.f, 0.f, 0.f, 0.f};
    const short8v* bhv = (const short8v*)Whi;
    const short8v* blv = (const short8v*)Wlo;
    const u16* ar0 = S_bf + (size_t)(m0 + lrow) * SK + kbase + lkg * 8;
    const u16* ar1 = ar0 + (size_t)16 * SK;
    int kc0 = (kbase >> 3) + lkg;           // kchunk index (8 kappa per chunk)

#pragma unroll 2
    for (int kk = 0; kk < SK / KSPLIT / 32; ++kk) {    // 16 iterations, K=32 each
        short8v ah0 = *(const short8v*)(ar0 + kk * 32);
        short8v ah1 = *(const short8v*)(ar1 + kk * 32);
        int bo = (kc0 + kk * 4) * 64 + lrow;
        short8v bh[4], bl[4];
#pragma unroll
        for (int nt = 0; nt < 4; ++nt) { bh[nt] = bhv[bo + nt * 16]; bl[nt] = blv[bo + nt * 16]; }
#pragma unroll
        for (int nt = 0; nt < 4; ++nt) {
            acc[0][nt] = __builtin_amdgcn_mfma_f32_16x16x32_bf16(ah0, bh[nt], acc[0][nt], 0, 0, 0);
            acc[0][nt] = __builtin_amdgcn_mfma_f32_16x16x32_bf16(ah0, bl[nt], acc[0][nt], 0, 0, 0);
            acc[1][nt] = __builtin_amdgcn_mfma_f32_16x16x32_bf16(ah1, bh[nt], acc[1][nt], 0, 0, 0);
            acc[1][nt] = __builtin_amdgcn_mfma_f32_16x16x32_bf16(ah1, bl[nt], acc[1][nt], 0, 0, 0);
        }
    }
    int gbase = base + m0;
#pragma unroll
    for (int ms = 0; ms < 2; ++ms)
#pragma unroll
        for (int nt = 0; nt < 4; ++nt)
#pragma unroll
            for (int jj = 0; jj < 4; ++jj) {
                int row = ms * 16 + lkg * 4 + jj;   // C/D: row=(lane>>4)*4+reg  [m89 verified]
                int o = nt * 16 + lrow;             //      col=lane&15
                P[((size_t)ks * NN + gbase + row) * 64 + o] = acc[ms][nt][jj];
            }
}

// ---------- Psum reduce ----------
__global__ __launch_bounds__(256) void k_psum(const float* __restrict__ P,
                                              float* __restrict__ Psum) {
    int i = blockIdx.x * 256 + threadIdx.x;    // < NN*64/4
    const float4* P4 = (const float4*)P;
    float4 s = P4[i];
#pragma unroll
    for (int p = 1; p < KSPLIT; ++p) {
        float4 v = P4[(size_t)p * (NN * 16) + i];
        s.x += v.x; s.y += v.y; s.z += v.z; s.w += v.w;
    }
    ((float4*)Psum)[i] = s;
}

// ---------- m = relu((Psum + Osum@b2)/deg + out@root + cb)  [MFMA bf16x3] ----------
__global__ __launch_bounds__(64) void k_mrelu2(
    const float* __restrict__ out, const float* __restrict__ Osum,
    const float* __restrict__ Psum, const float* __restrict__ degf,
    const u16* __restrict__ Bmh, const u16* __restrict__ Bml,
    const float* __restrict__ conv_bias, float* __restrict__ M) {
    int lane = threadIdx.x;
    int lrow = lane & 15, lkg = lane >> 4;
    int n0 = blockIdx.x * 16;
    int arow = n0 + lrow;
    float invd = 1.f / degf[arow];
    float4v acc[4];
#pragma unroll
    for (int nt = 0; nt < 4; ++nt) acc[nt] = (float4v){0.f, 0.f, 0.f, 0.f};
    const short8v* bhv = (const short8v*)Bmh;
    const short8v* blv = (const short8v*)Bml;
#pragma unroll
    for (int s = 0; s < 4; ++s) {
        short8v ah, al;
        if (s < 2) pack8(&Osum[(size_t)arow * 64 + s * 32 + lkg * 8], invd, ah, al);
        else       pack8(&out[(size_t)arow * 64 + (s - 2) * 32 + lkg * 8], 1.f, ah, al);
        int kc = s * 4 + lkg;
#pragma unroll
        for (int nt = 0; nt < 4; ++nt) {
            short8v bh = bhv[kc * 64 + nt * 16 + lrow];
            short8v bl = blv[kc * 64 + nt * 16 + lrow];
            acc[nt] = __builtin_amdgcn_mfma_f32_16x16x32_bf16(ah, bh, acc[nt], 0, 0, 0);
            acc[nt] = __builtin_amdgcn_mfma_f32_16x16x32_bf16(al, bh, acc[nt], 0, 0, 0);
            acc[nt] = __builtin_amdgcn_mfma_f32_16x16x32_bf16(ah, bl, acc[nt], 0, 0, 0);
        }
    }
    float invd2[4];
#pragma unroll
    for (int jj = 0; jj < 4; ++jj) invd2[jj] = 1.f / degf[n0 + lkg * 4 + jj];
#pragma unroll
    for (int nt = 0; nt < 4; ++nt) {
        int o = nt * 16 + lrow;
        float cb = conv_bias[o];
#pragma unroll
        for (int jj = 0; jj < 4; ++jj) {
            int row = n0 + lkg * 4 + jj;
            M[(size_t)row * 64 + o] = fmaxf(acc[nt][jj] + Psum[(size_t)row * 64 + o] * invd2[jj] + cb, 0.f);
        }
    }
}

// ---------- GRU gates [MFMA bf16x3]; out <- h' ----------
__global__ __launch_bounds__(64) void k_gates2(
    float* __restrict__ out, const float* __restrict__ M,
    const u16* __restrict__ Bih_h, const u16* __restrict__ Bih_l,
    const u16* __restrict__ Bhh_h, const u16* __restrict__ Bhh_l,
    const float* __restrict__ gb_ih, const float* __restrict__ gb_hh) {
    int lane = threadIdx.x;
    int lrow = lane & 15, lkg = lane >> 4;
    int n0 = blockIdx.x * 16;
    int arow = n0 + lrow;
    float4v ai[12], ah_[12];
#pragma unroll
    for (int nt = 0; nt < 12; ++nt) { ai[nt] = (float4v){0.f, 0.f, 0.f, 0.f}; ah_[nt] = (float4v){0.f, 0.f, 0.f, 0.f}; }
    const short8v* bih_h = (const short8v*)Bih_h;
    const short8v* bih_l = (const short8v*)Bih_l;
    const short8v* bhh_h = (const short8v*)Bhh_h;
    const short8v* bhh_l = (const short8v*)Bhh_l;
#pragma unroll
    for (int s = 0; s < 2; ++s) {
        short8v mh, ml, hh, hl;
        pack8(&M[(size_t)arow * 64 + s * 32 + lkg * 8], 1.f, mh, ml);
        pack8(&out[(size_t)arow * 64 + s * 32 + lkg * 8], 1.f, hh, hl);
        int kc = s * 4 + lkg;
#pragma unroll
        for (int nt = 0; nt < 12; ++nt) {
            int bo = kc * 192 + nt * 16 + lrow;
            short8v b1 = bih_h[bo], b2 = bih_l[bo];
            ai[nt] = __builtin_amdgcn_mfma_f32_16x16x32_bf16(mh, b1, ai[nt], 0, 0, 0);
            ai[nt] = __builtin_amdgcn_mfma_f32_16x16x32_bf16(ml, b1, ai[nt], 0, 0, 0);
            ai[nt] = __builtin_amdgcn_mfma_f32_16x16x32_bf16(mh, b2, ai[nt], 0, 0, 0);
            short8v b3 = bhh_h[bo], b4 = bhh_l[bo];
            ah_[nt] = __builtin_amdgcn_mfma_f32_16x16x32_bf16(hh, b3, ah_[nt], 0, 0, 0);
            ah_[nt] = __builtin_amdgcn_mfma_f32_16x16x32_bf16(hl, b3, ah_[nt], 0, 0, 0);
            ah_[nt] = __builtin_amdgcn_mfma_f32_16x16x32_bf16(hh, b4, ah_[nt], 0, 0, 0);
        }
    }
#pragma unroll
    for (int nt = 0; nt < 4; ++nt) {
        int o = nt * 16 + lrow;
        float bi0 = gb_ih[o], bi1 = gb_ih[64 + o], bi2 = gb_ih[128 + o];
        float bh0 = gb_hh[o], bh1 = gb_hh[64 + o], bh2 = gb_hh[128 + o];
#pragma unroll
        for (int jj = 0; jj < 4; ++jj) {
            int row = n0 + lkg * 4 + jj;
            float ir = ai[nt][jj] + bi0,  hr = ah_[nt][jj] + bh0;
            float iz = ai[nt + 4][jj] + bi1, hz = ah_[nt + 4][jj] + bh1;
            float in_ = ai[nt + 8][jj] + bi2, hn = ah_[nt + 8][jj] + bh2;
            float r = sigmoidf_(ir + hr);
            float z = sigmoidf_(iz + hz);
            float nv = tanhf(in_ + r * hn);
            float ho = out[(size_t)row * 64 + o];
            out[(size_t)row * 64 + o] = (1.f - z) * nv + z * ho;
        }
    }
}

// ---------- Set2Set ----------
__global__ __launch_bounds__(256) void k_lstm(
    const float* __restrict__ q_star, float* __restrict__ hs, float* __restrict__ cs,
    const float* __restrict__ w_ih, const float* __restrict__ w_hh,
    const float* __restrict__ b_ih, const float* __restrict__ b_hh) {
    __shared__ float qs[128], hr[64], gates[256];
    int bg = blockIdx.x, t = threadIdx.x;
    if (t < 128) qs[t] = q_star[bg * 128 + t];
    else if (t < 192) hr[t - 128] = hs[bg * 64 + (t - 128)];
    __syncthreads();
    float s = b_ih[t] + b_hh[t];
    const float4* wi = (const float4*)&w_ih[t * 128];
#pragma unroll
    for (int i = 0; i < 32; ++i) {
        float4 a = wi[i];
        s += qs[i * 4] * a.x + qs[i * 4 + 1] * a.y + qs[i * 4 + 2] * a.z + qs[i * 4 + 3] * a.w;
    }
    const float4* wh = (const float4*)&w_hh[t * 64];
#pragma unroll
    for (int i = 0; i < 16; ++i) {
        float4 a = wh[i];
        s += hr[i * 4] * a.x + hr[i * 4 + 1] * a.y + hr[i * 4 + 2] * a.z + hr[i * 4 + 3] * a.w;
    }
    gates[t] = s;
    __syncthreads();
    if (t < 64) {
        float ig = sigmoidf_(gates[t]);
        float fg = sigmoidf_(gates[64 + t]);
        float gg = tanhf(gates[128 + t]);
        float og = sigmoidf_(gates[192 + t]);
        float c = fg * cs[bg * 64 + t] + ig * gg;
        float hv = og * tanhf(c);
        cs[bg * 64 + t] = c;
        hs[bg * 64 + t] = hv;
    }
}

__global__ void k_attn(const float* __restrict__ out, const int* __restrict__ gstart,
                       const float* __restrict__ hs, float* __restrict__ q_star) {
    int g = blockIdx.x, o = threadIdx.x;
    float q = hs[g * 64 + o];
    int s0 = gstart[g], s1 = gstart[g + 1];
    float mmax = -1e30f;
    for (int i = s0; i < s1; ++i) {
        float p = out[(size_t)i * 64 + o] * q;
#pragma unroll
        for (int off = 32; off >= 1; off >>= 1) p += __shfl_xor(p, off);
        mmax = fmaxf(mmax, p);
    }
    float ssum = 0.f, racc = 0.f;
    for (int i = s0; i < s1; ++i) {
        float ov = out[(size_t)i * 64 + o];
        float p = ov * q;
#pragma unroll
        for (int off = 32; off >= 1; off >>= 1) p += __shfl_xor(p, off);
        float w = expf(p - mmax);
        ssum += w;
        racc += w * ov;
    }
    q_star[g * 128 + o] = q;
    q_star[g * 128 + 64 + o] = (s1 > s0) ? (racc / ssum) : 0.f;
}

__global__ void k_final(const float* __restrict__ q_star, const float* __restrict__ w1,
                        const float* __restrict__ b1, const float* __restrict__ w2,
                        const float* __restrict__ b2, float* __restrict__ yout) {
    __shared__ float qs[128];
    int g = blockIdx.x, t = threadIdx.x;
    qs[t] = q_star[g * 128 + t];
    qs[64 + t] = q_star[g * 128 + 64 + t];
    __syncthreads();
    float s = b1[t];
    const float4* w = (const float4*)&w1[t * 128];
#pragma unroll
    for (int i = 0; i < 32; ++i) {
        float4 a = w[i];
        s += qs[i * 4] * a.x + qs[i * 4 + 1] * a.y + qs[i * 4 + 2] * a.z + qs[i * 4 + 3] * a.w;
    }
    s = fmaxf(s, 0.f) * w2[t];
#pragma unroll
    for (int off = 32; off >= 1; off >>= 1) s += __shfl_xor(s, off);
    if (t == 0) yout[g] = s + b2[0];
}

extern "C" void kernel_launch(void* const* d_in, const int* in_sizes, int n_in,
                              void* d_out, int out_size, void* d_ws, size_t ws_size,
                              hipStream_t stream) {
    (void)in_sizes; (void)n_in; (void)out_size;
    const float* x        = (const float*)d_in[0];
    const float* eattr    = (const float*)d_in[1];
    const int*   ei       = (const int*)d_in[2];
    const int*   batch    = (const int*)d_in[3];
    const float* lin0_w   = (const float*)d_in[4];
    const float* lin0_b   = (const float*)d_in[5];
    const float* nn_w1    = (const float*)d_in[6];
    const float* nn_b1    = (const float*)d_in[7];
    const float* nn_w2    = (const float*)d_in[8];
    const float* nn_b2    = (const float*)d_in[9];
    const float* conv_root= (const float*)d_in[10];
    const float* conv_bias= (const float*)d_in[11];
    const float* gw_ih    = (const float*)d_in[12];
    const float* gw_hh    = (const float*)d_in[13];
    const float* gb_ih    = (const float*)d_in[14];
    const float* gb_hh    = (const float*)d_in[15];
    const float* lw_ih    = (const float*)d_in[16];
    const float* lw_hh    = (const float*)d_in[17];
    const float* lb_ih    = (const float*)d_in[18];
    const float* lb_hh    = (const float*)d_in[19];
    const float* lin1_w   = (const float*)d_in[20];
    const float* lin1_b   = (const float*)d_in[21];
    const float* lin2_w   = (const float*)d_in[22];
    const float* lin2_b   = (const float*)d_in[23];
    const int* src = ei;
    const int* dst = ei + NE;

    char* w = (char*)d_ws;
    auto alloc = [&](size_t bytes) { char* p = w; w += (bytes + 255) & ~(size_t)255; return p; };
    float* out    = (float*)alloc((size_t)NN * 64 * 4);
    float* e_h    = (float*)alloc((size_t)NE * 128 * 4);
    u16*   Whi    = (u16*)alloc((size_t)64 * SK * 2);
    u16*   Wlo    = (u16*)alloc((size_t)64 * SK * 2);
    float* P      = (float*)alloc((size_t)KSPLIT * NN * 64 * 4);
    float* Psum   = (float*)alloc((size_t)NN * 64 * 4);
    float* Osum   = (float*)alloc((size_t)NN * 64 * 4);
    float* M      = (float*)alloc((size_t)NN * 64 * 4);
    u16*   Bmh    = (u16*)alloc((size_t)8192 * 2);
    u16*   Bml    = (u16*)alloc((size_t)8192 * 2);
    u16*   Bih_h  = (u16*)alloc((size_t)12288 * 2);
    u16*   Bih_l  = (u16*)alloc((size_t)12288 * 2);
    u16*   Bhh_h  = (u16*)alloc((size_t)12288 * 2);
    u16*   Bhh_l  = (u16*)alloc((size_t)12288 * 2);
    float* degf   = (float*)alloc((size_t)NN * 4);
    int*   degi   = (int*)alloc((size_t)NN * 4);
    int*   rowptr = (int*)alloc((size_t)(NN + 1) * 4);
    int*   cursor = (int*)alloc((size_t)(NN + 1) * 4);
    int*   elist  = (int*)alloc((size_t)NE * 4);
    int*   gstart = (int*)alloc((size_t)(NGB + 1) * 4);
    float* q_star = (float*)alloc((size_t)NGB * 128 * 4);
    float* hs     = (float*)alloc((size_t)NGB * 64 * 4);
    float* cs     = (float*)alloc((size_t)NGB * 64 * 4);
    size_t used = (size_t)(w - (char*)d_ws);
    size_t avail = ws_size > used ? ws_size - used : 0;
    size_t maxrows = avail / ((size_t)SK * 2);      // bf16 S: 16 KB per row
    int chunkN = maxrows > (size_t)NN ? NN : (int)maxrows;
    chunkN = (chunkN / 64) * 64;
    if (chunkN < 64) chunkN = 64;
    u16* S_bf = (u16*)w;

    hipMemsetAsync(degi, 0, (size_t)NN * 4, stream);
    hipMemsetAsync(q_star, 0, (size_t)NGB * 128 * 4, stream);
    hipMemsetAsync(hs, 0, (size_t)NGB * 64 * 4, stream);
    hipMemsetAsync(cs, 0, (size_t)NGB * 64 * 4, stream);

    k_lin0<<<NN, 64, 0, stream>>>(x, lin0_w, lin0_b, out);
    k_eh<<<NE / 2, 256, 0, stream>>>(eattr, nn_w1, nn_b1, e_h);
    k_wsplit<<<(64 * SK) / 256, 256, 0, stream>>>(nn_w2, Whi, Wlo);
    k_prep_mw<<<32, 256, 0, stream>>>(conv_root, nn_b2, Bmh, Bml);
    k_prep_gb<<<96, 256, 0, stream>>>(gw_ih, gw_hh, Bih_h, Bih_l, Bhh_h, Bhh_l);
    k_deg<<<(NE + 255) / 256, 256, 0, stream>>>(dst, degi);
    k_scan<<<1, 1024, 0, stream>>>(degi, rowptr, cursor, degf);
    k_fill<<<(NE + 255) / 256, 256, 0, stream>>>(dst, cursor, elist);
    k_gstart<<<5, 64, 0, stream>>>(batch, gstart);

    for (int it = 0; it < 3; ++it) {
        for (int cb = 0; cb < NN; cb += chunkN) {
            int cn = (NN - cb) < chunkN ? (NN - cb) : chunkN;
            k_sbuild<<<cn, 256, 0, stream>>>(out, e_h, src, rowptr, elist, S_bf, Osum, cb);
            k_gemm<<<dim3(cn / 32, KSPLIT), 64, 0, stream>>>(S_bf, Whi, Wlo, P, cb);
        }
        k_psum<<<NN / 16, 256, 0, stream>>>(P, Psum);
        k_mrelu2<<<NN / 16, 64, 0, stream>>>(out, Osum, Psum, degf, Bmh, Bml, conv_bias, M);
        k_gates2<<<NN / 16, 64, 0, stream>>>(out, M, Bih_h, Bih_l, Bhh_h, Bhh_l, gb_ih, gb_hh);
    }

    for (int st = 0; st < 3; ++st) {
        k_lstm<<<NGB, 256, 0, stream>>>(q_star, hs, cs, lw_ih, lw_hh, lb_ih, lb_hh);
        k_attn<<<NGB, 64, 0, stream>>>(out, gstart, hs, q_star);
    }
    k_final<<<NGB, 64, 0, stream>>>(q_star, lin1_w, lin1_b, lin2_w, lin2_b, (float*)d_out);
}

// Round 13
// 403.016 us; speedup vs baseline: 3.7688x; 1.2331x over previous
//
#include <hip/hip_runtime.h>
#include <math.h>

#define NN 8000
#define NE 40000
#define NGB 256
#define SK 8192
#define KSPLIT 32

typedef unsigned int u32;
typedef unsigned short u16;
typedef __attribute__((ext_vector_type(8))) short short8v;
typedef __attribute__((ext_vector_type(4))) float float4v;
typedef __attribute__((ext_vector_type(4))) unsigned int uint4v;

__device__ __forceinline__ float sigmoidf_(float x) { return 1.f / (1.f + expf(-x)); }

__device__ __forceinline__ u32 bf16_rne(float f) {
    u32 x = __builtin_bit_cast(u32, f);
    return (x + 0x7FFFu + ((x >> 16) & 1u)) >> 16;
}

// pack 8 floats -> 8 bf16 (RNE) in a uint4
__device__ __forceinline__ uint4v pack_bf8(const float v[8]) {
    u32 h[8];
#pragma unroll
    for (int j = 0; j < 8; ++j) h[j] = bf16_rne(v[j]);
    return (uint4v){ h[0] | (h[1] << 16), h[2] | (h[3] << 16),
                     h[4] | (h[5] << 16), h[6] | (h[7] << 16) };
}

// load 8 consecutive floats, scale, split into hi/lo bf16x8 fragments (for tiny GEMMs)
__device__ __forceinline__ void pack8(const float* p, float scale, short8v& ah, short8v& al) {
    float v[8];
#pragma unroll
    for (int j = 0; j < 8; ++j) v[j] = p[j];
    u32 hu[8], lu[8];
#pragma unroll
    for (int j = 0; j < 8; ++j) {
        float s = v[j] * scale;
        hu[j] = bf16_rne(s);
        float fh = __builtin_bit_cast(float, hu[j] << 16);
        lu[j] = bf16_rne(s - fh);
    }
    uint4v hset = { hu[0] | (hu[1] << 16), hu[2] | (hu[3] << 16),
                    hu[4] | (hu[5] << 16), hu[6] | (hu[7] << 16) };
    uint4v lset = { lu[0] | (lu[1] << 16), lu[2] | (lu[3] << 16),
                    lu[4] | (lu[5] << 16), lu[6] | (lu[7] << 16) };
    ah = __builtin_bit_cast(short8v, hset);
    al = __builtin_bit_cast(short8v, lset);
}

// ---------- small setup kernels ----------

__global__ void k_lin0(const float* __restrict__ x, const float* __restrict__ w,
                       const float* __restrict__ b, float* __restrict__ out) {
    __shared__ float xr[21];
    int n = blockIdx.x, t = threadIdx.x;
    if (t < 21) xr[t] = x[n * 21 + t];
    __syncthreads();
    float s = b[t];
#pragma unroll
    for (int c = 0; c < 21; ++c) s += xr[c] * w[t * 21 + c];
    out[n * 64 + t] = fmaxf(s, 0.f);
}

__global__ void k_eh(const float* __restrict__ ea, const float* __restrict__ w1,
                     const float* __restrict__ b1, float* __restrict__ e_h) {
    __shared__ float a[2][16];
    int t = threadIdx.x;
    int e0 = blockIdx.x * 2;
    if (t < 32) a[t >> 4][t & 15] = ea[(e0 + (t >> 4)) * 16 + (t & 15)];
    __syncthreads();
    int sub = t >> 7, j = t & 127;
    float s = b1[j];
#pragma unroll
    for (int c = 0; c < 16; ++c) s += a[sub][c] * w1[j * 16 + c];
    e_h[(size_t)(e0 + sub) * 128 + j] = fmaxf(s, 0.f);
}

// merged weight prep: W2T hi/lo (524288) + mrelu B (8192) + gate B (24576)
__global__ void k_prep(const float* __restrict__ nn_w2, const float* __restrict__ conv_root,
                       const float* __restrict__ nn_b2, const float* __restrict__ w_ih,
                       const float* __restrict__ w_hh,
                       u16* __restrict__ Whi, u16* __restrict__ Wlo,
                       u16* __restrict__ Bmh, u16* __restrict__ Bml,
                       u16* __restrict__ Bih_h, u16* __restrict__ Bih_l,
                       u16* __restrict__ Bhh_h, u16* __restrict__ Bhh_l) {
    int idx = blockIdx.x * 256 + threadIdx.x;
    if (idx < 524288) {
        int o = idx >> 13, kap = idx & 8191;
        int i = kap >> 7, k = kap & 127;
        float v = nn_w2[(size_t)((i << 6) + o) * 128 + k];
        u32 h = bf16_rne(v);
        float fh = __builtin_bit_cast(float, h << 16);
        u32 l = bf16_rne(v - fh);
        int pos = ((kap >> 3) * 64 + o) * 8 + (kap & 7);
        Whi[pos] = (u16)h; Wlo[pos] = (u16)l;
    } else if (idx < 524288 + 8192) {
        int i2 = idx - 524288;
        int k = i2 >> 6, o = i2 & 63;
        float v = (k < 64) ? nn_b2[k * 64 + o] : conv_root[(k - 64) * 64 + o];
        u32 h = bf16_rne(v);
        float fh = __builtin_bit_cast(float, h << 16);
        u32 l = bf16_rne(v - fh);
        int pos = ((k >> 3) * 64 + o) * 8 + (k & 7);
        Bmh[pos] = (u16)h; Bml[pos] = (u16)l;
    } else if (idx < 524288 + 8192 + 24576) {
        int i3 = idx - 524288 - 8192;
        int half = i3 >= 12288;
        int i2 = i3 - half * 12288;
        int o = i2 % 192, k = i2 / 192;
        float v = half ? w_hh[o * 64 + k] : w_ih[o * 64 + k];
        u32 h = bf16_rne(v);
        float fh = __builtin_bit_cast(float, h << 16);
        u32 l = bf16_rne(v - fh);
        int pos = ((k >> 3) * 192 + o) * 8 + (k & 7);
        if (half) { Bhh_h[pos] = (u16)h; Bhh_l[pos] = (u16)l; }
        else      { Bih_h[pos] = (u16)h; Bih_l[pos] = (u16)l; }
    }
}

__global__ void k_deg(const int* __restrict__ dst, int* __restrict__ degi) {
    int e = blockIdx.x * blockDim.x + threadIdx.x;
    if (e < NE) atomicAdd(&degi[dst[e]], 1);
}

__global__ void k_scan(const int* __restrict__ degi, int* __restrict__ rowptr,
                       int* __restrict__ cursor, float* __restrict__ degf) {
    __shared__ int lds[1024];
    __shared__ int carry;
    int t = threadIdx.x;
    if (t == 0) carry = 0;
    __syncthreads();
    for (int base = 0; base < NN; base += 1024) {
        int i = base + t;
        int v = (i < NN) ? degi[i] : 0;
        lds[t] = v;
        __syncthreads();
        for (int off = 1; off < 1024; off <<= 1) {
            int add = (t >= off) ? lds[t - off] : 0;
            __syncthreads();
            lds[t] += add;
            __syncthreads();
        }
        if (i < NN) {
            int exc = lds[t] - v + carry;
            rowptr[i] = exc; cursor[i] = exc;
            degf[i] = (float)(v > 1 ? v : 1);
        }
        __syncthreads();
        if (t == 0) carry += lds[1023];
        __syncthreads();
    }
    if (t == 0) rowptr[NN] = carry;
}

__global__ void k_fill(const int* __restrict__ dst, int* __restrict__ cursor,
                       int* __restrict__ elist) {
    int e = blockIdx.x * blockDim.x + threadIdx.x;
    if (e < NE) { int p = atomicAdd(&cursor[dst[e]], 1); elist[p] = e; }
}

__global__ void k_gstart(const int* __restrict__ batch, int* __restrict__ gstart) {
    int g = blockIdx.x * blockDim.x + threadIdx.x;
    if (g > NGB) return;
    int lo = 0, hi = NN;
    while (lo < hi) { int mid = (lo + hi) >> 1; if (batch[mid] < g) lo = mid + 1; else hi = mid; }
    gstart[g] = lo;
}

// ---------- NNConv: S build (bf16 S) ----------
__global__ __launch_bounds__(256) void k_sbuild(
    const float* __restrict__ out, const float* __restrict__ e_h,
    const int* __restrict__ src, const int* __restrict__ rowptr,
    const int* __restrict__ elist, u16* __restrict__ S_bf,
    float* __restrict__ Osum, int base) {
    int t = threadIdx.x;
    int n = base + blockIdx.x;
    int ig = t >> 4;
    int k8 = t & 15;
    int lane = t & 63;
    float acc[4][8];
#pragma unroll
    for (int j = 0; j < 4; ++j)
#pragma unroll
        for (int c = 0; c < 8; ++c) acc[j][c] = 0.f;
    float osum = 0.f;
    int r0 = rowptr[n], r1 = rowptr[n + 1];
    const float4* out4 = (const float4*)out;
    const float4* eh4p = (const float4*)e_h;
    for (int idx = r0; idx < r1; ++idx) {
        int e = elist[idx];
        int sn = src[e];
        float4 e0 = eh4p[(size_t)e * 32 + k8 * 2];
        float4 e1 = eh4p[(size_t)e * 32 + k8 * 2 + 1];
        float ehv[8] = {e0.x, e0.y, e0.z, e0.w, e1.x, e1.y, e1.z, e1.w};
        float4 f = out4[sn * 16 + ig];
        float fv[4] = {f.x, f.y, f.z, f.w};
#pragma unroll
        for (int j = 0; j < 4; ++j)
#pragma unroll
            for (int c = 0; c < 8; ++c) acc[j][c] += fv[j] * ehv[c];
        if (t < 64) osum += out[(size_t)sn * 64 + lane];
    }
    uint4v* S4 = (uint4v*)S_bf;
    size_t rb = (size_t)blockIdx.x * (SK / 8);
#pragma unroll
    for (int j = 0; j < 4; ++j)
        S4[rb + (size_t)(ig * 4 + j) * 16 + k8] = pack_bf8(acc[j]);
    if (t < 64) Osum[(size_t)n * 64 + lane] = osum;
}

// ---------- NNConv: MFMA GEMM. 1 wave/block, M=32/wave, KSPLIT=32 ----------
__global__ __launch_bounds__(64) void k_gemm(
    const u16* __restrict__ S_bf, const u16* __restrict__ Whi,
    const u16* __restrict__ Wlo, float* __restrict__ P, int base) {
    int lane = threadIdx.x;
    int lrow = lane & 15, lkg = lane >> 4;
    int m0 = blockIdx.x * 32;
    int ks = blockIdx.y;
    int kbase = ks * (SK / KSPLIT);         // 256 kappa per split
    float4v acc[2][4];
#pragma unroll
    for (int ms = 0; ms < 2; ++ms)
#pragma unroll
        for (int nt = 0; nt < 4; ++nt) acc[ms][nt] = (float4v){0.f, 0.f, 0.f, 0.f};
    const short8v* bhv = (const short8v*)Whi;
    const short8v* blv = (const short8v*)Wlo;
    const u16* ar0 = S_bf + (size_t)(m0 + lrow) * SK + kbase + lkg * 8;
    const u16* ar1 = ar0 + (size_t)16 * SK;
    int kc0 = (kbase >> 3) + lkg;           // kchunk index (8 kappa per chunk)

#pragma unroll 2
    for (int kk = 0; kk < SK / KSPLIT / 32; ++kk) {    // 8 iterations, K=32 each
        short8v ah0 = *(const short8v*)(ar0 + kk * 32);
        short8v ah1 = *(const short8v*)(ar1 + kk * 32);
        int bo = (kc0 + kk * 4) * 64 + lrow;
        short8v bh[4], bl[4];
#pragma unroll
        for (int nt = 0; nt < 4; ++nt) { bh[nt] = bhv[bo + nt * 16]; bl[nt] = blv[bo + nt * 16]; }
#pragma unroll
        for (int nt = 0; nt < 4; ++nt) {
            acc[0][nt] = __builtin_amdgcn_mfma_f32_16x16x32_bf16(ah0, bh[nt], acc[0][nt], 0, 0, 0);
            acc[0][nt] = __builtin_amdgcn_mfma_f32_16x16x32_bf16(ah0, bl[nt], acc[0][nt], 0, 0, 0);
            acc[1][nt] = __builtin_amdgcn_mfma_f32_16x16x32_bf16(ah1, bh[nt], acc[1][nt], 0, 0, 0);
            acc[1][nt] = __builtin_amdgcn_mfma_f32_16x16x32_bf16(ah1, bl[nt], acc[1][nt], 0, 0, 0);
        }
    }
    int gbase = base + m0;
#pragma unroll
    for (int ms = 0; ms < 2; ++ms)
#pragma unroll
        for (int nt = 0; nt < 4; ++nt)
#pragma unroll
            for (int jj = 0; jj < 4; ++jj) {
                int row = ms * 16 + lkg * 4 + jj;   // C/D: row=(lane>>4)*4+reg  [m89 verified]
                int o = nt * 16 + lrow;             //      col=lane&15
                P[((size_t)ks * NN + gbase + row) * 64 + o] = acc[ms][nt][jj];
            }
}

// ---------- fused node update: psum + mrelu(MFMA) + GRU gates(MFMA); out <- h' ----------
__global__ __launch_bounds__(64) void k_node(
    float* __restrict__ out, const float* __restrict__ P,
    const float* __restrict__ Osum, const float* __restrict__ degf,
    const u16* __restrict__ Bmh, const u16* __restrict__ Bml,
    const u16* __restrict__ Bih_h, const u16* __restrict__ Bih_l,
    const u16* __restrict__ Bhh_h, const u16* __restrict__ Bhh_l,
    const float* __restrict__ conv_bias,
    const float* __restrict__ gb_ih, const float* __restrict__ gb_hh) {
    __shared__ float lds[16][68];     // psum, then M (padded stride 68)
    int lane = threadIdx.x;
    int lrow = lane & 15, lkg = lane >> 4;
    int n0 = blockIdx.x * 16;
    int arow = n0 + lrow;

    // phase 1: Psum[arow][lkg*16 .. +15] = sum over KSPLIT planes (coalesced)
    {
        const float4* P4 = (const float4*)P;
        float4 ps[4];
#pragma unroll
        for (int c = 0; c < 4; ++c) ps[c] = make_float4(0.f, 0.f, 0.f, 0.f);
        for (int p = 0; p < KSPLIT; ++p) {
#pragma unroll
            for (int c = 0; c < 4; ++c) {
                float4 v = P4[(size_t)p * (NN * 16) + (size_t)arow * 16 + lkg * 4 + c];
                ps[c].x += v.x; ps[c].y += v.y; ps[c].z += v.z; ps[c].w += v.w;
            }
        }
#pragma unroll
        for (int c = 0; c < 4; ++c)
            *(float4*)&lds[lrow][lkg * 16 + c * 4] = ps[c];
    }
    __syncthreads();

    // phase 2: mrelu MFMA (A rows: Osum/deg then out; B: nn_b2 then conv_root)
    float invd = 1.f / degf[arow];
    float4v acc[4];
#pragma unroll
    for (int nt = 0; nt < 4; ++nt) acc[nt] = (float4v){0.f, 0.f, 0.f, 0.f};
    const short8v* bhv = (const short8v*)Bmh;
    const short8v* blv = (const short8v*)Bml;
#pragma unroll
    for (int s = 0; s < 4; ++s) {
        short8v ah, al;
        if (s < 2) pack8(&Osum[(size_t)arow * 64 + s * 32 + lkg * 8], invd, ah, al);
        else       pack8(&out[(size_t)arow * 64 + (s - 2) * 32 + lkg * 8], 1.f, ah, al);
        int kc = s * 4 + lkg;
#pragma unroll
        for (int nt = 0; nt < 4; ++nt) {
            short8v bh = bhv[kc * 64 + nt * 16 + lrow];
            short8v bl = blv[kc * 64 + nt * 16 + lrow];
            acc[nt] = __builtin_amdgcn_mfma_f32_16x16x32_bf16(ah, bh, acc[nt], 0, 0, 0);
            acc[nt] = __builtin_amdgcn_mfma_f32_16x16x32_bf16(al, bh, acc[nt], 0, 0, 0);
            acc[nt] = __builtin_amdgcn_mfma_f32_16x16x32_bf16(ah, bl, acc[nt], 0, 0, 0);
        }
    }
    float invd2[4];
#pragma unroll
    for (int jj = 0; jj < 4; ++jj) invd2[jj] = 1.f / degf[n0 + lkg * 4 + jj];
    float mval[4][4];
#pragma unroll
    for (int nt = 0; nt < 4; ++nt) {
        int o = nt * 16 + lrow;
        float cb = conv_bias[o];
#pragma unroll
        for (int jj = 0; jj < 4; ++jj)
            mval[nt][jj] = fmaxf(acc[nt][jj] + lds[lkg * 4 + jj][o] * invd2[jj] + cb, 0.f);
    }
    __syncthreads();   // all psum reads done
#pragma unroll
    for (int nt = 0; nt < 4; ++nt)
#pragma unroll
        for (int jj = 0; jj < 4; ++jj)
            lds[lkg * 4 + jj][nt * 16 + lrow] = mval[nt][jj];
    __syncthreads();   // M ready in LDS

    // phase 3: GRU gates MFMA
    float4v ai[12], ah_[12];
#pragma unroll
    for (int nt = 0; nt < 12; ++nt) { ai[nt] = (float4v){0.f, 0.f, 0.f, 0.f}; ah_[nt] = (float4v){0.f, 0.f, 0.f, 0.f}; }
    const short8v* bih_h = (const short8v*)Bih_h;
    const short8v* bih_l = (const short8v*)Bih_l;
    const short8v* bhh_h = (const short8v*)Bhh_h;
    const short8v* bhh_l = (const short8v*)Bhh_l;
#pragma unroll
    for (int s = 0; s < 2; ++s) {
        short8v mh, ml, hh, hl;
        pack8(&lds[lrow][s * 32 + lkg * 8], 1.f, mh, ml);
        pack8(&out[(size_t)arow * 64 + s * 32 + lkg * 8], 1.f, hh, hl);
        int kc = s * 4 + lkg;
#pragma unroll
        for (int nt = 0; nt < 12; ++nt) {
            int bo = kc * 192 + nt * 16 + lrow;
            short8v b1 = bih_h[bo], b2 = bih_l[bo];
            ai[nt] = __builtin_amdgcn_mfma_f32_16x16x32_bf16(mh, b1, ai[nt], 0, 0, 0);
            ai[nt] = __builtin_amdgcn_mfma_f32_16x16x32_bf16(ml, b1, ai[nt], 0, 0, 0);
            ai[nt] = __builtin_amdgcn_mfma_f32_16x16x32_bf16(mh, b2, ai[nt], 0, 0, 0);
            short8v b3 = bhh_h[bo], b4 = bhh_l[bo];
            ah_[nt] = __builtin_amdgcn_mfma_f32_16x16x32_bf16(hh, b3, ah_[nt], 0, 0, 0);
            ah_[nt] = __builtin_amdgcn_mfma_f32_16x16x32_bf16(hl, b3, ah_[nt], 0, 0, 0);
            ah_[nt] = __builtin_amdgcn_mfma_f32_16x16x32_bf16(hh, b4, ah_[nt], 0, 0, 0);
        }
    }
#pragma unroll
    for (int nt = 0; nt < 4; ++nt) {
        int o = nt * 16 + lrow;
        float bi0 = gb_ih[o], bi1 = gb_ih[64 + o], bi2 = gb_ih[128 + o];
        float bh0 = gb_hh[o], bh1 = gb_hh[64 + o], bh2 = gb_hh[128 + o];
#pragma unroll
        for (int jj = 0; jj < 4; ++jj) {
            int row = n0 + lkg * 4 + jj;
            float ir = ai[nt][jj] + bi0,  hr = ah_[nt][jj] + bh0;
            float iz = ai[nt + 4][jj] + bi1, hz = ah_[nt + 4][jj] + bh1;
            float in_ = ai[nt + 8][jj] + bi2, hn = ah_[nt + 8][jj] + bh2;
            float r = sigmoidf_(ir + hr);
            float z = sigmoidf_(iz + hz);
            float nv = tanhf(in_ + r * hn);
            float ho = out[(size_t)row * 64 + o];
            out[(size_t)row * 64 + o] = (1.f - z) * nv + z * ho;
        }
    }
}

// ---------- fused Set2Set: 3x(LSTM+attention) + final linear, one block per graph ----------
__global__ __launch_bounds__(256) void k_s2s(
    const float* __restrict__ out, const int* __restrict__ gstart,
    const float* __restrict__ lw_ih, const float* __restrict__ lw_hh,
    const float* __restrict__ lb_ih, const float* __restrict__ lb_hh,
    const float* __restrict__ lin1_w, const float* __restrict__ lin1_b,
    const float* __restrict__ lin2_w, const float* __restrict__ lin2_b,
    float* __restrict__ yout) {
    __shared__ float qs[128], hsL[64], csL[64], gates[256];
    __shared__ float pv[384];
    __shared__ float red[4][64];
    __shared__ float sswv[4], mmaxw[4];
    int g = blockIdx.x, t = threadIdx.x, wv = t >> 6, lane = t & 63;
    int s0 = gstart[g], s1 = gstart[g + 1];
    if (t < 128) qs[t] = 0.f;
    if (t < 64) { hsL[t] = 0.f; csL[t] = 0.f; }
    __syncthreads();
    for (int st = 0; st < 3; ++st) {
        // LSTM gates
        float s = lb_ih[t] + lb_hh[t];
        const float4* wi = (const float4*)&lw_ih[t * 128];
#pragma unroll
        for (int i = 0; i < 32; ++i) {
            float4 a = wi[i];
            s += qs[i * 4] * a.x + qs[i * 4 + 1] * a.y + qs[i * 4 + 2] * a.z + qs[i * 4 + 3] * a.w;
        }
        const float4* wh = (const float4*)&lw_hh[t * 64];
#pragma unroll
        for (int i = 0; i < 16; ++i) {
            float4 a = wh[i];
            s += hsL[i * 4] * a.x + hsL[i * 4 + 1] * a.y + hsL[i * 4 + 2] * a.z + hsL[i * 4 + 3] * a.w;
        }
        gates[t] = s;
        __syncthreads();
        if (t < 64) {
            float ig = sigmoidf_(gates[t]);
            float fg = sigmoidf_(gates[64 + t]);
            float gg = tanhf(gates[128 + t]);
            float og = sigmoidf_(gates[192 + t]);
            float c = fg * csL[t] + ig * gg;
            csL[t] = c;
            hsL[t] = og * tanhf(c);
        }
        __syncthreads();
        // attention pass A: logits + max
        float wmax = -1e30f;
        for (int i = s0 + wv; i < s1; i += 4) {
            float p = out[(size_t)i * 64 + lane] * hsL[lane];
#pragma unroll
            for (int off = 32; off >= 1; off >>= 1) p += __shfl_xor(p, off);
            if (lane == 0) pv[i - s0] = p;
            wmax = fmaxf(wmax, p);
        }
        if (lane == 0) mmaxw[wv] = wmax;
        __syncthreads();
        float mmax = fmaxf(fmaxf(mmaxw[0], mmaxw[1]), fmaxf(mmaxw[2], mmaxw[3]));
        // pass B: weighted sums
        float ssum = 0.f, racc = 0.f;
        for (int i = s0 + wv; i < s1; i += 4) {
            float w = expf(pv[i - s0] - mmax);
            ssum += w;
            racc += w * out[(size_t)i * 64 + lane];
        }
        red[wv][lane] = racc;
        if (lane == 0) sswv[wv] = ssum;
        __syncthreads();
        if (t < 64) {
            float rt = red[0][t] + red[1][t] + red[2][t] + red[3][t];
            float stot = sswv[0] + sswv[1] + sswv[2] + sswv[3];
            qs[t] = hsL[t];
            qs[64 + t] = (s1 > s0) ? rt / stot : 0.f;
        }
        __syncthreads();
    }
    // final: y = relu(q_star @ lin1^T + b1) @ lin2^T + b2
    if (t < 64) {
        float s = lin1_b[t];
        const float4* w1 = (const float4*)&lin1_w[t * 128];
#pragma unroll
        for (int i = 0; i < 32; ++i) {
            float4 a = w1[i];
            s += qs[i * 4] * a.x + qs[i * 4 + 1] * a.y + qs[i * 4 + 2] * a.z + qs[i * 4 + 3] * a.w;
        }
        s = fmaxf(s, 0.f) * lin2_w[t];
#pragma unroll
        for (int off = 32; off >= 1; off >>= 1) s += __shfl_xor(s, off);
        if (t == 0) yout[g] = s + lin2_b[0];
    }
}

extern "C" void kernel_launch(void* const* d_in, const int* in_sizes, int n_in,
                              void* d_out, int out_size, void* d_ws, size_t ws_size,
                              hipStream_t stream) {
    (void)in_sizes; (void)n_in; (void)out_size;
    const float* x        = (const float*)d_in[0];
    const float* eattr    = (const float*)d_in[1];
    const int*   ei       = (const int*)d_in[2];
    const int*   batch    = (const int*)d_in[3];
    const float* lin0_w   = (const float*)d_in[4];
    const float* lin0_b   = (const float*)d_in[5];
    const float* nn_w1    = (const float*)d_in[6];
    const float* nn_b1    = (const float*)d_in[7];
    const float* nn_w2    = (const float*)d_in[8];
    const float* nn_b2    = (const float*)d_in[9];
    const float* conv_root= (const float*)d_in[10];
    const float* conv_bias= (const float*)d_in[11];
    const float* gw_ih    = (const float*)d_in[12];
    const float* gw_hh    = (const float*)d_in[13];
    const float* gb_ih    = (const float*)d_in[14];
    const float* gb_hh    = (const float*)d_in[15];
    const float* lw_ih    = (const float*)d_in[16];
    const float* lw_hh    = (const float*)d_in[17];
    const float* lb_ih    = (const float*)d_in[18];
    const float* lb_hh    = (const float*)d_in[19];
    const float* lin1_w   = (const float*)d_in[20];
    const float* lin1_b   = (const float*)d_in[21];
    const float* lin2_w   = (const float*)d_in[22];
    const float* lin2_b   = (const float*)d_in[23];
    const int* src = ei;
    const int* dst = ei + NE;

    char* w = (char*)d_ws;
    auto alloc = [&](size_t bytes) { char* p = w; w += (bytes + 255) & ~(size_t)255; return p; };
    float* out    = (float*)alloc((size_t)NN * 64 * 4);
    float* e_h    = (float*)alloc((size_t)NE * 128 * 4);
    u16*   Whi    = (u16*)alloc((size_t)64 * SK * 2);
    u16*   Wlo    = (u16*)alloc((size_t)64 * SK * 2);
    float* P      = (float*)alloc((size_t)KSPLIT * NN * 64 * 4);
    float* Osum   = (float*)alloc((size_t)NN * 64 * 4);
    u16*   Bmh    = (u16*)alloc((size_t)8192 * 2);
    u16*   Bml    = (u16*)alloc((size_t)8192 * 2);
    u16*   Bih_h  = (u16*)alloc((size_t)12288 * 2);
    u16*   Bih_l  = (u16*)alloc((size_t)12288 * 2);
    u16*   Bhh_h  = (u16*)alloc((size_t)12288 * 2);
    u16*   Bhh_l  = (u16*)alloc((size_t)12288 * 2);
    float* degf   = (float*)alloc((size_t)NN * 4);
    int*   degi   = (int*)alloc((size_t)NN * 4);
    int*   rowptr = (int*)alloc((size_t)(NN + 1) * 4);
    int*   cursor = (int*)alloc((size_t)(NN + 1) * 4);
    int*   elist  = (int*)alloc((size_t)NE * 4);
    int*   gstart = (int*)alloc((size_t)(NGB + 1) * 4);
    size_t used = (size_t)(w - (char*)d_ws);
    size_t avail = ws_size > used ? ws_size - used : 0;
    size_t maxrows = avail / ((size_t)SK * 2);      // bf16 S: 16 KB per row
    int chunkN = maxrows > (size_t)NN ? NN : (int)maxrows;
    chunkN = (chunkN / 64) * 64;
    if (chunkN < 64) chunkN = 64;
    u16* S_bf = (u16*)w;

    hipMemsetAsync(degi, 0, (size_t)NN * 4, stream);

    k_lin0<<<NN, 64, 0, stream>>>(x, lin0_w, lin0_b, out);
    k_eh<<<NE / 2, 256, 0, stream>>>(eattr, nn_w1, nn_b1, e_h);
    k_prep<<<2176, 256, 0, stream>>>(nn_w2, conv_root, nn_b2, gw_ih, gw_hh,
                                     Whi, Wlo, Bmh, Bml, Bih_h, Bih_l, Bhh_h, Bhh_l);
    k_deg<<<(NE + 255) / 256, 256, 0, stream>>>(dst, degi);
    k_scan<<<1, 1024, 0, stream>>>(degi, rowptr, cursor, degf);
    k_fill<<<(NE + 255) / 256, 256, 0, stream>>>(dst, cursor, elist);
    k_gstart<<<5, 64, 0, stream>>>(batch, gstart);

    for (int it = 0; it < 3; ++it) {
        for (int cb = 0; cb < NN; cb += chunkN) {
            int cn = (NN - cb) < chunkN ? (NN - cb) : chunkN;
            k_sbuild<<<cn, 256, 0, stream>>>(out, e_h, src, rowptr, elist, S_bf, Osum, cb);
            k_gemm<<<dim3(cn / 32, KSPLIT), 64, 0, stream>>>(S_bf, Whi, Wlo, P, cb);
        }
        k_node<<<NN / 16, 64, 0, stream>>>(out, P, Osum, degf, Bmh, Bml,
                                           Bih_h, Bih_l, Bhh_h, Bhh_l,
                                           conv_bias, gb_ih, gb_hh);
    }

    k_s2s<<<NGB, 256, 0, stream>>>(out, gstart, lw_ih, lw_hh, lb_ih, lb_hh,
                                   lin1_w, lin1_b, lin2_w, lin2_b, (float*)d_out);
}

// Round 16
// 384.343 us; speedup vs baseline: 3.9519x; 1.0486x over previous
//
#include <hip/hip_runtime.h>
#include <math.h>

#define NN 8000
#define NE 40000
#define NGB 256
#define SK 8192
#define KSPLIT 16

typedef unsigned int u32;
typedef unsigned short u16;
typedef __attribute__((ext_vector_type(8))) short short8v;
typedef __attribute__((ext_vector_type(4))) float float4v;
typedef __attribute__((ext_vector_type(4))) unsigned int uint4v;

__device__ __forceinline__ float sigmoidf_(float x) { return 1.f / (1.f + expf(-x)); }

__device__ __forceinline__ u32 bf16_rne(float f) {
    u32 x = __builtin_bit_cast(u32, f);
    return (x + 0x7FFFu + ((x >> 16) & 1u)) >> 16;
}

// pack 8 floats -> 8 bf16 (RNE) in a uint4
__device__ __forceinline__ uint4v pack_bf8(const float v[8]) {
    u32 h[8];
#pragma unroll
    for (int j = 0; j < 8; ++j) h[j] = bf16_rne(v[j]);
    return (uint4v){ h[0] | (h[1] << 16), h[2] | (h[3] << 16),
                     h[4] | (h[5] << 16), h[6] | (h[7] << 16) };
}

// load 8 consecutive floats, scale, split into hi/lo bf16x8 fragments (for tiny GEMMs)
__device__ __forceinline__ void pack8(const float* p, float scale, short8v& ah, short8v& al) {
    float v[8];
#pragma unroll
    for (int j = 0; j < 8; ++j) v[j] = p[j];
    u32 hu[8], lu[8];
#pragma unroll
    for (int j = 0; j < 8; ++j) {
        float s = v[j] * scale;
        hu[j] = bf16_rne(s);
        float fh = __builtin_bit_cast(float, hu[j] << 16);
        lu[j] = bf16_rne(s - fh);
    }
    uint4v hset = { hu[0] | (hu[1] << 16), hu[2] | (hu[3] << 16),
                    hu[4] | (hu[5] << 16), hu[6] | (hu[7] << 16) };
    uint4v lset = { lu[0] | (lu[1] << 16), lu[2] | (lu[3] << 16),
                    lu[4] | (lu[5] << 16), lu[6] | (lu[7] << 16) };
    ah = __builtin_bit_cast(short8v, hset);
    al = __builtin_bit_cast(short8v, lset);
}

// ---------- small setup kernels ----------

__global__ void k_lin0(const float* __restrict__ x, const float* __restrict__ w,
                       const float* __restrict__ b, float* __restrict__ out) {
    __shared__ float xr[21];
    int n = blockIdx.x, t = threadIdx.x;
    if (t < 21) xr[t] = x[n * 21 + t];
    __syncthreads();
    float s = b[t];
#pragma unroll
    for (int c = 0; c < 21; ++c) s += xr[c] * w[t * 21 + c];
    out[n * 64 + t] = fmaxf(s, 0.f);
}

__global__ void k_eh(const float* __restrict__ ea, const float* __restrict__ w1,
                     const float* __restrict__ b1, float* __restrict__ e_h) {
    __shared__ float a[2][16];
    int t = threadIdx.x;
    int e0 = blockIdx.x * 2;
    if (t < 32) a[t >> 4][t & 15] = ea[(e0 + (t >> 4)) * 16 + (t & 15)];
    __syncthreads();
    int sub = t >> 7, j = t & 127;
    float s = b1[j];
#pragma unroll
    for (int c = 0; c < 16; ++c) s += a[sub][c] * w1[j * 16 + c];
    e_h[(size_t)(e0 + sub) * 128 + j] = fmaxf(s, 0.f);
}

// merged weight prep: W2T hi/lo (524288) + mrelu B (8192) + gate B (24576)
__global__ void k_prep(const float* __restrict__ nn_w2, const float* __restrict__ conv_root,
                       const float* __restrict__ nn_b2, const float* __restrict__ w_ih,
                       const float* __restrict__ w_hh,
                       u16* __restrict__ Whi, u16* __restrict__ Wlo,
                       u16* __restrict__ Bmh, u16* __restrict__ Bml,
                       u16* __restrict__ Bih_h, u16* __restrict__ Bih_l,
                       u16* __restrict__ Bhh_h, u16* __restrict__ Bhh_l) {
    int idx = blockIdx.x * 256 + threadIdx.x;
    if (idx < 524288) {
        int o = idx >> 13, kap = idx & 8191;
        int i = kap >> 7, k = kap & 127;
        float v = nn_w2[(size_t)((i << 6) + o) * 128 + k];
        u32 h = bf16_rne(v);
        float fh = __builtin_bit_cast(float, h << 16);
        u32 l = bf16_rne(v - fh);
        int pos = ((kap >> 3) * 64 + o) * 8 + (kap & 7);
        Whi[pos] = (u16)h; Wlo[pos] = (u16)l;
    } else if (idx < 524288 + 8192) {
        int i2 = idx - 524288;
        int k = i2 >> 6, o = i2 & 63;
        float v = (k < 64) ? nn_b2[k * 64 + o] : conv_root[(k - 64) * 64 + o];
        u32 h = bf16_rne(v);
        float fh = __builtin_bit_cast(float, h << 16);
        u32 l = bf16_rne(v - fh);
        int pos = ((k >> 3) * 64 + o) * 8 + (k & 7);
        Bmh[pos] = (u16)h; Bml[pos] = (u16)l;
    } else if (idx < 524288 + 8192 + 24576) {
        int i3 = idx - 524288 - 8192;
        int half = i3 >= 12288;
        int i2 = i3 - half * 12288;
        int o = i2 % 192, k = i2 / 192;
        float v = half ? w_hh[o * 64 + k] : w_ih[o * 64 + k];
        u32 h = bf16_rne(v);
        float fh = __builtin_bit_cast(float, h << 16);
        u32 l = bf16_rne(v - fh);
        int pos = ((k >> 3) * 192 + o) * 8 + (k & 7);
        if (half) { Bhh_h[pos] = (u16)h; Bhh_l[pos] = (u16)l; }
        else      { Bih_h[pos] = (u16)h; Bih_l[pos] = (u16)l; }
    }
}

__global__ void k_deg(const int* __restrict__ dst, int* __restrict__ degi) {
    int e = blockIdx.x * blockDim.x + threadIdx.x;
    if (e < NE) atomicAdd(&degi[dst[e]], 1);
}

// single-block scan, sequential 8-per-thread chunks + one LDS log-scan
__global__ __launch_bounds__(1024) void k_scan(
    const int* __restrict__ degi, int* __restrict__ rowptr,
    int* __restrict__ cursor, float* __restrict__ degf) {
    __shared__ int tsum[1024];
    int t = threadIdx.x;
    int base = t * 8;                  // 1024*8 = 8192 >= NN
    int v[8];
    int s = 0;
#pragma unroll
    for (int j = 0; j < 8; ++j) {
        int i = base + j;
        v[j] = (i < NN) ? degi[i] : 0;
        s += v[j];
    }
    tsum[t] = s;
    __syncthreads();
    // inclusive scan of tsum
    for (int off = 1; off < 1024; off <<= 1) {
        int add = (t >= off) ? tsum[t - off] : 0;
        __syncthreads();
        tsum[t] += add;
        __syncthreads();
    }
    int exc = (t == 0) ? 0 : tsum[t - 1];
#pragma unroll
    for (int j = 0; j < 8; ++j) {
        int i = base + j;
        if (i < NN) {
            rowptr[i] = exc; cursor[i] = exc;
            degf[i] = (float)(v[j] > 1 ? v[j] : 1);
            exc += v[j];
        }
    }
    if (t == 1023) rowptr[NN] = tsum[1023];
}

__global__ void k_fill(const int* __restrict__ dst, int* __restrict__ cursor,
                       int* __restrict__ elist) {
    int e = blockIdx.x * blockDim.x + threadIdx.x;
    if (e < NE) { int p = atomicAdd(&cursor[dst[e]], 1); elist[p] = e; }
}

__global__ void k_gstart(const int* __restrict__ batch, int* __restrict__ gstart) {
    int g = blockIdx.x * blockDim.x + threadIdx.x;
    if (g > NGB) return;
    int lo = 0, hi = NN;
    while (lo < hi) { int mid = (lo + hi) >> 1; if (batch[mid] < g) lo = mid + 1; else hi = mid; }
    gstart[g] = lo;
}

// ---------- NNConv: S build (bf16 S) ----------
__global__ __launch_bounds__(256) void k_sbuild(
    const float* __restrict__ out, const float* __restrict__ e_h,
    const int* __restrict__ src, const int* __restrict__ rowptr,
    const int* __restrict__ elist, u16* __restrict__ S_bf,
    float* __restrict__ Osum, int base) {
    int t = threadIdx.x;
    int n = base + blockIdx.x;
    int ig = t >> 4;
    int k8 = t & 15;
    int lane = t & 63;
    float acc[4][8];
#pragma unroll
    for (int j = 0; j < 4; ++j)
#pragma unroll
        for (int c = 0; c < 8; ++c) acc[j][c] = 0.f;
    float osum = 0.f;
    int r0 = rowptr[n], r1 = rowptr[n + 1];
    const float4* out4 = (const float4*)out;
    const float4* eh4p = (const float4*)e_h;
    for (int idx = r0; idx < r1; ++idx) {
        int e = elist[idx];
        int sn = src[e];
        float4 e0 = eh4p[(size_t)e * 32 + k8 * 2];
        float4 e1 = eh4p[(size_t)e * 32 + k8 * 2 + 1];
        float ehv[8] = {e0.x, e0.y, e0.z, e0.w, e1.x, e1.y, e1.z, e1.w};
        float4 f = out4[sn * 16 + ig];
        float fv[4] = {f.x, f.y, f.z, f.w};
#pragma unroll
        for (int j = 0; j < 4; ++j)
#pragma unroll
            for (int c = 0; c < 8; ++c) acc[j][c] += fv[j] * ehv[c];
        if (t < 64) osum += out[(size_t)sn * 64 + lane];
    }
    uint4v* S4 = (uint4v*)S_bf;
    size_t rb = (size_t)blockIdx.x * (SK / 8);
#pragma unroll
    for (int j = 0; j < 4; ++j)
        S4[rb + (size_t)(ig * 4 + j) * 16 + k8] = pack_bf8(acc[j]);
    if (t < 64) Osum[(size_t)n * 64 + lane] = osum;
}

// ---------- NNConv: MFMA GEMM. 1 wave/block, M=32/wave, KSPLIT=16 ----------
__global__ __launch_bounds__(64) void k_gemm(
    const u16* __restrict__ S_bf, const u16* __restrict__ Whi,
    const u16* __restrict__ Wlo, float* __restrict__ P, int base) {
    int lane = threadIdx.x;
    int lrow = lane & 15, lkg = lane >> 4;
    int m0 = blockIdx.x * 32;
    int ks = blockIdx.y;
    int kbase = ks * (SK / KSPLIT);         // 512 kappa per split
    float4v acc[2][4];
#pragma unroll
    for (int ms = 0; ms < 2; ++ms)
#pragma unroll
        for (int nt = 0; nt < 4; ++nt) acc[ms][nt] = (float4v){0.f, 0.f, 0.f, 0.f};
    const short8v* bhv = (const short8v*)Whi;
    const short8v* blv = (const short8v*)Wlo;
    const u16* ar0 = S_bf + (size_t)(m0 + lrow) * SK + kbase + lkg * 8;
    const u16* ar1 = ar0 + (size_t)16 * SK;
    int kc0 = (kbase >> 3) + lkg;           // kchunk index (8 kappa per chunk)

#pragma unroll 4
    for (int kk = 0; kk < SK / KSPLIT / 32; ++kk) {    // 16 iterations, K=32 each
        short8v ah0 = *(const short8v*)(ar0 + kk * 32);
        short8v ah1 = *(const short8v*)(ar1 + kk * 32);
        int bo = (kc0 + kk * 4) * 64 + lrow;
        short8v bh[4], bl[4];
#pragma unroll
        for (int nt = 0; nt < 4; ++nt) { bh[nt] = bhv[bo + nt * 16]; bl[nt] = blv[bo + nt * 16]; }
#pragma unroll
        for (int nt = 0; nt < 4; ++nt) {
            acc[0][nt] = __builtin_amdgcn_mfma_f32_16x16x32_bf16(ah0, bh[nt], acc[0][nt], 0, 0, 0);
            acc[0][nt] = __builtin_amdgcn_mfma_f32_16x16x32_bf16(ah0, bl[nt], acc[0][nt], 0, 0, 0);
            acc[1][nt] = __builtin_amdgcn_mfma_f32_16x16x32_bf16(ah1, bh[nt], acc[1][nt], 0, 0, 0);
            acc[1][nt] = __builtin_amdgcn_mfma_f32_16x16x32_bf16(ah1, bl[nt], acc[1][nt], 0, 0, 0);
        }
    }
    int gbase = base + m0;
#pragma unroll
    for (int ms = 0; ms < 2; ++ms)
#pragma unroll
        for (int nt = 0; nt < 4; ++nt)
#pragma unroll
            for (int jj = 0; jj < 4; ++jj) {
                int row = ms * 16 + lkg * 4 + jj;   // C/D: row=(lane>>4)*4+reg  [m89 verified]
                int o = nt * 16 + lrow;             //      col=lane&15
                P[((size_t)ks * NN + gbase + row) * 64 + o] = acc[ms][nt][jj];
            }
}

// ---------- fused node update: psum + mrelu(MFMA) + GRU gates(MFMA); out <- h' ----------
__global__ __launch_bounds__(64) void k_node(
    float* __restrict__ out, const float* __restrict__ P,
    const float* __restrict__ Osum, const float* __restrict__ degf,
    const u16* __restrict__ Bmh, const u16* __restrict__ Bml,
    const u16* __restrict__ Bih_h, const u16* __restrict__ Bih_l,
    const u16* __restrict__ Bhh_h, const u16* __restrict__ Bhh_l,
    const float* __restrict__ conv_bias,
    const float* __restrict__ gb_ih, const float* __restrict__ gb_hh) {
    __shared__ float lds[16][68];     // psum, then M (padded stride 68)
    int lane = threadIdx.x;
    int lrow = lane & 15, lkg = lane >> 4;
    int n0 = blockIdx.x * 16;
    int arow = n0 + lrow;

    // phase 1: Psum[arow][lkg*16 .. +15] = sum over KSPLIT planes (coalesced)
    {
        const float4* P4 = (const float4*)P;
        float4 ps[4];
#pragma unroll
        for (int c = 0; c < 4; ++c) ps[c] = make_float4(0.f, 0.f, 0.f, 0.f);
        for (int p = 0; p < KSPLIT; ++p) {
#pragma unroll
            for (int c = 0; c < 4; ++c) {
                float4 v = P4[(size_t)p * (NN * 16) + (size_t)arow * 16 + lkg * 4 + c];
                ps[c].x += v.x; ps[c].y += v.y; ps[c].z += v.z; ps[c].w += v.w;
            }
        }
#pragma unroll
        for (int c = 0; c < 4; ++c)
            *(float4*)&lds[lrow][lkg * 16 + c * 4] = ps[c];
    }
    __syncthreads();

    // phase 2: mrelu MFMA (A rows: Osum/deg then out; B: nn_b2 then conv_root)
    float invd = 1.f / degf[arow];
    float4v acc[4];
#pragma unroll
    for (int nt = 0; nt < 4; ++nt) acc[nt] = (float4v){0.f, 0.f, 0.f, 0.f};
    const short8v* bhv = (const short8v*)Bmh;
    const short8v* blv = (const short8v*)Bml;
#pragma unroll
    for (int s = 0; s < 4; ++s) {
        short8v ah, al;
        if (s < 2) pack8(&Osum[(size_t)arow * 64 + s * 32 + lkg * 8], invd, ah, al);
        else       pack8(&out[(size_t)arow * 64 + (s - 2) * 32 + lkg * 8], 1.f, ah, al);
        int kc = s * 4 + lkg;
#pragma unroll
        for (int nt = 0; nt < 4; ++nt) {
            short8v bh = bhv[kc * 64 + nt * 16 + lrow];
            short8v bl = blv[kc * 64 + nt * 16 + lrow];
            acc[nt] = __builtin_amdgcn_mfma_f32_16x16x32_bf16(ah, bh, acc[nt], 0, 0, 0);
            acc[nt] = __builtin_amdgcn_mfma_f32_16x16x32_bf16(al, bh, acc[nt], 0, 0, 0);
            acc[nt] = __builtin_amdgcn_mfma_f32_16x16x32_bf16(ah, bl, acc[nt], 0, 0, 0);
        }
    }
    float invd2[4];
#pragma unroll
    for (int jj = 0; jj < 4; ++jj) invd2[jj] = 1.f / degf[n0 + lkg * 4 + jj];
    float mval[4][4];
#pragma unroll
    for (int nt = 0; nt < 4; ++nt) {
        int o = nt * 16 + lrow;
        float cb = conv_bias[o];
#pragma unroll
        for (int jj = 0; jj < 4; ++jj)
            mval[nt][jj] = fmaxf(acc[nt][jj] + lds[lkg * 4 + jj][o] * invd2[jj] + cb, 0.f);
    }
    __syncthreads();   // all psum reads done
#pragma unroll
    for (int nt = 0; nt < 4; ++nt)
#pragma unroll
        for (int jj = 0; jj < 4; ++jj)
            lds[lkg * 4 + jj][nt * 16 + lrow] = mval[nt][jj];
    __syncthreads();   // M ready in LDS

    // phase 3: GRU gates MFMA
    float4v ai[12], ah_[12];
#pragma unroll
    for (int nt = 0; nt < 12; ++nt) { ai[nt] = (float4v){0.f, 0.f, 0.f, 0.f}; ah_[nt] = (float4v){0.f, 0.f, 0.f, 0.f}; }
    const short8v* bih_h = (const short8v*)Bih_h;
    const short8v* bih_l = (const short8v*)Bih_l;
    const short8v* bhh_h = (const short8v*)Bhh_h;
    const short8v* bhh_l = (const short8v*)Bhh_l;
#pragma unroll
    for (int s = 0; s < 2; ++s) {
        short8v mh, ml, hh, hl;
        pack8(&lds[lrow][s * 32 + lkg * 8], 1.f, mh, ml);
        pack8(&out[(size_t)arow * 64 + s * 32 + lkg * 8], 1.f, hh, hl);
        int kc = s * 4 + lkg;
#pragma unroll
        for (int nt = 0; nt < 12; ++nt) {
            int bo = kc * 192 + nt * 16 + lrow;
            short8v b1 = bih_h[bo], b2 = bih_l[bo];
            ai[nt] = __builtin_amdgcn_mfma_f32_16x16x32_bf16(mh, b1, ai[nt], 0, 0, 0);
            ai[nt] = __builtin_amdgcn_mfma_f32_16x16x32_bf16(ml, b1, ai[nt], 0, 0, 0);
            ai[nt] = __builtin_amdgcn_mfma_f32_16x16x32_bf16(mh, b2, ai[nt], 0, 0, 0);
            short8v b3 = bhh_h[bo], b4 = bhh_l[bo];
            ah_[nt] = __builtin_amdgcn_mfma_f32_16x16x32_bf16(hh, b3, ah_[nt], 0, 0, 0);
            ah_[nt] = __builtin_amdgcn_mfma_f32_16x16x32_bf16(hl, b3, ah_[nt], 0, 0, 0);
            ah_[nt] = __builtin_amdgcn_mfma_f32_16x16x32_bf16(hh, b4, ah_[nt], 0, 0, 0);
        }
    }
#pragma unroll
    for (int nt = 0; nt < 4; ++nt) {
        int o = nt * 16 + lrow;
        float bi0 = gb_ih[o], bi1 = gb_ih[64 + o], bi2 = gb_ih[128 + o];
        float bh0 = gb_hh[o], bh1 = gb_hh[64 + o], bh2 = gb_hh[128 + o];
#pragma unroll
        for (int jj = 0; jj < 4; ++jj) {
            int row = n0 + lkg * 4 + jj;
            float ir = ai[nt][jj] + bi0,  hr = ah_[nt][jj] + bh0;
            float iz = ai[nt + 4][jj] + bi1, hz = ah_[nt + 4][jj] + bh1;
            float in_ = ai[nt + 8][jj] + bi2, hn = ah_[nt + 8][jj] + bh2;
            float r = sigmoidf_(ir + hr);
            float z = sigmoidf_(iz + hz);
            float nv = tanhf(in_ + r * hn);
            float ho = out[(size_t)row * 64 + o];
            out[(size_t)row * 64 + o] = (1.f - z) * nv + z * ho;
        }
    }
}

// ---------- fused Set2Set: 3x(LSTM+attention) + final linear, one block per graph ----------
__global__ __launch_bounds__(256) void k_s2s(
    const float* __restrict__ out, const int* __restrict__ gstart,
    const float* __restrict__ lw_ih, const float* __restrict__ lw_hh,
    const float* __restrict__ lb_ih, const float* __restrict__ lb_hh,
    const float* __restrict__ lin1_w, const float* __restrict__ lin1_b,
    const float* __restrict__ lin2_w, const float* __restrict__ lin2_b,
    float* __restrict__ yout) {
    __shared__ float qs[128], hsL[64], csL[64], gates[256];
    __shared__ float pv[384];
    __shared__ float red[4][64];
    __shared__ float sswv[4], mmaxw[4];
    int g = blockIdx.x, t = threadIdx.x, wv = t >> 6, lane = t & 63;
    int s0 = gstart[g], s1 = gstart[g + 1];
    if (t < 128) qs[t] = 0.f;
    if (t < 64) { hsL[t] = 0.f; csL[t] = 0.f; }
    __syncthreads();
    for (int st = 0; st < 3; ++st) {
        // LSTM gates
        float s = lb_ih[t] + lb_hh[t];
        const float4* wi = (const float4*)&lw_ih[t * 128];
#pragma unroll
        for (int i = 0; i < 32; ++i) {
            float4 a = wi[i];
            s += qs[i * 4] * a.x + qs[i * 4 + 1] * a.y + qs[i * 4 + 2] * a.z + qs[i * 4 + 3] * a.w;
        }
        const float4* wh = (const float4*)&lw_hh[t * 64];
#pragma unroll
        for (int i = 0; i < 16; ++i) {
            float4 a = wh[i];
            s += hsL[i * 4] * a.x + hsL[i * 4 + 1] * a.y + hsL[i * 4 + 2] * a.z + hsL[i * 4 + 3] * a.w;
        }
        gates[t] = s;
        __syncthreads();
        if (t < 64) {
            float ig = sigmoidf_(gates[t]);
            float fg = sigmoidf_(gates[64 + t]);
            float gg = tanhf(gates[128 + t]);
            float og = sigmoidf_(gates[192 + t]);
            float c = fg * csL[t] + ig * gg;
            csL[t] = c;
            hsL[t] = og * tanhf(c);
        }
        __syncthreads();
        // attention pass A: logits + max
        float wmax = -1e30f;
        for (int i = s0 + wv; i < s1; i += 4) {
            float p = out[(size_t)i * 64 + lane] * hsL[lane];
#pragma unroll
            for (int off = 32; off >= 1; off >>= 1) p += __shfl_xor(p, off);
            if (lane == 0) pv[i - s0] = p;
            wmax = fmaxf(wmax, p);
        }
        if (lane == 0) mmaxw[wv] = wmax;
        __syncthreads();
        float mmax = fmaxf(fmaxf(mmaxw[0], mmaxw[1]), fmaxf(mmaxw[2], mmaxw[3]));
        // pass B: weighted sums
        float ssum = 0.f, racc = 0.f;
        for (int i = s0 + wv; i < s1; i += 4) {
            float w = expf(pv[i - s0] - mmax);
            ssum += w;
            racc += w * out[(size_t)i * 64 + lane];
        }
        red[wv][lane] = racc;
        if (lane == 0) sswv[wv] = ssum;
        __syncthreads();
        if (t < 64) {
            float rt = red[0][t] + red[1][t] + red[2][t] + red[3][t];
            float stot = sswv[0] + sswv[1] + sswv[2] + sswv[3];
            qs[t] = hsL[t];
            qs[64 + t] = (s1 > s0) ? rt / stot : 0.f;
        }
        __syncthreads();
    }
    // final: y = relu(q_star @ lin1^T + b1) @ lin2^T + b2
    if (t < 64) {
        float s = lin1_b[t];
        const float4* w1 = (const float4*)&lin1_w[t * 128];
#pragma unroll
        for (int i = 0; i < 32; ++i) {
            float4 a = w1[i];
            s += qs[i * 4] * a.x + qs[i * 4 + 1] * a.y + qs[i * 4 + 2] * a.z + qs[i * 4 + 3] * a.w;
        }
        s = fmaxf(s, 0.f) * lin2_w[t];
#pragma unroll
        for (int off = 32; off >= 1; off >>= 1) s += __shfl_xor(s, off);
        if (t == 0) yout[g] = s + lin2_b[0];
    }
}

extern "C" void kernel_launch(void* const* d_in, const int* in_sizes, int n_in,
                              void* d_out, int out_size, void* d_ws, size_t ws_size,
                              hipStream_t stream) {
    (void)in_sizes; (void)n_in; (void)out_size;
    const float* x        = (const float*)d_in[0];
    const float* eattr    = (const float*)d_in[1];
    const int*   ei       = (const int*)d_in[2];
    const int*   batch    = (const int*)d_in[3];
    const float* lin0_w   = (const float*)d_in[4];
    const float* lin0_b   = (const float*)d_in[5];
    const float* nn_w1    = (const float*)d_in[6];
    const float* nn_b1    = (const float*)d_in[7];
    const float* nn_w2    = (const float*)d_in[8];
    const float* nn_b2    = (const float*)d_in[9];
    const float* conv_root= (const float*)d_in[10];
    const float* conv_bias= (const float*)d_in[11];
    const float* gw_ih    = (const float*)d_in[12];
    const float* gw_hh    = (const float*)d_in[13];
    const float* gb_ih    = (const float*)d_in[14];
    const float* gb_hh    = (const float*)d_in[15];
    const float* lw_ih    = (const float*)d_in[16];
    const float* lw_hh    = (const float*)d_in[17];
    const float* lb_ih    = (const float*)d_in[18];
    const float* lb_hh    = (const float*)d_in[19];
    const float* lin1_w   = (const float*)d_in[20];
    const float* lin1_b   = (const float*)d_in[21];
    const float* lin2_w   = (const float*)d_in[22];
    const float* lin2_b   = (const float*)d_in[23];
    const int* src = ei;
    const int* dst = ei + NE;

    char* w = (char*)d_ws;
    auto alloc = [&](size_t bytes) { char* p = w; w += (bytes + 255) & ~(size_t)255; return p; };
    float* out    = (float*)alloc((size_t)NN * 64 * 4);
    float* e_h    = (float*)alloc((size_t)NE * 128 * 4);
    u16*   Whi    = (u16*)alloc((size_t)64 * SK * 2);
    u16*   Wlo    = (u16*)alloc((size_t)64 * SK * 2);
    float* P      = (float*)alloc((size_t)KSPLIT * NN * 64 * 4);
    float* Osum   = (float*)alloc((size_t)NN * 64 * 4);
    u16*   Bmh    = (u16*)alloc((size_t)8192 * 2);
    u16*   Bml    = (u16*)alloc((size_t)8192 * 2);
    u16*   Bih_h  = (u16*)alloc((size_t)12288 * 2);
    u16*   Bih_l  = (u16*)alloc((size_t)12288 * 2);
    u16*   Bhh_h  = (u16*)alloc((size_t)12288 * 2);
    u16*   Bhh_l  = (u16*)alloc((size_t)12288 * 2);
    float* degf   = (float*)alloc((size_t)NN * 4);
    int*   degi   = (int*)alloc((size_t)NN * 4);
    int*   rowptr = (int*)alloc((size_t)(NN + 1) * 4);
    int*   cursor = (int*)alloc((size_t)(NN + 1) * 4);
    int*   elist  = (int*)alloc((size_t)NE * 4);
    int*   gstart = (int*)alloc((size_t)(NGB + 1) * 4);
    size_t used = (size_t)(w - (char*)d_ws);
    size_t avail = ws_size > used ? ws_size - used : 0;
    size_t maxrows = avail / ((size_t)SK * 2);      // bf16 S: 16 KB per row
    int chunkN = maxrows > (size_t)NN ? NN : (int)maxrows;
    chunkN = (chunkN / 64) * 64;
    if (chunkN < 64) chunkN = 64;
    u16* S_bf = (u16*)w;

    hipMemsetAsync(degi, 0, (size_t)NN * 4, stream);

    k_lin0<<<NN, 64, 0, stream>>>(x, lin0_w, lin0_b, out);
    k_eh<<<NE / 2, 256, 0, stream>>>(eattr, nn_w1, nn_b1, e_h);
    k_prep<<<2176, 256, 0, stream>>>(nn_w2, conv_root, nn_b2, gw_ih, gw_hh,
                                     Whi, Wlo, Bmh, Bml, Bih_h, Bih_l, Bhh_h, Bhh_l);
    k_deg<<<(NE + 255) / 256, 256, 0, stream>>>(dst, degi);
    k_scan<<<1, 1024, 0, stream>>>(degi, rowptr, cursor, degf);
    k_fill<<<(NE + 255) / 256, 256, 0, stream>>>(dst, cursor, elist);
    k_gstart<<<5, 64, 0, stream>>>(batch, gstart);

    for (int it = 0; it < 3; ++it) {
        for (int cb = 0; cb < NN; cb += chunkN) {
            int cn = (NN - cb) < chunkN ? (NN - cb) : chunkN;
            k_sbuild<<<cn, 256, 0, stream>>>(out, e_h, src, rowptr, elist, S_bf, Osum, cb);
            k_gemm<<<dim3(cn / 32, KSPLIT), 64, 0, stream>>>(S_bf, Whi, Wlo, P, cb);
        }
        k_node<<<NN / 16, 64, 0, stream>>>(out, P, Osum, degf, Bmh, Bml,
                                           Bih_h, Bih_l, Bhh_h, Bhh_l,
                                           conv_bias, gb_ih, gb_hh);
    }

    k_s2s<<<NGB, 256, 0, stream>>>(out, gstart, lw_ih, lw_hh, lb_ih, lb_hh,
                                   lin1_w, lin1_b, lin2_w, lin2_b, (float*)d_out);
}